// Round 7
// baseline (963.235 us; speedup 1.0000x reference)
//
#include <hip/hip_runtime.h>
#include <math.h>

// MoE top-2 of 8 experts, D=1024, H=4096, 8192 tokens.
// Round 7: 128x256xBK64 tiles, 512 threads / 8 waves, 3-buffer counted
// vmcnt(6) ring, XOR-swizzled LDS (slot = granule ^ (row&7), applied on
// both the pre-swizzled global source and the ds_read). 4x MFMA per
// barrier vs round 6. Bookkeeping/tiling (128-row token tiles) unchanged.
#define TOKENS 8192
#define DIM    1024
#define NEXP   8
#define HID    4096
#define TILE_M 128
#define MAX_TILES 136

// old-path (fallback) LDS strides
#define BK     32
#define LDA    40
#define LDB    40

typedef __bf16 bf16x8 __attribute__((ext_vector_type(8)));
typedef float  f32x4  __attribute__((ext_vector_type(4)));
typedef unsigned int u32x4 __attribute__((ext_vector_type(4)));

__device__ __forceinline__ unsigned short f2bf(float f) {
  union { float f; unsigned u; } v; v.f = f;
  unsigned u = v.u + 0x7fffu + ((v.u >> 16) & 1u);   // RNE
  return (unsigned short)(u >> 16);
}
__device__ __forceinline__ float gelu_f(float v) {
  return 0.5f * v * (1.f + erff(v * 0.7071067811865476f));
}
__device__ __forceinline__ float gelu_fast(float v) {
  float t = v * v;
  float y = 0.7978845608f * v * fmaf(t, 0.044715f, 1.0f);
  y = fminf(y, 15.f);
  float z = __expf(2.f * y);
  return v * z * __builtin_amdgcn_rcpf(1.f + z);
}
__device__ __forceinline__ void gload16(const void* g, void* l) {
  __builtin_amdgcn_global_load_lds(
      (const __attribute__((address_space(1))) void*)g,
      (__attribute__((address_space(3))) void*)l, 16, 0, 0);
}
// bijective XCD-chunked swizzle (m204)
__device__ __forceinline__ int xcd_swz(int id, int nwg) {
  int q = nwg >> 3, r = nwg & 7;
  int xcd = id & 7, rank = id >> 3;
  return (xcd < r) ? xcd * (q + 1) + rank : r * (q + 1) + (xcd - r) * q + rank;
}

// ---------------- router (+ fused x->bf16 cast): one wave per token ----------------
__global__ __launch_bounds__(256) void k_router(
    const float* __restrict__ x, const float* __restrict__ wr,
    const float* __restrict__ br, int* __restrict__ sel,
    float* __restrict__ gates, int* __restrict__ counts,
    unsigned short* __restrict__ xb)
{
  int t = blockIdx.x * 4 + (threadIdx.x >> 6);
  int lane = threadIdx.x & 63;
  const float* xr = x + (size_t)t * DIM;
  unsigned short* xo = xb + (size_t)t * DIM;
  float acc[NEXP];
#pragma unroll
  for (int e = 0; e < NEXP; ++e) acc[e] = 0.f;
#pragma unroll
  for (int it = 0; it < 4; ++it) {
    int d = it * 256 + lane * 4;
    float4 xv = *(const float4*)(xr + d);
    ushort4 pk;
    pk.x = f2bf(xv.x); pk.y = f2bf(xv.y); pk.z = f2bf(xv.z); pk.w = f2bf(xv.w);
    *(ushort4*)(xo + d) = pk;
    float xs[4] = {xv.x, xv.y, xv.z, xv.w};
#pragma unroll
    for (int j = 0; j < 4; ++j) {
      float4 wa = *(const float4*)(wr + (size_t)(d + j) * NEXP);
      float4 wb = *(const float4*)(wr + (size_t)(d + j) * NEXP + 4);
      acc[0] += xs[j] * wa.x; acc[1] += xs[j] * wa.y;
      acc[2] += xs[j] * wa.z; acc[3] += xs[j] * wa.w;
      acc[4] += xs[j] * wb.x; acc[5] += xs[j] * wb.y;
      acc[6] += xs[j] * wb.z; acc[7] += xs[j] * wb.w;
    }
  }
#pragma unroll
  for (int off = 32; off >= 1; off >>= 1) {
#pragma unroll
    for (int e = 0; e < NEXP; ++e) acc[e] += __shfl_xor(acc[e], off);
  }
  if (lane == 0) {
    float l[NEXP];
#pragma unroll
    for (int e = 0; e < NEXP; ++e) l[e] = acc[e] + br[e];
    int e1 = 0; float v1 = l[0];
#pragma unroll
    for (int e = 1; e < NEXP; ++e) if (l[e] > v1) { v1 = l[e]; e1 = e; }
    int e2 = -1; float v2 = -1e30f;
#pragma unroll
    for (int e = 0; e < NEXP; ++e) {
      if (e == e1) continue;
      if (l[e] > v2) { v2 = l[e]; e2 = e; }
    }
    float g1 = 1.f / (1.f + expf(v2 - v1));
    sel[t * 2] = e1; sel[t * 2 + 1] = e2;
    gates[t * 2] = g1; gates[t * 2 + 1] = 1.f - g1;
    atomicAdd(&counts[e1], 1);
    atomicAdd(&counts[e2], 1);
  }
}

// ---------------- setup: offsets, tile table, padding (parallel), loss ----------------
__global__ __launch_bounds__(256) void k_setup(
    const int* __restrict__ counts, int* __restrict__ cursors,
    int* __restrict__ ntiles_p, int* __restrict__ tile_expert,
    int* __restrict__ tile_row0, int* __restrict__ pair_token,
    float* __restrict__ pair_gate, float* __restrict__ loss_out)
{
  __shared__ int s_pad0[NEXP], s_pad1[NEXP];
  int tid = threadIdx.x;
  if (tid == 0) {
    int poff = 0, nt = 0;
    float var = 0.f;
    for (int e = 0; e < NEXP; ++e) {
      int c = counts[e];
      cursors[e] = poff;
      int ntl = (c + TILE_M - 1) / TILE_M;
      for (int i = 0; i < ntl; ++i) { tile_expert[nt] = e; tile_row0[nt] = poff + i * TILE_M; ++nt; }
      s_pad0[e] = poff + c;
      s_pad1[e] = poff + ntl * TILE_M;
      float d = (float)c - 2048.f;
      var += d * d;
      poff += ntl * TILE_M;
    }
    *ntiles_p = nt;
    *loss_out = (var * (1.f / 7.f)) * (1.f / 2048.f) * 0.01f;
  }
  __syncthreads();
#pragma unroll
  for (int e = 0; e < NEXP; ++e) {
    for (int r = s_pad0[e] + tid; r < s_pad1[e]; r += 256) {
      pair_token[r] = -1; pair_gate[r] = 0.f;
    }
  }
}

// ---------------- bucket: scatter pairs ----------------
__global__ __launch_bounds__(256) void k_bucket(
    const int* __restrict__ sel, const float* __restrict__ gates,
    int* __restrict__ cursors, int* __restrict__ pair_token, float* __restrict__ pair_gate)
{
  int t = blockIdx.x * 256 + threadIdx.x;
#pragma unroll
  for (int k = 0; k < 2; ++k) {
    int e = sel[t * 2 + k];
    int pos = atomicAdd(&cursors[e], 1);
    pair_token[pos] = t;
    pair_gate[pos] = gates[t * 2 + k];
  }
}

// ---------------- transpose-cast: w [E][K][N] f32 -> wT [E][N][K] bf16 ----------------
__global__ __launch_bounds__(256) void k_castwT(
    const float* __restrict__ w, unsigned short* __restrict__ wT, int K, int N)
{
  __shared__ unsigned short t[64][72];
  int e = blockIdx.z, n0 = blockIdx.x * 64, k0 = blockIdx.y * 64;
  int tid = threadIdx.x;
  int kr = tid >> 2, nc = (tid & 3) * 16;
  const float* src = w + ((size_t)e * K + k0 + kr) * N + n0 + nc;
#pragma unroll
  for (int j = 0; j < 4; ++j) {
    f32x4 v = *(const f32x4*)(src + j * 4);
#pragma unroll
    for (int q = 0; q < 4; ++q) t[nc + j * 4 + q][kr] = f2bf(v[q]);
  }
  __syncthreads();
  int nr = tid >> 2, kc = (tid & 3) * 16;
  unsigned short* dst = wT + ((size_t)e * N + n0 + nr) * K + k0 + kc;
  *(u32x4*)dst = *(const u32x4*)&t[nr][kc];
  *(u32x4*)(dst + 8) = *(const u32x4*)&t[nr][kc + 8];
}

// ================= 128x256xBK64, 512-thread, 3-buffer counted-vmcnt GEMMs =================
// LDS rows are 64 bf16 (128 B). Swizzle: slot s holds logical granule g = s ^ (row&7).
// Stage: per-lane source granule = (lane&7) ^ (lane>>3); dest linear (gload_lds).
// Read: slot = (ks*4+lk) ^ (lr&7).
// GEMM1: h = gelu(x_gathered @ w1T^T + b1).  1-D grid = tpc * (HID/256).
// Swapped mfma(bfr, af, acc): n = wn+ni*16+lk*4+r, m = wm+mi*16+lr.
__global__ __launch_bounds__(512) void k_gemm1n(
    const unsigned short* __restrict__ xb, const unsigned short* __restrict__ w1T,
    const float* __restrict__ b1, const int* __restrict__ pair_token,
    const int* __restrict__ tile_expert, const int* __restrict__ tile_row0,
    const int* __restrict__ ntiles_p, unsigned short* __restrict__ h, int chunk_base)
{
  const int NBn = HID / 256;                       // 16
  int newid = xcd_swz(blockIdx.x, gridDim.x);
  int ltile = newid / NBn, nb = newid - ltile * NBn;
  int tile = chunk_base + ltile;
  if (tile >= *ntiles_p) return;
  const int e = tile_expert[tile];
  const int row0 = tile_row0[tile];
  const int n0 = nb * 256;
  const int tid = threadIdx.x;
  const int w = tid >> 6, lane = tid & 63;

  __shared__ unsigned short As[3][128 * 64];
  __shared__ unsigned short Bs[3][256 * 64];
  __shared__ int tok[128];

  if (tid < 128) { int t = pair_token[row0 + tid]; tok[tid] = (t < 0) ? 0 : t; }
  __syncthreads();

  const int rg  = lane >> 3;                       // row within 8-row group
  const int swz = ((lane & 7) ^ rg) * 8;           // pre-swizzled source granule (bf16 units)
  const unsigned short* ag0 = xb + (size_t)tok[w * 16 + rg] * DIM + swz;
  const unsigned short* ag1 = xb + (size_t)tok[w * 16 + 8 + rg] * DIM + swz;
  const size_t bbase = (size_t)e * HID + n0 + w * 32;
  const unsigned short* bg0 = w1T + (bbase + rg) * DIM + swz;
  const unsigned short* bg1 = w1T + (bbase + 8 + rg) * DIM + swz;
  const unsigned short* bg2 = w1T + (bbase + 16 + rg) * DIM + swz;
  const unsigned short* bg3 = w1T + (bbase + 24 + rg) * DIM + swz;

  const int wm = (w & 1) * 64, wn = (w >> 1) * 64;
  const int lr = lane & 15, lk = lane >> 4;
  const int rs = (lr & 7);                         // read-side row-low bits

  f32x4 acc[4][4];
#pragma unroll
  for (int mi = 0; mi < 4; ++mi)
#pragma unroll
    for (int ni = 0; ni < 4; ++ni) acc[mi][ni] = {0.f, 0.f, 0.f, 0.f};

#define STAGE1(buf, koff)                                  \
  gload16(ag0 + (koff), &As[buf][(w * 16) * 64]);          \
  gload16(ag1 + (koff), &As[buf][(w * 16 + 8) * 64]);      \
  gload16(bg0 + (koff), &Bs[buf][(w * 32) * 64]);          \
  gload16(bg1 + (koff), &Bs[buf][(w * 32 + 8) * 64]);      \
  gload16(bg2 + (koff), &Bs[buf][(w * 32 + 16) * 64]);     \
  gload16(bg3 + (koff), &Bs[buf][(w * 32 + 24) * 64]);

  STAGE1(0, 0)
  STAGE1(1, 64)
  asm volatile("s_waitcnt vmcnt(6)" ::: "memory");
  __builtin_amdgcn_s_barrier();

  const int NT = DIM / 64;                         // 16
  int cur = 0, dst = 2;
  for (int t = 0; t < NT; ++t) {
    if (t + 2 < NT) { STAGE1(dst, (t + 2) * 64) }
    bf16x8 af[4][2], bfr[4][2];
#pragma unroll
    for (int mi = 0; mi < 4; ++mi)
#pragma unroll
      for (int ks = 0; ks < 2; ++ks)
        af[mi][ks] = *(const bf16x8*)&As[cur][(wm + mi * 16 + lr) * 64 + ((ks * 4 + lk) ^ rs) * 8];
#pragma unroll
    for (int ni = 0; ni < 4; ++ni)
#pragma unroll
      for (int ks = 0; ks < 2; ++ks)
        bfr[ni][ks] = *(const bf16x8*)&Bs[cur][(wn + ni * 16 + lr) * 64 + ((ks * 4 + lk) ^ rs) * 8];
    asm volatile("s_waitcnt lgkmcnt(0)" ::: "memory");
    __builtin_amdgcn_sched_barrier(0);
    __builtin_amdgcn_s_setprio(1);
#pragma unroll
    for (int mi = 0; mi < 4; ++mi)
#pragma unroll
      for (int ni = 0; ni < 4; ++ni)
#pragma unroll
        for (int ks = 0; ks < 2; ++ks)
          acc[mi][ni] = __builtin_amdgcn_mfma_f32_16x16x32_bf16(bfr[ni][ks], af[mi][ks], acc[mi][ni], 0, 0, 0);
    __builtin_amdgcn_s_setprio(0);
    if (t + 2 < NT) { asm volatile("s_waitcnt vmcnt(6)" ::: "memory"); }
    else            { asm volatile("s_waitcnt vmcnt(0)" ::: "memory"); }
    __builtin_amdgcn_s_barrier();
    cur = (cur == 2) ? 0 : cur + 1;
    dst = (dst == 2) ? 0 : dst + 1;
  }
#undef STAGE1

  const size_t tl = (size_t)(tile - chunk_base);
  f32x4 bv[4];
#pragma unroll
  for (int ni = 0; ni < 4; ++ni)
    bv[ni] = *(const f32x4*)(b1 + (size_t)e * HID + n0 + wn + ni * 16 + lk * 4);
#pragma unroll
  for (int mi = 0; mi < 4; ++mi) {
    int m = wm + mi * 16 + lr;
    unsigned short* hrow = h + (tl * TILE_M + m) * HID + n0;
#pragma unroll
    for (int ni = 0; ni < 4; ++ni) {
      int nb4 = wn + ni * 16 + lk * 4;
      ushort4 pk;
      pk.x = f2bf(gelu_fast(acc[mi][ni][0] + bv[ni][0]));
      pk.y = f2bf(gelu_fast(acc[mi][ni][1] + bv[ni][1]));
      pk.z = f2bf(gelu_fast(acc[mi][ni][2] + bv[ni][2]));
      pk.w = f2bf(gelu_fast(acc[mi][ni][3] + bv[ni][3]));
      *(ushort4*)(hrow + nb4) = pk;
    }
  }
}

// GEMM2: out[token] += gate * (h @ w2T^T + b2).  1-D grid = tpc * (DIM/256).
// Standard mfma(af, bfr, acc): n = wn+ni*16+lr (coalesced atomics), m = wm+mi*16+lk*4+r.
__global__ __launch_bounds__(512) void k_gemm2n(
    const unsigned short* __restrict__ h, const unsigned short* __restrict__ w2T,
    const float* __restrict__ b2, const int* __restrict__ pair_token,
    const float* __restrict__ pair_gate,
    const int* __restrict__ tile_expert, const int* __restrict__ tile_row0,
    const int* __restrict__ ntiles_p, float* __restrict__ out, int chunk_base)
{
  const int NBn = DIM / 256;                       // 4
  int newid = xcd_swz(blockIdx.x, gridDim.x);
  int ltile = newid / NBn, nb = newid - ltile * NBn;
  int tile = chunk_base + ltile;
  if (tile >= *ntiles_p) return;
  const int e = tile_expert[tile];
  const int row0 = tile_row0[tile];
  const int n0 = nb * 256;
  const int tid = threadIdx.x;
  const int w = tid >> 6, lane = tid & 63;

  __shared__ unsigned short As[3][128 * 64];
  __shared__ unsigned short Bs[3][256 * 64];
  __shared__ int tok[128];
  __shared__ float gat[128];

  if (tid < 128) { tok[tid] = pair_token[row0 + tid]; gat[tid] = pair_gate[row0 + tid]; }
  __syncthreads();

  const int rg  = lane >> 3;
  const int swz = ((lane & 7) ^ rg) * 8;
  const size_t tl = (size_t)(tile - chunk_base);
  const unsigned short* ag0 = h + (tl * TILE_M + w * 16 + rg) * HID + swz;
  const unsigned short* ag1 = h + (tl * TILE_M + w * 16 + 8 + rg) * HID + swz;
  const size_t bbase = (size_t)e * DIM + n0 + w * 32;
  const unsigned short* bg0 = w2T + (bbase + rg) * HID + swz;
  const unsigned short* bg1 = w2T + (bbase + 8 + rg) * HID + swz;
  const unsigned short* bg2 = w2T + (bbase + 16 + rg) * HID + swz;
  const unsigned short* bg3 = w2T + (bbase + 24 + rg) * HID + swz;

  const int wm = (w & 1) * 64, wn = (w >> 1) * 64;
  const int lr = lane & 15, lk = lane >> 4;
  const int rs = (lr & 7);

  f32x4 acc[4][4];
#pragma unroll
  for (int mi = 0; mi < 4; ++mi)
#pragma unroll
    for (int ni = 0; ni < 4; ++ni) acc[mi][ni] = {0.f, 0.f, 0.f, 0.f};

#define STAGE2(buf, koff)                                  \
  gload16(ag0 + (koff), &As[buf][(w * 16) * 64]);          \
  gload16(ag1 + (koff), &As[buf][(w * 16 + 8) * 64]);      \
  gload16(bg0 + (koff), &Bs[buf][(w * 32) * 64]);          \
  gload16(bg1 + (koff), &Bs[buf][(w * 32 + 8) * 64]);      \
  gload16(bg2 + (koff), &Bs[buf][(w * 32 + 16) * 64]);     \
  gload16(bg3 + (koff), &Bs[buf][(w * 32 + 24) * 64]);

  STAGE2(0, 0)
  STAGE2(1, 64)
  asm volatile("s_waitcnt vmcnt(6)" ::: "memory");
  __builtin_amdgcn_s_barrier();

  const int NT = HID / 64;                         // 64
  int cur = 0, dst = 2;
  for (int t = 0; t < NT; ++t) {
    if (t + 2 < NT) { STAGE2(dst, (t + 2) * 64) }
    bf16x8 af[4][2], bfr[4][2];
#pragma unroll
    for (int mi = 0; mi < 4; ++mi)
#pragma unroll
      for (int ks = 0; ks < 2; ++ks)
        af[mi][ks] = *(const bf16x8*)&As[cur][(wm + mi * 16 + lr) * 64 + ((ks * 4 + lk) ^ rs) * 8];
#pragma unroll
    for (int ni = 0; ni < 4; ++ni)
#pragma unroll
      for (int ks = 0; ks < 2; ++ks)
        bfr[ni][ks] = *(const bf16x8*)&Bs[cur][(wn + ni * 16 + lr) * 64 + ((ks * 4 + lk) ^ rs) * 8];
    asm volatile("s_waitcnt lgkmcnt(0)" ::: "memory");
    __builtin_amdgcn_sched_barrier(0);
    __builtin_amdgcn_s_setprio(1);
#pragma unroll
    for (int mi = 0; mi < 4; ++mi)
#pragma unroll
      for (int ni = 0; ni < 4; ++ni)
#pragma unroll
        for (int ks = 0; ks < 2; ++ks)
          acc[mi][ni] = __builtin_amdgcn_mfma_f32_16x16x32_bf16(af[mi][ks], bfr[ni][ks], acc[mi][ni], 0, 0, 0);
    __builtin_amdgcn_s_setprio(0);
    if (t + 2 < NT) { asm volatile("s_waitcnt vmcnt(6)" ::: "memory"); }
    else            { asm volatile("s_waitcnt vmcnt(0)" ::: "memory"); }
    __builtin_amdgcn_s_barrier();
    cur = (cur == 2) ? 0 : cur + 1;
    dst = (dst == 2) ? 0 : dst + 1;
  }
#undef STAGE2

  float bia[4];
#pragma unroll
  for (int ni = 0; ni < 4; ++ni) bia[ni] = b2[(size_t)e * DIM + n0 + wn + ni * 16 + lr];
#pragma unroll
  for (int mi = 0; mi < 4; ++mi)
#pragma unroll
    for (int r = 0; r < 4; ++r) {
      int m = wm + mi * 16 + lk * 4 + r;
      int t = tok[m];
      if (t >= 0) {
        float g = gat[m];
#pragma unroll
        for (int ni = 0; ni < 4; ++ni) {
          int n = wn + ni * 16 + lr;
          atomicAdd(out + (size_t)t * DIM + n0 + n, (acc[mi][ni][r] + bia[ni]) * g);
        }
      }
    }
}

// ================= OLD fallback GEMMs (round-1, known-good) =================
__global__ __launch_bounds__(256) void k_gemm1(
    const unsigned short* __restrict__ xb, const float* __restrict__ w1,
    const float* __restrict__ b1, const int* __restrict__ pair_token,
    const int* __restrict__ tile_expert, const int* __restrict__ tile_row0,
    const int* __restrict__ ntiles_p, unsigned short* __restrict__ h, int chunk_base)
{
  int tile = chunk_base + blockIdx.y;
  if (tile >= *ntiles_p) return;
  const int e = tile_expert[tile];
  const int row0 = tile_row0[tile];
  const int n0 = blockIdx.x * 128;
  const int tid = threadIdx.x;

  __shared__ unsigned short As[TILE_M * LDA];
  __shared__ unsigned short Bs[128 * LDB];
  __shared__ int tok[TILE_M];

  if (tid < TILE_M) tok[tid] = pair_token[row0 + tid];
  __syncthreads();

  const int ar = tid >> 1, akh = (tid & 1) * 16;
  const int bk = tid >> 3, bnh = (tid & 7) * 16;
  const int bswz = tid & 3;
  const int wv = tid >> 6, lane = tid & 63;
  const int wm = (wv & 1) * 64, wn = (wv >> 1) * 64;
  const int lr = lane & 15, lk = lane >> 4;
  const int atok = tok[ar];

  f32x4 acc[4][4];
#pragma unroll
  for (int mi = 0; mi < 4; ++mi)
#pragma unroll
    for (int ni = 0; ni < 4; ++ni) acc[mi][ni] = {0.f, 0.f, 0.f, 0.f};

  const unsigned short* asrc = (atok >= 0) ? (xb + (size_t)atok * DIM + akh) : (const unsigned short*)0;
  const float* bsrc0 = w1 + ((size_t)e * DIM + bk) * HID + n0 + bnh;
  const int wcol = 8 * ((bk >> 3) ^ bswz) + (bk & 7);

  for (int k0 = 0; k0 < DIM; k0 += BK) {
    u32x4 av0 = {0, 0, 0, 0}, av1 = {0, 0, 0, 0};
    if (asrc) {
      av0 = *(const u32x4*)(asrc + k0);
      av1 = *(const u32x4*)(asrc + k0 + 8);
    }
    float bv[16];
    const float* bs = bsrc0 + (size_t)k0 * HID;
#pragma unroll
    for (int j = 0; j < 4; ++j) {
      f32x4 f = *(const f32x4*)(bs + j * 4);
      bv[j * 4 + 0] = f[0]; bv[j * 4 + 1] = f[1];
      bv[j * 4 + 2] = f[2]; bv[j * 4 + 3] = f[3];
    }
    __syncthreads();
    *(u32x4*)&As[ar * LDA + akh] = av0;
    *(u32x4*)&As[ar * LDA + akh + 8] = av1;
#pragma unroll
    for (int j = 0; j < 16; ++j)
      Bs[(bnh + j) * LDB + wcol] = f2bf(bv[j]);
    __syncthreads();

    bf16x8 af[4], bfr[4];
#pragma unroll
    for (int mi = 0; mi < 4; ++mi)
      af[mi] = *(const bf16x8*)&As[(wm + mi * 16 + lr) * LDA + lk * 8];
#pragma unroll
    for (int ni = 0; ni < 4; ++ni) {
      int pch = lk ^ (((wn >> 4) + ni) & 3);
      bfr[ni] = *(const bf16x8*)&Bs[(wn + ni * 16 + lr) * LDB + pch * 8];
    }
#pragma unroll
    for (int mi = 0; mi < 4; ++mi)
#pragma unroll
      for (int ni = 0; ni < 4; ++ni)
        acc[mi][ni] = __builtin_amdgcn_mfma_f32_16x16x32_bf16(af[mi], bfr[ni], acc[mi][ni], 0, 0, 0);
  }

  const size_t tl = (size_t)(tile - chunk_base);
#pragma unroll
  for (int mi = 0; mi < 4; ++mi)
#pragma unroll
    for (int ni = 0; ni < 4; ++ni)
#pragma unroll
      for (int r = 0; r < 4; ++r) {
        int m = wm + mi * 16 + (lane >> 4) * 4 + r;
        int n = wn + ni * 16 + (lane & 15);
        float v = acc[mi][ni][r] + b1[(size_t)e * HID + n0 + n];
        h[(tl * TILE_M + m) * HID + n0 + n] = f2bf(gelu_f(v));
      }
}

__global__ __launch_bounds__(256) void k_gemm2(
    const unsigned short* __restrict__ h, const float* __restrict__ w2,
    const float* __restrict__ b2, const int* __restrict__ pair_token,
    const float* __restrict__ pair_gate,
    const int* __restrict__ tile_expert, const int* __restrict__ tile_row0,
    const int* __restrict__ ntiles_p, float* __restrict__ out, int chunk_base)
{
  int tile = chunk_base + blockIdx.y;
  if (tile >= *ntiles_p) return;
  const int e = tile_expert[tile];
  const int row0 = tile_row0[tile];
  const int n0 = blockIdx.x * 128;
  const int tid = threadIdx.x;

  __shared__ unsigned short As[TILE_M * LDA];
  __shared__ unsigned short Bs[128 * LDB];
  __shared__ int tok[TILE_M];
  __shared__ float gat[TILE_M];

  if (tid < TILE_M) { tok[tid] = pair_token[row0 + tid]; gat[tid] = pair_gate[row0 + tid]; }
  __syncthreads();

  const int ar = tid >> 1, akh = (tid & 1) * 16;
  const int bk = tid >> 3, bnh = (tid & 7) * 16;
  const int bswz = tid & 3;
  const int wv = tid >> 6, lane = tid & 63;
  const int wm = (wv & 1) * 64, wn = (wv >> 1) * 64;
  const int lr = lane & 15, lk = lane >> 4;

  f32x4 acc[4][4];
#pragma unroll
  for (int mi = 0; mi < 4; ++mi)
#pragma unroll
    for (int ni = 0; ni < 4; ++ni) acc[mi][ni] = {0.f, 0.f, 0.f, 0.f};

  const size_t tl = (size_t)(tile - chunk_base);
  const unsigned short* asrc = h + (tl * TILE_M + ar) * HID + akh;
  const float* bsrc0 = w2 + ((size_t)e * HID + bk) * DIM + n0 + bnh;
  const int wcol = 8 * ((bk >> 3) ^ bswz) + (bk & 7);

  for (int k0 = 0; k0 < HID; k0 += BK) {
    u32x4 av0 = *(const u32x4*)(asrc + k0);
    u32x4 av1 = *(const u32x4*)(asrc + k0 + 8);
    float bv[16];
    const float* bs = bsrc0 + (size_t)k0 * DIM;
#pragma unroll
    for (int j = 0; j < 4; ++j) {
      f32x4 f = *(const f32x4*)(bs + j * 4);
      bv[j * 4 + 0] = f[0]; bv[j * 4 + 1] = f[1];
      bv[j * 4 + 2] = f[2]; bv[j * 4 + 3] = f[3];
    }
    __syncthreads();
    *(u32x4*)&As[ar * LDA + akh] = av0;
    *(u32x4*)&As[ar * LDA + akh + 8] = av1;
#pragma unroll
    for (int j = 0; j < 16; ++j)
      Bs[(bnh + j) * LDB + wcol] = f2bf(bv[j]);
    __syncthreads();

    bf16x8 af[4], bfr[4];
#pragma unroll
    for (int mi = 0; mi < 4; ++mi)
      af[mi] = *(const bf16x8*)&As[(wm + mi * 16 + lr) * LDA + lk * 8];
#pragma unroll
    for (int ni = 0; ni < 4; ++ni) {
      int pch = lk ^ (((wn >> 4) + ni) & 3);
      bfr[ni] = *(const bf16x8*)&Bs[(wn + ni * 16 + lr) * LDB + pch * 8];
    }
#pragma unroll
    for (int mi = 0; mi < 4; ++mi)
#pragma unroll
      for (int ni = 0; ni < 4; ++ni)
        acc[mi][ni] = __builtin_amdgcn_mfma_f32_16x16x32_bf16(af[mi], bfr[ni], acc[mi][ni], 0, 0, 0);
  }

#pragma unroll
  for (int mi = 0; mi < 4; ++mi)
#pragma unroll
    for (int ni = 0; ni < 4; ++ni)
#pragma unroll
      for (int r = 0; r < 4; ++r) {
        int m = wm + mi * 16 + (lane >> 4) * 4 + r;
        int n = wn + ni * 16 + (lane & 15);
        int t = tok[m];
        if (t >= 0) {
          float v = acc[mi][ni][r] + b2[(size_t)e * DIM + n0 + n];
          atomicAdd(out + (size_t)t * DIM + n0 + n, v * gat[m]);
        }
      }
}

extern "C" void kernel_launch(void* const* d_in, const int* in_sizes, int n_in,
                              void* d_out, int out_size, void* d_ws, size_t ws_size,
                              hipStream_t stream) {
  const float* x  = (const float*)d_in[0];
  const float* wr = (const float*)d_in[1];
  const float* br = (const float*)d_in[2];
  const float* w1 = (const float*)d_in[3];
  const float* b1 = (const float*)d_in[4];
  const float* w2 = (const float*)d_in[5];
  const float* b2 = (const float*)d_in[6];
  float* out = (float*)d_out;

  char* ws = (char*)d_ws;
  int*   counts      = (int*)(ws + 0);
  int*   cursors     = (int*)(ws + 64);
  int*   ntiles      = (int*)(ws + 128);
  int*   tile_expert = (int*)(ws + 256);
  int*   tile_row0   = (int*)(ws + 1024);
  int*   sel         = (int*)(ws + 4096);
  float* gates       = (float*)(ws + 4096 + 65536);
  int*   pair_token  = (int*)(ws + 4096 + 131072);
  float* pair_gate   = (float*)(ws + 4096 + 131072 + 69632);

  const size_t OFF_XB  = 274432;
  const size_t XB_SZ   = (size_t)TOKENS * DIM * 2;           // 16 MB
  const size_t OFF_W1T = OFF_XB + XB_SZ;
  const size_t WT_SZ   = (size_t)NEXP * DIM * HID * 2;       // 67 MB each
  const size_t OFF_W2T = OFF_W1T + WT_SZ;
  const size_t OFF_HN  = OFF_W2T + WT_SZ;
  const size_t tile_bytes = (size_t)TILE_M * HID * 2;        // 1 MB

  unsigned short* xb  = (unsigned short*)(ws + OFF_XB);

  hipMemsetAsync(d_out, 0, (size_t)out_size * sizeof(float), stream);
  hipMemsetAsync(counts, 0, 64, stream);

  hipLaunchKernelGGL(k_router, dim3(TOKENS / 4), dim3(256), 0, stream,
                     x, wr, br, sel, gates, counts, xb);
  hipLaunchKernelGGL(k_setup, dim3(1), dim3(256), 0, stream,
                     counts, cursors, ntiles, tile_expert, tile_row0,
                     pair_token, pair_gate, out + (size_t)out_size - 1);
  hipLaunchKernelGGL(k_bucket, dim3(TOKENS / 256), dim3(256), 0, stream,
                     sel, gates, cursors, pair_token, pair_gate);

  bool newpath = ws_size >= OFF_HN + tile_bytes;

  if (newpath) {
    unsigned short* w1T = (unsigned short*)(ws + OFF_W1T);
    unsigned short* w2T = (unsigned short*)(ws + OFF_W2T);
    unsigned short* h   = (unsigned short*)(ws + OFF_HN);

    hipLaunchKernelGGL(k_castwT, dim3(HID / 64, DIM / 64, NEXP), dim3(256), 0, stream,
                       w1, w1T, DIM, HID);
    hipLaunchKernelGGL(k_castwT, dim3(DIM / 64, HID / 64, NEXP), dim3(256), 0, stream,
                       w2, w2T, HID, DIM);

    long long avail = (long long)ws_size - (long long)OFF_HN;
    int tpc = (int)(avail / (long long)tile_bytes);
    if (tpc < 1) tpc = 1;
    if (tpc > MAX_TILES) tpc = MAX_TILES;
    int nchunks = (MAX_TILES + tpc - 1) / tpc;

    for (int c = 0; c < nchunks; ++c) {
      hipLaunchKernelGGL(k_gemm1n, dim3(tpc * (HID / 256)), dim3(512), 0, stream,
                         xb, w1T, b1, pair_token, tile_expert, tile_row0, ntiles, h, c * tpc);
      hipLaunchKernelGGL(k_gemm2n, dim3(tpc * (DIM / 256)), dim3(512), 0, stream,
                         h, w2T, b2, pair_token, pair_gate, tile_expert, tile_row0, ntiles, out, c * tpc);
    }
  } else {
    unsigned short* h = (unsigned short*)(ws + OFF_W1T);
    long long avail = (long long)ws_size - (long long)OFF_W1T;
    int tpc = (avail > 0) ? (int)(avail / (long long)tile_bytes) : 0;
    if (tpc < 1) tpc = 1;
    if (tpc > MAX_TILES) tpc = MAX_TILES;
    int nchunks = (MAX_TILES + tpc - 1) / tpc;

    for (int c = 0; c < nchunks; ++c) {
      hipLaunchKernelGGL(k_gemm1, dim3(HID / 128, tpc), dim3(256), 0, stream,
                         xb, w1, b1, pair_token, tile_expert, tile_row0, ntiles, h, c * tpc);
      hipLaunchKernelGGL(k_gemm2, dim3(DIM / 128, tpc), dim3(256), 0, stream,
                         h, w2, b2, pair_token, pair_gate, tile_expert, tile_row0, ntiles, out, c * tpc);
    }
  }
}

// Round 8
// 903.561 us; speedup vs baseline: 1.0660x; 1.0660x over previous
//
#include <hip/hip_runtime.h>
#include <math.h>

// MoE top-2 of 8 experts, D=1024, H=4096, 8192 tokens.
// Round 8: per-wave 128x64 output (FLOP/LDS-byte 32->42.7). BM=128 token
// tiles, BN=256, BK=32, 256 thr / 4 waves (1Mx4N), 3-buffer counted-vmcnt(6)
// ring (r6-proven step shape), XOR granule swizzle (0 conflicts), 72 KB LDS
// -> 2 blocks/CU.
#define TOKENS 8192
#define DIM    1024
#define NEXP   8
#define HID    4096
#define TILE_M 128
#define MAX_TILES 136
#define BKS    32

// old-path (fallback) LDS strides
#define BK     32
#define LDA    40
#define LDB    40

typedef __bf16 bf16x8 __attribute__((ext_vector_type(8)));
typedef float  f32x4  __attribute__((ext_vector_type(4)));
typedef unsigned int u32x4 __attribute__((ext_vector_type(4)));

__device__ __forceinline__ unsigned short f2bf(float f) {
  union { float f; unsigned u; } v; v.f = f;
  unsigned u = v.u + 0x7fffu + ((v.u >> 16) & 1u);   // RNE
  return (unsigned short)(u >> 16);
}
__device__ __forceinline__ float gelu_f(float v) {
  return 0.5f * v * (1.f + erff(v * 0.7071067811865476f));
}
__device__ __forceinline__ float gelu_fast(float v) {
  float t = v * v;
  float y = 0.7978845608f * v * fmaf(t, 0.044715f, 1.0f);
  y = fminf(y, 15.f);
  float z = __expf(2.f * y);
  return v * z * __builtin_amdgcn_rcpf(1.f + z);
}
__device__ __forceinline__ void gload16(const void* g, void* l) {
  __builtin_amdgcn_global_load_lds(
      (const __attribute__((address_space(1))) void*)g,
      (__attribute__((address_space(3))) void*)l, 16, 0, 0);
}
// bijective XCD-chunked swizzle (m204)
__device__ __forceinline__ int xcd_swz(int id, int nwg) {
  int q = nwg >> 3, r = nwg & 7;
  int xcd = id & 7, rank = id >> 3;
  return (xcd < r) ? xcd * (q + 1) + rank : r * (q + 1) + (xcd - r) * q + rank;
}

// ---------------- router (+ fused x->bf16 cast): one wave per token ----------------
__global__ __launch_bounds__(256) void k_router(
    const float* __restrict__ x, const float* __restrict__ wr,
    const float* __restrict__ br, int* __restrict__ sel,
    float* __restrict__ gates, int* __restrict__ counts,
    unsigned short* __restrict__ xb)
{
  int t = blockIdx.x * 4 + (threadIdx.x >> 6);
  int lane = threadIdx.x & 63;
  const float* xr = x + (size_t)t * DIM;
  unsigned short* xo = xb + (size_t)t * DIM;
  float acc[NEXP];
#pragma unroll
  for (int e = 0; e < NEXP; ++e) acc[e] = 0.f;
#pragma unroll
  for (int it = 0; it < 4; ++it) {
    int d = it * 256 + lane * 4;
    float4 xv = *(const float4*)(xr + d);
    ushort4 pk;
    pk.x = f2bf(xv.x); pk.y = f2bf(xv.y); pk.z = f2bf(xv.z); pk.w = f2bf(xv.w);
    *(ushort4*)(xo + d) = pk;
    float xs[4] = {xv.x, xv.y, xv.z, xv.w};
#pragma unroll
    for (int j = 0; j < 4; ++j) {
      float4 wa = *(const float4*)(wr + (size_t)(d + j) * NEXP);
      float4 wb = *(const float4*)(wr + (size_t)(d + j) * NEXP + 4);
      acc[0] += xs[j] * wa.x; acc[1] += xs[j] * wa.y;
      acc[2] += xs[j] * wa.z; acc[3] += xs[j] * wa.w;
      acc[4] += xs[j] * wb.x; acc[5] += xs[j] * wb.y;
      acc[6] += xs[j] * wb.z; acc[7] += xs[j] * wb.w;
    }
  }
#pragma unroll
  for (int off = 32; off >= 1; off >>= 1) {
#pragma unroll
    for (int e = 0; e < NEXP; ++e) acc[e] += __shfl_xor(acc[e], off);
  }
  if (lane == 0) {
    float l[NEXP];
#pragma unroll
    for (int e = 0; e < NEXP; ++e) l[e] = acc[e] + br[e];
    int e1 = 0; float v1 = l[0];
#pragma unroll
    for (int e = 1; e < NEXP; ++e) if (l[e] > v1) { v1 = l[e]; e1 = e; }
    int e2 = -1; float v2 = -1e30f;
#pragma unroll
    for (int e = 0; e < NEXP; ++e) {
      if (e == e1) continue;
      if (l[e] > v2) { v2 = l[e]; e2 = e; }
    }
    float g1 = 1.f / (1.f + expf(v2 - v1));
    sel[t * 2] = e1; sel[t * 2 + 1] = e2;
    gates[t * 2] = g1; gates[t * 2 + 1] = 1.f - g1;
    atomicAdd(&counts[e1], 1);
    atomicAdd(&counts[e2], 1);
  }
}

// ---------------- setup: offsets, tile table, padding (parallel), loss ----------------
__global__ __launch_bounds__(256) void k_setup(
    const int* __restrict__ counts, int* __restrict__ cursors,
    int* __restrict__ ntiles_p, int* __restrict__ tile_expert,
    int* __restrict__ tile_row0, int* __restrict__ pair_token,
    float* __restrict__ pair_gate, float* __restrict__ loss_out)
{
  __shared__ int s_pad0[NEXP], s_pad1[NEXP];
  int tid = threadIdx.x;
  if (tid == 0) {
    int poff = 0, nt = 0;
    float var = 0.f;
    for (int e = 0; e < NEXP; ++e) {
      int c = counts[e];
      cursors[e] = poff;
      int ntl = (c + TILE_M - 1) / TILE_M;
      for (int i = 0; i < ntl; ++i) { tile_expert[nt] = e; tile_row0[nt] = poff + i * TILE_M; ++nt; }
      s_pad0[e] = poff + c;
      s_pad1[e] = poff + ntl * TILE_M;
      float d = (float)c - 2048.f;
      var += d * d;
      poff += ntl * TILE_M;
    }
    *ntiles_p = nt;
    *loss_out = (var * (1.f / 7.f)) * (1.f / 2048.f) * 0.01f;
  }
  __syncthreads();
#pragma unroll
  for (int e = 0; e < NEXP; ++e) {
    for (int r = s_pad0[e] + tid; r < s_pad1[e]; r += 256) {
      pair_token[r] = -1; pair_gate[r] = 0.f;
    }
  }
}

// ---------------- bucket: scatter pairs ----------------
__global__ __launch_bounds__(256) void k_bucket(
    const int* __restrict__ sel, const float* __restrict__ gates,
    int* __restrict__ cursors, int* __restrict__ pair_token, float* __restrict__ pair_gate)
{
  int t = blockIdx.x * 256 + threadIdx.x;
#pragma unroll
  for (int k = 0; k < 2; ++k) {
    int e = sel[t * 2 + k];
    int pos = atomicAdd(&cursors[e], 1);
    pair_token[pos] = t;
    pair_gate[pos] = gates[t * 2 + k];
  }
}

// ---------------- transpose-cast: w [E][K][N] f32 -> wT [E][N][K] bf16 ----------------
__global__ __launch_bounds__(256) void k_castwT(
    const float* __restrict__ w, unsigned short* __restrict__ wT, int K, int N)
{
  __shared__ unsigned short t[64][72];
  int e = blockIdx.z, n0 = blockIdx.x * 64, k0 = blockIdx.y * 64;
  int tid = threadIdx.x;
  int kr = tid >> 2, nc = (tid & 3) * 16;
  const float* src = w + ((size_t)e * K + k0 + kr) * N + n0 + nc;
#pragma unroll
  for (int j = 0; j < 4; ++j) {
    f32x4 v = *(const f32x4*)(src + j * 4);
#pragma unroll
    for (int q = 0; q < 4; ++q) t[nc + j * 4 + q][kr] = f2bf(v[q]);
  }
  __syncthreads();
  int nr = tid >> 2, kc = (tid & 3) * 16;
  unsigned short* dst = wT + ((size_t)e * N + n0 + nr) * K + k0 + kc;
  *(u32x4*)dst = *(const u32x4*)&t[nr][kc];
  *(u32x4*)(dst + 8) = *(const u32x4*)&t[nr][kc + 8];
}

// ========== BM128 x BN256 x BK32, 4 waves, per-wave 128x64, 3-buffer ring ==========
// Swizzle (r6): LDS[row][slot s] holds logical granule s ^ ((row>>1)&3).
// GEMM1: h = gelu(x_gathered @ w1T^T + b1).  grid = tpc * (HID/256).
// Swapped mfma(bfr, af, acc): n = wn+ni*16+lk*4+r (contiguous), m = mi*16+lr.
__global__ __launch_bounds__(256, 2) void k_gemm1n(
    const unsigned short* __restrict__ xb, const unsigned short* __restrict__ w1T,
    const float* __restrict__ b1, const int* __restrict__ pair_token,
    const int* __restrict__ tile_expert, const int* __restrict__ tile_row0,
    const int* __restrict__ ntiles_p, unsigned short* __restrict__ h, int chunk_base)
{
  const int NBn = HID / 256;                       // 16
  int newid = xcd_swz(blockIdx.x, gridDim.x);
  int ltile = newid / NBn, nb = newid - ltile * NBn;
  int tile = chunk_base + ltile;
  if (tile >= *ntiles_p) return;
  const int e = tile_expert[tile];
  const int row0 = tile_row0[tile];
  const int n0 = nb * 256;
  const int tid = threadIdx.x;
  const int w = tid >> 6, lane = tid & 63;

  __shared__ unsigned short As[3][128 * BKS];
  __shared__ unsigned short Bs[3][256 * BKS];
  __shared__ int tok[128];

  if (tid < 128) { int t = pair_token[row0 + tid]; tok[tid] = (t < 0) ? 0 : t; }
  __syncthreads();

  const int sr = lane >> 2;
  const int kq = (((lane & 3) ^ ((sr >> 1) & 3))) * 8;   // swizzled source granule
  const int ar1 = w * 32 + sr, ar2 = ar1 + 16;
  const unsigned short* ag1 = xb + (size_t)tok[ar1] * DIM + kq;
  const unsigned short* ag2 = xb + (size_t)tok[ar2] * DIM + kq;
  const size_t bbase = (size_t)e * HID + n0 + w * 64;
  const unsigned short* bg0 = w1T + (bbase + sr) * DIM + kq;
  const unsigned short* bg1 = w1T + (bbase + 16 + sr) * DIM + kq;
  const unsigned short* bg2 = w1T + (bbase + 32 + sr) * DIM + kq;
  const unsigned short* bg3 = w1T + (bbase + 48 + sr) * DIM + kq;

  const int wn = w * 64;
  const int lr = lane & 15, lk = lane >> 4;
  const int gx = lk ^ ((lr >> 1) & 3);                   // swizzled read granule

  f32x4 acc[8][4];
#pragma unroll
  for (int mi = 0; mi < 8; ++mi)
#pragma unroll
    for (int ni = 0; ni < 4; ++ni) acc[mi][ni] = {0.f, 0.f, 0.f, 0.f};

#define STAGE1(buf, koff)                                      \
  gload16(ag1 + (koff), &As[buf][(w * 32) * BKS]);             \
  gload16(ag2 + (koff), &As[buf][(w * 32 + 16) * BKS]);        \
  gload16(bg0 + (koff), &Bs[buf][(w * 64) * BKS]);             \
  gload16(bg1 + (koff), &Bs[buf][(w * 64 + 16) * BKS]);        \
  gload16(bg2 + (koff), &Bs[buf][(w * 64 + 32) * BKS]);        \
  gload16(bg3 + (koff), &Bs[buf][(w * 64 + 48) * BKS]);

  STAGE1(0, 0)
  STAGE1(1, BKS)
  asm volatile("s_waitcnt vmcnt(6)" ::: "memory");
  __builtin_amdgcn_s_barrier();

  const int NT = DIM / BKS;                        // 32
  int cur = 0, dst = 2;
  for (int t = 0; t < NT; ++t) {
    if (t + 2 < NT) { STAGE1(dst, (t + 2) * BKS) }
    bf16x8 af[8], bfr[4];
#pragma unroll
    for (int mi = 0; mi < 8; ++mi)
      af[mi] = *(const bf16x8*)&As[cur][(mi * 16 + lr) * BKS + gx * 8];
#pragma unroll
    for (int ni = 0; ni < 4; ++ni)
      bfr[ni] = *(const bf16x8*)&Bs[cur][(wn + ni * 16 + lr) * BKS + gx * 8];
    asm volatile("s_waitcnt lgkmcnt(0)" ::: "memory");
    __builtin_amdgcn_sched_barrier(0);
    __builtin_amdgcn_s_setprio(1);
#pragma unroll
    for (int mi = 0; mi < 8; ++mi)
#pragma unroll
      for (int ni = 0; ni < 4; ++ni)
        acc[mi][ni] = __builtin_amdgcn_mfma_f32_16x16x32_bf16(bfr[ni], af[mi], acc[mi][ni], 0, 0, 0);
    __builtin_amdgcn_s_setprio(0);
    if (t + 2 < NT) { asm volatile("s_waitcnt vmcnt(6)" ::: "memory"); }
    else            { asm volatile("s_waitcnt vmcnt(0)" ::: "memory"); }
    __builtin_amdgcn_s_barrier();
    cur = (cur == 2) ? 0 : cur + 1;
    dst = (dst == 2) ? 0 : dst + 1;
  }
#undef STAGE1

  const size_t tl = (size_t)(tile - chunk_base);
  f32x4 bv[4];
#pragma unroll
  for (int ni = 0; ni < 4; ++ni)
    bv[ni] = *(const f32x4*)(b1 + (size_t)e * HID + n0 + wn + ni * 16 + lk * 4);
#pragma unroll
  for (int mi = 0; mi < 8; ++mi) {
    int m = mi * 16 + lr;
    unsigned short* hrow = h + (tl * TILE_M + m) * HID + n0;
#pragma unroll
    for (int ni = 0; ni < 4; ++ni) {
      int nb4 = wn + ni * 16 + lk * 4;
      ushort4 pk;
      pk.x = f2bf(gelu_fast(acc[mi][ni][0] + bv[ni][0]));
      pk.y = f2bf(gelu_fast(acc[mi][ni][1] + bv[ni][1]));
      pk.z = f2bf(gelu_fast(acc[mi][ni][2] + bv[ni][2]));
      pk.w = f2bf(gelu_fast(acc[mi][ni][3] + bv[ni][3]));
      *(ushort4*)(hrow + nb4) = pk;
    }
  }
}

// GEMM2: out[token] += gate * (h @ w2T^T + b2).  grid = tpc * (DIM/256).
// Standard mfma(af, bfr, acc): n = wn+ni*16+lr (coalesced atomics), m = mi*16+lk*4+r.
__global__ __launch_bounds__(256, 2) void k_gemm2n(
    const unsigned short* __restrict__ h, const unsigned short* __restrict__ w2T,
    const float* __restrict__ b2, const int* __restrict__ pair_token,
    const float* __restrict__ pair_gate,
    const int* __restrict__ tile_expert, const int* __restrict__ tile_row0,
    const int* __restrict__ ntiles_p, float* __restrict__ out, int chunk_base)
{
  const int NBn = DIM / 256;                       // 4
  int newid = xcd_swz(blockIdx.x, gridDim.x);
  int ltile = newid / NBn, nb = newid - ltile * NBn;
  int tile = chunk_base + ltile;
  if (tile >= *ntiles_p) return;
  const int e = tile_expert[tile];
  const int row0 = tile_row0[tile];
  const int n0 = nb * 256;
  const int tid = threadIdx.x;
  const int w = tid >> 6, lane = tid & 63;

  __shared__ unsigned short As[3][128 * BKS];
  __shared__ unsigned short Bs[3][256 * BKS];
  __shared__ int tok[128];
  __shared__ float gat[128];

  if (tid < 128) { tok[tid] = pair_token[row0 + tid]; gat[tid] = pair_gate[row0 + tid]; }
  __syncthreads();

  const int sr = lane >> 2;
  const int kq = (((lane & 3) ^ ((sr >> 1) & 3))) * 8;
  const int ar1 = w * 32 + sr, ar2 = ar1 + 16;
  const size_t tl = (size_t)(tile - chunk_base);
  const unsigned short* ag1 = h + (tl * TILE_M + ar1) * HID + kq;
  const unsigned short* ag2 = h + (tl * TILE_M + ar2) * HID + kq;
  const size_t bbase = (size_t)e * DIM + n0 + w * 64;
  const unsigned short* bg0 = w2T + (bbase + sr) * HID + kq;
  const unsigned short* bg1 = w2T + (bbase + 16 + sr) * HID + kq;
  const unsigned short* bg2 = w2T + (bbase + 32 + sr) * HID + kq;
  const unsigned short* bg3 = w2T + (bbase + 48 + sr) * HID + kq;

  const int wn = w * 64;
  const int lr = lane & 15, lk = lane >> 4;
  const int gx = lk ^ ((lr >> 1) & 3);

  f32x4 acc[8][4];
#pragma unroll
  for (int mi = 0; mi < 8; ++mi)
#pragma unroll
    for (int ni = 0; ni < 4; ++ni) acc[mi][ni] = {0.f, 0.f, 0.f, 0.f};

#define STAGE2(buf, koff)                                      \
  gload16(ag1 + (koff), &As[buf][(w * 32) * BKS]);             \
  gload16(ag2 + (koff), &As[buf][(w * 32 + 16) * BKS]);        \
  gload16(bg0 + (koff), &Bs[buf][(w * 64) * BKS]);             \
  gload16(bg1 + (koff), &Bs[buf][(w * 64 + 16) * BKS]);        \
  gload16(bg2 + (koff), &Bs[buf][(w * 64 + 32) * BKS]);        \
  gload16(bg3 + (koff), &Bs[buf][(w * 64 + 48) * BKS]);

  STAGE2(0, 0)
  STAGE2(1, BKS)
  asm volatile("s_waitcnt vmcnt(6)" ::: "memory");
  __builtin_amdgcn_s_barrier();

  const int NT = HID / BKS;                        // 128
  int cur = 0, dst = 2;
  for (int t = 0; t < NT; ++t) {
    if (t + 2 < NT) { STAGE2(dst, (t + 2) * BKS) }
    bf16x8 af[8], bfr[4];
#pragma unroll
    for (int mi = 0; mi < 8; ++mi)
      af[mi] = *(const bf16x8*)&As[cur][(mi * 16 + lr) * BKS + gx * 8];
#pragma unroll
    for (int ni = 0; ni < 4; ++ni)
      bfr[ni] = *(const bf16x8*)&Bs[cur][(wn + ni * 16 + lr) * BKS + gx * 8];
    asm volatile("s_waitcnt lgkmcnt(0)" ::: "memory");
    __builtin_amdgcn_sched_barrier(0);
    __builtin_amdgcn_s_setprio(1);
#pragma unroll
    for (int mi = 0; mi < 8; ++mi)
#pragma unroll
      for (int ni = 0; ni < 4; ++ni)
        acc[mi][ni] = __builtin_amdgcn_mfma_f32_16x16x32_bf16(af[mi], bfr[ni], acc[mi][ni], 0, 0, 0);
    __builtin_amdgcn_s_setprio(0);
    if (t + 2 < NT) { asm volatile("s_waitcnt vmcnt(6)" ::: "memory"); }
    else            { asm volatile("s_waitcnt vmcnt(0)" ::: "memory"); }
    __builtin_amdgcn_s_barrier();
    cur = (cur == 2) ? 0 : cur + 1;
    dst = (dst == 2) ? 0 : dst + 1;
  }
#undef STAGE2

  float bia[4];
#pragma unroll
  for (int ni = 0; ni < 4; ++ni) bia[ni] = b2[(size_t)e * DIM + n0 + wn + ni * 16 + lr];
#pragma unroll
  for (int mi = 0; mi < 8; ++mi)
#pragma unroll
    for (int r = 0; r < 4; ++r) {
      int m = mi * 16 + lk * 4 + r;
      int t = tok[m];
      if (t >= 0) {
        float g = gat[m];
#pragma unroll
        for (int ni = 0; ni < 4; ++ni) {
          int n = wn + ni * 16 + lr;
          atomicAdd(out + (size_t)t * DIM + n0 + n, (acc[mi][ni][r] + bia[ni]) * g);
        }
      }
    }
}

// ================= OLD fallback GEMMs (round-1, known-good) =================
__global__ __launch_bounds__(256) void k_gemm1(
    const unsigned short* __restrict__ xb, const float* __restrict__ w1,
    const float* __restrict__ b1, const int* __restrict__ pair_token,
    const int* __restrict__ tile_expert, const int* __restrict__ tile_row0,
    const int* __restrict__ ntiles_p, unsigned short* __restrict__ h, int chunk_base)
{
  int tile = chunk_base + blockIdx.y;
  if (tile >= *ntiles_p) return;
  const int e = tile_expert[tile];
  const int row0 = tile_row0[tile];
  const int n0 = blockIdx.x * 128;
  const int tid = threadIdx.x;

  __shared__ unsigned short As[TILE_M * LDA];
  __shared__ unsigned short Bs[128 * LDB];
  __shared__ int tok[TILE_M];

  if (tid < TILE_M) tok[tid] = pair_token[row0 + tid];
  __syncthreads();

  const int ar = tid >> 1, akh = (tid & 1) * 16;
  const int bk = tid >> 3, bnh = (tid & 7) * 16;
  const int bswz = tid & 3;
  const int wv = tid >> 6, lane = tid & 63;
  const int wm = (wv & 1) * 64, wn = (wv >> 1) * 64;
  const int lr = lane & 15, lk = lane >> 4;
  const int atok = tok[ar];

  f32x4 acc[4][4];
#pragma unroll
  for (int mi = 0; mi < 4; ++mi)
#pragma unroll
    for (int ni = 0; ni < 4; ++ni) acc[mi][ni] = {0.f, 0.f, 0.f, 0.f};

  const unsigned short* asrc = (atok >= 0) ? (xb + (size_t)atok * DIM + akh) : (const unsigned short*)0;
  const float* bsrc0 = w1 + ((size_t)e * DIM + bk) * HID + n0 + bnh;
  const int wcol = 8 * ((bk >> 3) ^ bswz) + (bk & 7);

  for (int k0 = 0; k0 < DIM; k0 += BK) {
    u32x4 av0 = {0, 0, 0, 0}, av1 = {0, 0, 0, 0};
    if (asrc) {
      av0 = *(const u32x4*)(asrc + k0);
      av1 = *(const u32x4*)(asrc + k0 + 8);
    }
    float bv[16];
    const float* bs = bsrc0 + (size_t)k0 * HID;
#pragma unroll
    for (int j = 0; j < 4; ++j) {
      f32x4 f = *(const f32x4*)(bs + j * 4);
      bv[j * 4 + 0] = f[0]; bv[j * 4 + 1] = f[1];
      bv[j * 4 + 2] = f[2]; bv[j * 4 + 3] = f[3];
    }
    __syncthreads();
    *(u32x4*)&As[ar * LDA + akh] = av0;
    *(u32x4*)&As[ar * LDA + akh + 8] = av1;
#pragma unroll
    for (int j = 0; j < 16; ++j)
      Bs[(bnh + j) * LDB + wcol] = f2bf(bv[j]);
    __syncthreads();

    bf16x8 af[4], bfr[4];
#pragma unroll
    for (int mi = 0; mi < 4; ++mi)
      af[mi] = *(const bf16x8*)&As[(wm + mi * 16 + lr) * LDA + lk * 8];
#pragma unroll
    for (int ni = 0; ni < 4; ++ni) {
      int pch = lk ^ (((wn >> 4) + ni) & 3);
      bfr[ni] = *(const bf16x8*)&Bs[(wn + ni * 16 + lr) * LDB + pch * 8];
    }
#pragma unroll
    for (int mi = 0; mi < 4; ++mi)
#pragma unroll
      for (int ni = 0; ni < 4; ++ni)
        acc[mi][ni] = __builtin_amdgcn_mfma_f32_16x16x32_bf16(af[mi], bfr[ni], acc[mi][ni], 0, 0, 0);
  }

  const size_t tl = (size_t)(tile - chunk_base);
#pragma unroll
  for (int mi = 0; mi < 4; ++mi)
#pragma unroll
    for (int ni = 0; ni < 4; ++ni)
#pragma unroll
      for (int r = 0; r < 4; ++r) {
        int m = wm + mi * 16 + (lane >> 4) * 4 + r;
        int n = wn + ni * 16 + (lane & 15);
        float v = acc[mi][ni][r] + b1[(size_t)e * HID + n0 + n];
        h[(tl * TILE_M + m) * HID + n0 + n] = f2bf(gelu_f(v));
      }
}

__global__ __launch_bounds__(256) void k_gemm2(
    const unsigned short* __restrict__ h, const float* __restrict__ w2,
    const float* __restrict__ b2, const int* __restrict__ pair_token,
    const float* __restrict__ pair_gate,
    const int* __restrict__ tile_expert, const int* __restrict__ tile_row0,
    const int* __restrict__ ntiles_p, float* __restrict__ out, int chunk_base)
{
  int tile = chunk_base + blockIdx.y;
  if (tile >= *ntiles_p) return;
  const int e = tile_expert[tile];
  const int row0 = tile_row0[tile];
  const int n0 = blockIdx.x * 128;
  const int tid = threadIdx.x;

  __shared__ unsigned short As[TILE_M * LDA];
  __shared__ unsigned short Bs[128 * LDB];
  __shared__ int tok[TILE_M];
  __shared__ float gat[TILE_M];

  if (tid < TILE_M) { tok[tid] = pair_token[row0 + tid]; gat[tid] = pair_gate[row0 + tid]; }
  __syncthreads();

  const int ar = tid >> 1, akh = (tid & 1) * 16;
  const int bk = tid >> 3, bnh = (tid & 7) * 16;
  const int bswz = tid & 3;
  const int wv = tid >> 6, lane = tid & 63;
  const int wm = (wv & 1) * 64, wn = (wv >> 1) * 64;
  const int lr = lane & 15, lk = lane >> 4;

  f32x4 acc[4][4];
#pragma unroll
  for (int mi = 0; mi < 4; ++mi)
#pragma unroll
    for (int ni = 0; ni < 4; ++ni) acc[mi][ni] = {0.f, 0.f, 0.f, 0.f};

  const size_t tl = (size_t)(tile - chunk_base);
  const unsigned short* asrc = h + (tl * TILE_M + ar) * HID + akh;
  const float* bsrc0 = w2 + ((size_t)e * HID + bk) * DIM + n0 + bnh;
  const int wcol = 8 * ((bk >> 3) ^ bswz) + (bk & 7);

  for (int k0 = 0; k0 < HID; k0 += BK) {
    u32x4 av0 = *(const u32x4*)(asrc + k0);
    u32x4 av1 = *(const u32x4*)(asrc + k0 + 8);
    float bv[16];
    const float* bs = bsrc0 + (size_t)k0 * DIM;
#pragma unroll
    for (int j = 0; j < 4; ++j) {
      f32x4 f = *(const f32x4*)(bs + j * 4);
      bv[j * 4 + 0] = f[0]; bv[j * 4 + 1] = f[1];
      bv[j * 4 + 2] = f[2]; bv[j * 4 + 3] = f[3];
    }
    __syncthreads();
    *(u32x4*)&As[ar * LDA + akh] = av0;
    *(u32x4*)&As[ar * LDA + akh + 8] = av1;
#pragma unroll
    for (int j = 0; j < 16; ++j)
      Bs[(bnh + j) * LDB + wcol] = f2bf(bv[j]);
    __syncthreads();

    bf16x8 af[4], bfr[4];
#pragma unroll
    for (int mi = 0; mi < 4; ++mi)
      af[mi] = *(const bf16x8*)&As[(wm + mi * 16 + lr) * LDA + lk * 8];
#pragma unroll
    for (int ni = 0; ni < 4; ++ni) {
      int pch = lk ^ (((wn >> 4) + ni) & 3);
      bfr[ni] = *(const bf16x8*)&Bs[(wn + ni * 16 + lr) * LDB + pch * 8];
    }
#pragma unroll
    for (int mi = 0; mi < 4; ++mi)
#pragma unroll
      for (int ni = 0; ni < 4; ++ni)
        acc[mi][ni] = __builtin_amdgcn_mfma_f32_16x16x32_bf16(af[mi], bfr[ni], acc[mi][ni], 0, 0, 0);
  }

#pragma unroll
  for (int mi = 0; mi < 4; ++mi)
#pragma unroll
    for (int ni = 0; ni < 4; ++ni)
#pragma unroll
      for (int r = 0; r < 4; ++r) {
        int m = wm + mi * 16 + (lane >> 4) * 4 + r;
        int n = wn + ni * 16 + (lane & 15);
        int t = tok[m];
        if (t >= 0) {
          float v = acc[mi][ni][r] + b2[(size_t)e * DIM + n0 + n];
          atomicAdd(out + (size_t)t * DIM + n0 + n, v * gat[m]);
        }
      }
}

extern "C" void kernel_launch(void* const* d_in, const int* in_sizes, int n_in,
                              void* d_out, int out_size, void* d_ws, size_t ws_size,
                              hipStream_t stream) {
  const float* x  = (const float*)d_in[0];
  const float* wr = (const float*)d_in[1];
  const float* br = (const float*)d_in[2];
  const float* w1 = (const float*)d_in[3];
  const float* b1 = (const float*)d_in[4];
  const float* w2 = (const float*)d_in[5];
  const float* b2 = (const float*)d_in[6];
  float* out = (float*)d_out;

  char* ws = (char*)d_ws;
  int*   counts      = (int*)(ws + 0);
  int*   cursors     = (int*)(ws + 64);
  int*   ntiles      = (int*)(ws + 128);
  int*   tile_expert = (int*)(ws + 256);
  int*   tile_row0   = (int*)(ws + 1024);
  int*   sel         = (int*)(ws + 4096);
  float* gates       = (float*)(ws + 4096 + 65536);
  int*   pair_token  = (int*)(ws + 4096 + 131072);
  float* pair_gate   = (float*)(ws + 4096 + 131072 + 69632);

  const size_t OFF_XB  = 274432;
  const size_t XB_SZ   = (size_t)TOKENS * DIM * 2;           // 16 MB
  const size_t OFF_W1T = OFF_XB + XB_SZ;
  const size_t WT_SZ   = (size_t)NEXP * DIM * HID * 2;       // 67 MB each
  const size_t OFF_W2T = OFF_W1T + WT_SZ;
  const size_t OFF_HN  = OFF_W2T + WT_SZ;
  const size_t tile_bytes = (size_t)TILE_M * HID * 2;        // 1 MB

  unsigned short* xb  = (unsigned short*)(ws + OFF_XB);

  hipMemsetAsync(d_out, 0, (size_t)out_size * sizeof(float), stream);
  hipMemsetAsync(counts, 0, 64, stream);

  hipLaunchKernelGGL(k_router, dim3(TOKENS / 4), dim3(256), 0, stream,
                     x, wr, br, sel, gates, counts, xb);
  hipLaunchKernelGGL(k_setup, dim3(1), dim3(256), 0, stream,
                     counts, cursors, ntiles, tile_expert, tile_row0,
                     pair_token, pair_gate, out + (size_t)out_size - 1);
  hipLaunchKernelGGL(k_bucket, dim3(TOKENS / 256), dim3(256), 0, stream,
                     sel, gates, cursors, pair_token, pair_gate);

  bool newpath = ws_size >= OFF_HN + tile_bytes;

  if (newpath) {
    unsigned short* w1T = (unsigned short*)(ws + OFF_W1T);
    unsigned short* w2T = (unsigned short*)(ws + OFF_W2T);
    unsigned short* h   = (unsigned short*)(ws + OFF_HN);

    hipLaunchKernelGGL(k_castwT, dim3(HID / 64, DIM / 64, NEXP), dim3(256), 0, stream,
                       w1, w1T, DIM, HID);
    hipLaunchKernelGGL(k_castwT, dim3(DIM / 64, HID / 64, NEXP), dim3(256), 0, stream,
                       w2, w2T, HID, DIM);

    long long avail = (long long)ws_size - (long long)OFF_HN;
    int tpc = (int)(avail / (long long)tile_bytes);
    if (tpc < 1) tpc = 1;
    if (tpc > MAX_TILES) tpc = MAX_TILES;
    int nchunks = (MAX_TILES + tpc - 1) / tpc;

    for (int c = 0; c < nchunks; ++c) {
      hipLaunchKernelGGL(k_gemm1n, dim3(tpc * (HID / 256)), dim3(256), 0, stream,
                         xb, w1T, b1, pair_token, tile_expert, tile_row0, ntiles, h, c * tpc);
      hipLaunchKernelGGL(k_gemm2n, dim3(tpc * (DIM / 256)), dim3(256), 0, stream,
                         h, w2T, b2, pair_token, pair_gate, tile_expert, tile_row0, ntiles, out, c * tpc);
    }
  } else {
    unsigned short* h = (unsigned short*)(ws + OFF_W1T);
    long long avail = (long long)ws_size - (long long)OFF_W1T;
    int tpc = (avail > 0) ? (int)(avail / (long long)tile_bytes) : 0;
    if (tpc < 1) tpc = 1;
    if (tpc > MAX_TILES) tpc = MAX_TILES;
    int nchunks = (MAX_TILES + tpc - 1) / tpc;

    for (int c = 0; c < nchunks; ++c) {
      hipLaunchKernelGGL(k_gemm1, dim3(HID / 128, tpc), dim3(256), 0, stream,
                         xb, w1, b1, pair_token, tile_expert, tile_row0, ntiles, h, c * tpc);
      hipLaunchKernelGGL(k_gemm2, dim3(DIM / 128, tpc), dim3(256), 0, stream,
                         h, w2, b2, pair_token, pair_gate, tile_expert, tile_row0, ntiles, out, c * tpc);
    }
  }
}

// Round 9
// 829.721 us; speedup vs baseline: 1.1609x; 1.0890x over previous
//
#include <hip/hip_runtime.h>
#include <math.h>

// MoE top-2 of 8 experts, D=1024, H=4096, 8192 tokens.
// Round 9: GEMMs reverted to round-6 config (best measured). gemm2n adds
// split-K x2 (each K-half 2048 is an independent block; epilogue already
// atomicAdd so split-K is free; bias gated on kh==0). 2112 real blocks
// at 3/CU -> ~91% CU utilization vs 80%.
#define TOKENS 8192
#define DIM    1024
#define NEXP   8
#define HID    4096
#define TILE_M 128
#define MAX_TILES 136
#define BKS    32

// old-path (fallback) LDS strides
#define BK     32
#define LDA    40
#define LDB    40

typedef __bf16 bf16x8 __attribute__((ext_vector_type(8)));
typedef float  f32x4  __attribute__((ext_vector_type(4)));
typedef unsigned int u32x4 __attribute__((ext_vector_type(4)));

__device__ __forceinline__ unsigned short f2bf(float f) {
  union { float f; unsigned u; } v; v.f = f;
  unsigned u = v.u + 0x7fffu + ((v.u >> 16) & 1u);   // RNE
  return (unsigned short)(u >> 16);
}
__device__ __forceinline__ float gelu_f(float v) {
  return 0.5f * v * (1.f + erff(v * 0.7071067811865476f));
}
__device__ __forceinline__ float gelu_fast(float v) {
  float t = v * v;
  float y = 0.7978845608f * v * fmaf(t, 0.044715f, 1.0f);
  y = fminf(y, 15.f);
  float z = __expf(2.f * y);
  return v * z * __builtin_amdgcn_rcpf(1.f + z);
}
__device__ __forceinline__ void gload16(const void* g, void* l) {
  __builtin_amdgcn_global_load_lds(
      (const __attribute__((address_space(1))) void*)g,
      (__attribute__((address_space(3))) void*)l, 16, 0, 0);
}
// bijective XCD-chunked swizzle (m204)
__device__ __forceinline__ int xcd_swz(int id, int nwg) {
  int q = nwg >> 3, r = nwg & 7;
  int xcd = id & 7, rank = id >> 3;
  return (xcd < r) ? xcd * (q + 1) + rank : r * (q + 1) + (xcd - r) * q + rank;
}

// ---------------- router (+ fused x->bf16 cast): one wave per token ----------------
__global__ __launch_bounds__(256) void k_router(
    const float* __restrict__ x, const float* __restrict__ wr,
    const float* __restrict__ br, int* __restrict__ sel,
    float* __restrict__ gates, int* __restrict__ counts,
    unsigned short* __restrict__ xb)
{
  int t = blockIdx.x * 4 + (threadIdx.x >> 6);
  int lane = threadIdx.x & 63;
  const float* xr = x + (size_t)t * DIM;
  unsigned short* xo = xb + (size_t)t * DIM;
  float acc[NEXP];
#pragma unroll
  for (int e = 0; e < NEXP; ++e) acc[e] = 0.f;
#pragma unroll
  for (int it = 0; it < 4; ++it) {
    int d = it * 256 + lane * 4;
    float4 xv = *(const float4*)(xr + d);
    ushort4 pk;
    pk.x = f2bf(xv.x); pk.y = f2bf(xv.y); pk.z = f2bf(xv.z); pk.w = f2bf(xv.w);
    *(ushort4*)(xo + d) = pk;
    float xs[4] = {xv.x, xv.y, xv.z, xv.w};
#pragma unroll
    for (int j = 0; j < 4; ++j) {
      float4 wa = *(const float4*)(wr + (size_t)(d + j) * NEXP);
      float4 wb = *(const float4*)(wr + (size_t)(d + j) * NEXP + 4);
      acc[0] += xs[j] * wa.x; acc[1] += xs[j] * wa.y;
      acc[2] += xs[j] * wa.z; acc[3] += xs[j] * wa.w;
      acc[4] += xs[j] * wb.x; acc[5] += xs[j] * wb.y;
      acc[6] += xs[j] * wb.z; acc[7] += xs[j] * wb.w;
    }
  }
#pragma unroll
  for (int off = 32; off >= 1; off >>= 1) {
#pragma unroll
    for (int e = 0; e < NEXP; ++e) acc[e] += __shfl_xor(acc[e], off);
  }
  if (lane == 0) {
    float l[NEXP];
#pragma unroll
    for (int e = 0; e < NEXP; ++e) l[e] = acc[e] + br[e];
    int e1 = 0; float v1 = l[0];
#pragma unroll
    for (int e = 1; e < NEXP; ++e) if (l[e] > v1) { v1 = l[e]; e1 = e; }
    int e2 = -1; float v2 = -1e30f;
#pragma unroll
    for (int e = 0; e < NEXP; ++e) {
      if (e == e1) continue;
      if (l[e] > v2) { v2 = l[e]; e2 = e; }
    }
    float g1 = 1.f / (1.f + expf(v2 - v1));
    sel[t * 2] = e1; sel[t * 2 + 1] = e2;
    gates[t * 2] = g1; gates[t * 2 + 1] = 1.f - g1;
    atomicAdd(&counts[e1], 1);
    atomicAdd(&counts[e2], 1);
  }
}

// ---------------- setup: offsets, tile table, padding (parallel), loss ----------------
__global__ __launch_bounds__(256) void k_setup(
    const int* __restrict__ counts, int* __restrict__ cursors,
    int* __restrict__ ntiles_p, int* __restrict__ tile_expert,
    int* __restrict__ tile_row0, int* __restrict__ pair_token,
    float* __restrict__ pair_gate, float* __restrict__ loss_out)
{
  __shared__ int s_pad0[NEXP], s_pad1[NEXP];
  int tid = threadIdx.x;
  if (tid == 0) {
    int poff = 0, nt = 0;
    float var = 0.f;
    for (int e = 0; e < NEXP; ++e) {
      int c = counts[e];
      cursors[e] = poff;
      int ntl = (c + TILE_M - 1) / TILE_M;
      for (int i = 0; i < ntl; ++i) { tile_expert[nt] = e; tile_row0[nt] = poff + i * TILE_M; ++nt; }
      s_pad0[e] = poff + c;
      s_pad1[e] = poff + ntl * TILE_M;
      float d = (float)c - 2048.f;
      var += d * d;
      poff += ntl * TILE_M;
    }
    *ntiles_p = nt;
    *loss_out = (var * (1.f / 7.f)) * (1.f / 2048.f) * 0.01f;
  }
  __syncthreads();
#pragma unroll
  for (int e = 0; e < NEXP; ++e) {
    for (int r = s_pad0[e] + tid; r < s_pad1[e]; r += 256) {
      pair_token[r] = -1; pair_gate[r] = 0.f;
    }
  }
}

// ---------------- bucket: scatter pairs ----------------
__global__ __launch_bounds__(256) void k_bucket(
    const int* __restrict__ sel, const float* __restrict__ gates,
    int* __restrict__ cursors, int* __restrict__ pair_token, float* __restrict__ pair_gate)
{
  int t = blockIdx.x * 256 + threadIdx.x;
#pragma unroll
  for (int k = 0; k < 2; ++k) {
    int e = sel[t * 2 + k];
    int pos = atomicAdd(&cursors[e], 1);
    pair_token[pos] = t;
    pair_gate[pos] = gates[t * 2 + k];
  }
}

// ---------------- transpose-cast: w [E][K][N] f32 -> wT [E][N][K] bf16 ----------------
__global__ __launch_bounds__(256) void k_castwT(
    const float* __restrict__ w, unsigned short* __restrict__ wT, int K, int N)
{
  __shared__ unsigned short t[64][72];
  int e = blockIdx.z, n0 = blockIdx.x * 64, k0 = blockIdx.y * 64;
  int tid = threadIdx.x;
  int kr = tid >> 2, nc = (tid & 3) * 16;
  const float* src = w + ((size_t)e * K + k0 + kr) * N + n0 + nc;
#pragma unroll
  for (int j = 0; j < 4; ++j) {
    f32x4 v = *(const f32x4*)(src + j * 4);
#pragma unroll
    for (int q = 0; q < 4; ++q) t[nc + j * 4 + q][kr] = f2bf(v[q]);
  }
  __syncthreads();
  int nr = tid >> 2, kc = (tid & 3) * 16;
  unsigned short* dst = wT + ((size_t)e * N + n0 + nr) * K + k0 + kc;
  *(u32x4*)dst = *(const u32x4*)&t[nr][kc];
  *(u32x4*)(dst + 8) = *(const u32x4*)&t[nr][kc + 8];
}

// ================= 3-buffer counted-vmcnt GEMMs (T2-swizzled LDS, r6 config) =================
// Swizzle: LDS[row][granule g] holds logical granule g ^ ((row>>1)&3).
//  - write side (linear gload dest): source granule = (lane&3) ^ ((sr>>1)&3)
//  - read side: granule = lk ^ ((lr>>1)&3)   (lane-constant)
// GEMM1: h = gelu(x_gathered @ w1T^T + b1).  1-D grid = tpc * (HID/128).
__global__ __launch_bounds__(256) void k_gemm1n(
    const unsigned short* __restrict__ xb, const unsigned short* __restrict__ w1T,
    const float* __restrict__ b1, const int* __restrict__ pair_token,
    const int* __restrict__ tile_expert, const int* __restrict__ tile_row0,
    const int* __restrict__ ntiles_p, unsigned short* __restrict__ h, int chunk_base)
{
  const int NBn = HID / 128;                       // 32
  const int nwg = gridDim.x;
  int newid = xcd_swz(blockIdx.x, nwg);
  int ltile = newid / NBn, nb = newid - ltile * NBn;
  int tile = chunk_base + ltile;
  if (tile >= *ntiles_p) return;
  const int e = tile_expert[tile];
  const int row0 = tile_row0[tile];
  const int n0 = nb * 128;
  const int tid = threadIdx.x;
  const int w = tid >> 6, lane = tid & 63;

  __shared__ unsigned short As[3][128 * BKS];
  __shared__ unsigned short Bs[3][128 * BKS];
  __shared__ int tok[128];

  if (tid < 128) { int t = pair_token[row0 + tid]; tok[tid] = (t < 0) ? 0 : t; }
  __syncthreads();

  const int sr = lane >> 2;
  const int kq = (((lane & 3) ^ ((sr >> 1) & 3))) * 8;   // swizzled source granule
  const int ar1 = w * 32 + sr, ar2 = ar1 + 16;
  const unsigned short* ag1 = xb + (size_t)tok[ar1] * DIM + kq;
  const unsigned short* ag2 = xb + (size_t)tok[ar2] * DIM + kq;
  const unsigned short* bg1 = w1T + ((size_t)e * HID + n0 + ar1) * DIM + kq;
  const unsigned short* bg2 = w1T + ((size_t)e * HID + n0 + ar2) * DIM + kq;

  const int wm = (w & 1) * 64, wn = (w >> 1) * 64;
  const int lr = lane & 15, lk = lane >> 4;
  const int gx = lk ^ ((lr >> 1) & 3);                   // swizzled read granule

  f32x4 acc[4][4];
#pragma unroll
  for (int mi = 0; mi < 4; ++mi)
#pragma unroll
    for (int ni = 0; ni < 4; ++ni) acc[mi][ni] = {0.f, 0.f, 0.f, 0.f};

#define STAGE1(buf, koff)                                      \
  gload16(ag1 + (koff), &As[buf][(w * 32) * BKS]);             \
  gload16(ag2 + (koff), &As[buf][(w * 32 + 16) * BKS]);        \
  gload16(bg1 + (koff), &Bs[buf][(w * 32) * BKS]);             \
  gload16(bg2 + (koff), &Bs[buf][(w * 32 + 16) * BKS]);

  STAGE1(0, 0)
  STAGE1(1, BKS)
  asm volatile("s_waitcnt vmcnt(4)" ::: "memory");
  __builtin_amdgcn_s_barrier();

  const int NT = DIM / BKS;                        // 32
  int cur = 0, dst = 2;
  for (int t = 0; t < NT; ++t) {
    if (t + 2 < NT) { STAGE1(dst, (t + 2) * BKS) }
    bf16x8 af[4], bfr[4];
#pragma unroll
    for (int mi = 0; mi < 4; ++mi)
      af[mi] = *(const bf16x8*)&As[cur][(wm + mi * 16 + lr) * BKS + gx * 8];
#pragma unroll
    for (int ni = 0; ni < 4; ++ni)
      bfr[ni] = *(const bf16x8*)&Bs[cur][(wn + ni * 16 + lr) * BKS + gx * 8];
    asm volatile("s_waitcnt lgkmcnt(0)" ::: "memory");
    __builtin_amdgcn_sched_barrier(0);
    __builtin_amdgcn_s_setprio(1);
#pragma unroll
    for (int mi = 0; mi < 4; ++mi)
#pragma unroll
      for (int ni = 0; ni < 4; ++ni)
        acc[mi][ni] = __builtin_amdgcn_mfma_f32_16x16x32_bf16(bfr[ni], af[mi], acc[mi][ni], 0, 0, 0);
    __builtin_amdgcn_s_setprio(0);
    if (t + 2 < NT) { asm volatile("s_waitcnt vmcnt(4)" ::: "memory"); }
    else            { asm volatile("s_waitcnt vmcnt(0)" ::: "memory"); }
    __builtin_amdgcn_s_barrier();
    cur = (cur == 2) ? 0 : cur + 1;
    dst = (dst == 2) ? 0 : dst + 1;
  }
#undef STAGE1

  const size_t tl = (size_t)(tile - chunk_base);
  f32x4 bv[4];
#pragma unroll
  for (int ni = 0; ni < 4; ++ni)
    bv[ni] = *(const f32x4*)(b1 + (size_t)e * HID + n0 + wn + ni * 16 + lk * 4);
#pragma unroll
  for (int mi = 0; mi < 4; ++mi) {
    int m = wm + mi * 16 + lr;
    unsigned short* hrow = h + (tl * TILE_M + m) * HID + n0;
#pragma unroll
    for (int ni = 0; ni < 4; ++ni) {
      int nb4 = wn + ni * 16 + lk * 4;
      ushort4 pk;
      pk.x = f2bf(gelu_fast(acc[mi][ni][0] + bv[ni][0]));
      pk.y = f2bf(gelu_fast(acc[mi][ni][1] + bv[ni][1]));
      pk.z = f2bf(gelu_fast(acc[mi][ni][2] + bv[ni][2]));
      pk.w = f2bf(gelu_fast(acc[mi][ni][3] + bv[ni][3]));
      *(ushort4*)(hrow + nb4) = pk;
    }
  }
}

// GEMM2: out[token] += gate * (h @ w2T^T + b2).  Split-K x2.
// 1-D grid = tpc * (DIM/128) * 2; newid decomposed kh-fastest so a tile's
// 16 blocks stay in one XCD chunk.
__global__ __launch_bounds__(256) void k_gemm2n(
    const unsigned short* __restrict__ h, const unsigned short* __restrict__ w2T,
    const float* __restrict__ b2, const int* __restrict__ pair_token,
    const float* __restrict__ pair_gate,
    const int* __restrict__ tile_expert, const int* __restrict__ tile_row0,
    const int* __restrict__ ntiles_p, float* __restrict__ out, int chunk_base)
{
  const int NBn = DIM / 128;                       // 8
  const int nwg = gridDim.x;
  int newid = xcd_swz(blockIdx.x, nwg);
  int kh    = newid & 1;
  int rest  = newid >> 1;
  int ltile = rest / NBn, nb = rest - ltile * NBn;
  int tile = chunk_base + ltile;
  if (tile >= *ntiles_p) return;
  const int e = tile_expert[tile];
  const int row0 = tile_row0[tile];
  const int n0 = nb * 128;
  const int kbase = kh * (HID / 2);                // 0 or 2048
  const int tid = threadIdx.x;
  const int w = tid >> 6, lane = tid & 63;

  __shared__ unsigned short As[3][128 * BKS];
  __shared__ unsigned short Bs[3][128 * BKS];
  __shared__ int tok[128];
  __shared__ float gat[128];

  if (tid < 128) { tok[tid] = pair_token[row0 + tid]; gat[tid] = pair_gate[row0 + tid]; }
  __syncthreads();

  const int sr = lane >> 2;
  const int kq = (((lane & 3) ^ ((sr >> 1) & 3))) * 8;   // swizzled source granule
  const int ar1 = w * 32 + sr, ar2 = ar1 + 16;
  const size_t tl = (size_t)(tile - chunk_base);
  const unsigned short* ag1 = h + (tl * TILE_M + ar1) * HID + kbase + kq;
  const unsigned short* ag2 = h + (tl * TILE_M + ar2) * HID + kbase + kq;
  const unsigned short* bg1 = w2T + ((size_t)e * DIM + n0 + ar1) * HID + kbase + kq;
  const unsigned short* bg2 = w2T + ((size_t)e * DIM + n0 + ar2) * HID + kbase + kq;

  const int wm = (w & 1) * 64, wn = (w >> 1) * 64;
  const int lr = lane & 15, lk = lane >> 4;
  const int gx = lk ^ ((lr >> 1) & 3);                   // swizzled read granule

  f32x4 acc[4][4];
#pragma unroll
  for (int mi = 0; mi < 4; ++mi)
#pragma unroll
    for (int ni = 0; ni < 4; ++ni) acc[mi][ni] = {0.f, 0.f, 0.f, 0.f};

#define STAGE2(buf, koff)                                      \
  gload16(ag1 + (koff), &As[buf][(w * 32) * BKS]);             \
  gload16(ag2 + (koff), &As[buf][(w * 32 + 16) * BKS]);        \
  gload16(bg1 + (koff), &Bs[buf][(w * 32) * BKS]);             \
  gload16(bg2 + (koff), &Bs[buf][(w * 32 + 16) * BKS]);

  STAGE2(0, 0)
  STAGE2(1, BKS)
  asm volatile("s_waitcnt vmcnt(4)" ::: "memory");
  __builtin_amdgcn_s_barrier();

  const int NT = (HID / 2) / BKS;                  // 64
  int cur = 0, dst = 2;
  for (int t = 0; t < NT; ++t) {
    if (t + 2 < NT) { STAGE2(dst, (t + 2) * BKS) }
    bf16x8 af[4], bfr[4];
#pragma unroll
    for (int mi = 0; mi < 4; ++mi)
      af[mi] = *(const bf16x8*)&As[cur][(wm + mi * 16 + lr) * BKS + gx * 8];
#pragma unroll
    for (int ni = 0; ni < 4; ++ni)
      bfr[ni] = *(const bf16x8*)&Bs[cur][(wn + ni * 16 + lr) * BKS + gx * 8];
    asm volatile("s_waitcnt lgkmcnt(0)" ::: "memory");
    __builtin_amdgcn_sched_barrier(0);
    __builtin_amdgcn_s_setprio(1);
#pragma unroll
    for (int mi = 0; mi < 4; ++mi)
#pragma unroll
      for (int ni = 0; ni < 4; ++ni)
        acc[mi][ni] = __builtin_amdgcn_mfma_f32_16x16x32_bf16(af[mi], bfr[ni], acc[mi][ni], 0, 0, 0);
    __builtin_amdgcn_s_setprio(0);
    if (t + 2 < NT) { asm volatile("s_waitcnt vmcnt(4)" ::: "memory"); }
    else            { asm volatile("s_waitcnt vmcnt(0)" ::: "memory"); }
    __builtin_amdgcn_s_barrier();
    cur = (cur == 2) ? 0 : cur + 1;
    dst = (dst == 2) ? 0 : dst + 1;
  }
#undef STAGE2

  float bia[4];
#pragma unroll
  for (int ni = 0; ni < 4; ++ni)
    bia[ni] = (kh == 0) ? b2[(size_t)e * DIM + n0 + wn + ni * 16 + lr] : 0.f;
#pragma unroll
  for (int mi = 0; mi < 4; ++mi)
#pragma unroll
    for (int r = 0; r < 4; ++r) {
      int m = wm + mi * 16 + lk * 4 + r;
      int t = tok[m];
      if (t >= 0) {
        float g = gat[m];
#pragma unroll
        for (int ni = 0; ni < 4; ++ni) {
          int n = wn + ni * 16 + lr;
          atomicAdd(out + (size_t)t * DIM + n0 + n, (acc[mi][ni][r] + bia[ni]) * g);
        }
      }
    }
}

// ================= OLD fallback GEMMs (round-1, known-good) =================
__global__ __launch_bounds__(256) void k_gemm1(
    const unsigned short* __restrict__ xb, const float* __restrict__ w1,
    const float* __restrict__ b1, const int* __restrict__ pair_token,
    const int* __restrict__ tile_expert, const int* __restrict__ tile_row0,
    const int* __restrict__ ntiles_p, unsigned short* __restrict__ h, int chunk_base)
{
  int tile = chunk_base + blockIdx.y;
  if (tile >= *ntiles_p) return;
  const int e = tile_expert[tile];
  const int row0 = tile_row0[tile];
  const int n0 = blockIdx.x * 128;
  const int tid = threadIdx.x;

  __shared__ unsigned short As[TILE_M * LDA];
  __shared__ unsigned short Bs[128 * LDB];
  __shared__ int tok[TILE_M];

  if (tid < TILE_M) tok[tid] = pair_token[row0 + tid];
  __syncthreads();

  const int ar = tid >> 1, akh = (tid & 1) * 16;
  const int bk = tid >> 3, bnh = (tid & 7) * 16;
  const int bswz = tid & 3;
  const int wv = tid >> 6, lane = tid & 63;
  const int wm = (wv & 1) * 64, wn = (wv >> 1) * 64;
  const int lr = lane & 15, lk = lane >> 4;
  const int atok = tok[ar];

  f32x4 acc[4][4];
#pragma unroll
  for (int mi = 0; mi < 4; ++mi)
#pragma unroll
    for (int ni = 0; ni < 4; ++ni) acc[mi][ni] = {0.f, 0.f, 0.f, 0.f};

  const unsigned short* asrc = (atok >= 0) ? (xb + (size_t)atok * DIM + akh) : (const unsigned short*)0;
  const float* bsrc0 = w1 + ((size_t)e * DIM + bk) * HID + n0 + bnh;
  const int wcol = 8 * ((bk >> 3) ^ bswz) + (bk & 7);

  for (int k0 = 0; k0 < DIM; k0 += BK) {
    u32x4 av0 = {0, 0, 0, 0}, av1 = {0, 0, 0, 0};
    if (asrc) {
      av0 = *(const u32x4*)(asrc + k0);
      av1 = *(const u32x4*)(asrc + k0 + 8);
    }
    float bv[16];
    const float* bs = bsrc0 + (size_t)k0 * HID;
#pragma unroll
    for (int j = 0; j < 4; ++j) {
      f32x4 f = *(const f32x4*)(bs + j * 4);
      bv[j * 4 + 0] = f[0]; bv[j * 4 + 1] = f[1];
      bv[j * 4 + 2] = f[2]; bv[j * 4 + 3] = f[3];
    }
    __syncthreads();
    *(u32x4*)&As[ar * LDA + akh] = av0;
    *(u32x4*)&As[ar * LDA + akh + 8] = av1;
#pragma unroll
    for (int j = 0; j < 16; ++j)
      Bs[(bnh + j) * LDB + wcol] = f2bf(bv[j]);
    __syncthreads();

    bf16x8 af[4], bfr[4];
#pragma unroll
    for (int mi = 0; mi < 4; ++mi)
      af[mi] = *(const bf16x8*)&As[(wm + mi * 16 + lr) * LDA + lk * 8];
#pragma unroll
    for (int ni = 0; ni < 4; ++ni) {
      int pch = lk ^ (((wn >> 4) + ni) & 3);
      bfr[ni] = *(const bf16x8*)&Bs[(wn + ni * 16 + lr) * LDB + pch * 8];
    }
#pragma unroll
    for (int mi = 0; mi < 4; ++mi)
#pragma unroll
      for (int ni = 0; ni < 4; ++ni)
        acc[mi][ni] = __builtin_amdgcn_mfma_f32_16x16x32_bf16(af[mi], bfr[ni], acc[mi][ni], 0, 0, 0);
  }

  const size_t tl = (size_t)(tile - chunk_base);
#pragma unroll
  for (int mi = 0; mi < 4; ++mi)
#pragma unroll
    for (int ni = 0; ni < 4; ++ni)
#pragma unroll
      for (int r = 0; r < 4; ++r) {
        int m = wm + mi * 16 + (lane >> 4) * 4 + r;
        int n = wn + ni * 16 + (lane & 15);
        float v = acc[mi][ni][r] + b1[(size_t)e * HID + n0 + n];
        h[(tl * TILE_M + m) * HID + n0 + n] = f2bf(gelu_f(v));
      }
}

__global__ __launch_bounds__(256) void k_gemm2(
    const unsigned short* __restrict__ h, const float* __restrict__ w2,
    const float* __restrict__ b2, const int* __restrict__ pair_token,
    const float* __restrict__ pair_gate,
    const int* __restrict__ tile_expert, const int* __restrict__ tile_row0,
    const int* __restrict__ ntiles_p, float* __restrict__ out, int chunk_base)
{
  int tile = chunk_base + blockIdx.y;
  if (tile >= *ntiles_p) return;
  const int e = tile_expert[tile];
  const int row0 = tile_row0[tile];
  const int n0 = blockIdx.x * 128;
  const int tid = threadIdx.x;

  __shared__ unsigned short As[TILE_M * LDA];
  __shared__ unsigned short Bs[128 * LDB];
  __shared__ int tok[TILE_M];
  __shared__ float gat[TILE_M];

  if (tid < TILE_M) { tok[tid] = pair_token[row0 + tid]; gat[tid] = pair_gate[row0 + tid]; }
  __syncthreads();

  const int ar = tid >> 1, akh = (tid & 1) * 16;
  const int bk = tid >> 3, bnh = (tid & 7) * 16;
  const int bswz = tid & 3;
  const int wv = tid >> 6, lane = tid & 63;
  const int wm = (wv & 1) * 64, wn = (wv >> 1) * 64;
  const int lr = lane & 15, lk = lane >> 4;

  f32x4 acc[4][4];
#pragma unroll
  for (int mi = 0; mi < 4; ++mi)
#pragma unroll
    for (int ni = 0; ni < 4; ++ni) acc[mi][ni] = {0.f, 0.f, 0.f, 0.f};

  const size_t tl = (size_t)(tile - chunk_base);
  const unsigned short* asrc = h + (tl * TILE_M + ar) * HID + akh;
  const float* bsrc0 = w2 + ((size_t)e * HID + bk) * DIM + n0 + bnh;
  const int wcol = 8 * ((bk >> 3) ^ bswz) + (bk & 7);

  for (int k0 = 0; k0 < HID; k0 += BK) {
    u32x4 av0 = *(const u32x4*)(asrc + k0);
    u32x4 av1 = *(const u32x4*)(asrc + k0 + 8);
    float bv[16];
    const float* bs = bsrc0 + (size_t)k0 * DIM;
#pragma unroll
    for (int j = 0; j < 4; ++j) {
      f32x4 f = *(const f32x4*)(bs + j * 4);
      bv[j * 4 + 0] = f[0]; bv[j * 4 + 1] = f[1];
      bv[j * 4 + 2] = f[2]; bv[j * 4 + 3] = f[3];
    }
    __syncthreads();
    *(u32x4*)&As[ar * LDA + akh] = av0;
    *(u32x4*)&As[ar * LDA + akh + 8] = av1;
#pragma unroll
    for (int j = 0; j < 16; ++j)
      Bs[(bnh + j) * LDB + wcol] = f2bf(bv[j]);
    __syncthreads();

    bf16x8 af[4], bfr[4];
#pragma unroll
    for (int mi = 0; mi < 4; ++mi)
      af[mi] = *(const bf16x8*)&As[(wm + mi * 16 + lr) * LDA + lk * 8];
#pragma unroll
    for (int ni = 0; ni < 4; ++ni) {
      int pch = lk ^ (((wn >> 4) + ni) & 3);
      bfr[ni] = *(const bf16x8*)&Bs[(wn + ni * 16 + lr) * LDB + pch * 8];
    }
#pragma unroll
    for (int mi = 0; mi < 4; ++mi)
#pragma unroll
      for (int ni = 0; ni < 4; ++ni)
        acc[mi][ni] = __builtin_amdgcn_mfma_f32_16x16x32_bf16(af[mi], bfr[ni], acc[mi][ni], 0, 0, 0);
  }

#pragma unroll
  for (int mi = 0; mi < 4; ++mi)
#pragma unroll
    for (int ni = 0; ni < 4; ++ni)
#pragma unroll
      for (int r = 0; r < 4; ++r) {
        int m = wm + mi * 16 + (lane >> 4) * 4 + r;
        int n = wn + ni * 16 + (lane & 15);
        int t = tok[m];
        if (t >= 0) {
          float v = acc[mi][ni][r] + b2[(size_t)e * DIM + n0 + n];
          atomicAdd(out + (size_t)t * DIM + n0 + n, v * gat[m]);
        }
      }
}

extern "C" void kernel_launch(void* const* d_in, const int* in_sizes, int n_in,
                              void* d_out, int out_size, void* d_ws, size_t ws_size,
                              hipStream_t stream) {
  const float* x  = (const float*)d_in[0];
  const float* wr = (const float*)d_in[1];
  const float* br = (const float*)d_in[2];
  const float* w1 = (const float*)d_in[3];
  const float* b1 = (const float*)d_in[4];
  const float* w2 = (const float*)d_in[5];
  const float* b2 = (const float*)d_in[6];
  float* out = (float*)d_out;

  char* ws = (char*)d_ws;
  int*   counts      = (int*)(ws + 0);
  int*   cursors     = (int*)(ws + 64);
  int*   ntiles      = (int*)(ws + 128);
  int*   tile_expert = (int*)(ws + 256);
  int*   tile_row0   = (int*)(ws + 1024);
  int*   sel         = (int*)(ws + 4096);
  float* gates       = (float*)(ws + 4096 + 65536);
  int*   pair_token  = (int*)(ws + 4096 + 131072);
  float* pair_gate   = (float*)(ws + 4096 + 131072 + 69632);

  const size_t OFF_XB  = 274432;
  const size_t XB_SZ   = (size_t)TOKENS * DIM * 2;           // 16 MB
  const size_t OFF_W1T = OFF_XB + XB_SZ;
  const size_t WT_SZ   = (size_t)NEXP * DIM * HID * 2;       // 67 MB each
  const size_t OFF_W2T = OFF_W1T + WT_SZ;
  const size_t OFF_HN  = OFF_W2T + WT_SZ;
  const size_t tile_bytes = (size_t)TILE_M * HID * 2;        // 1 MB

  unsigned short* xb  = (unsigned short*)(ws + OFF_XB);

  hipMemsetAsync(d_out, 0, (size_t)out_size * sizeof(float), stream);
  hipMemsetAsync(counts, 0, 64, stream);

  hipLaunchKernelGGL(k_router, dim3(TOKENS / 4), dim3(256), 0, stream,
                     x, wr, br, sel, gates, counts, xb);
  hipLaunchKernelGGL(k_setup, dim3(1), dim3(256), 0, stream,
                     counts, cursors, ntiles, tile_expert, tile_row0,
                     pair_token, pair_gate, out + (size_t)out_size - 1);
  hipLaunchKernelGGL(k_bucket, dim3(TOKENS / 256), dim3(256), 0, stream,
                     sel, gates, cursors, pair_token, pair_gate);

  bool newpath = ws_size >= OFF_HN + tile_bytes;

  if (newpath) {
    unsigned short* w1T = (unsigned short*)(ws + OFF_W1T);
    unsigned short* w2T = (unsigned short*)(ws + OFF_W2T);
    unsigned short* h   = (unsigned short*)(ws + OFF_HN);

    hipLaunchKernelGGL(k_castwT, dim3(HID / 64, DIM / 64, NEXP), dim3(256), 0, stream,
                       w1, w1T, DIM, HID);
    hipLaunchKernelGGL(k_castwT, dim3(DIM / 64, HID / 64, NEXP), dim3(256), 0, stream,
                       w2, w2T, HID, DIM);

    long long avail = (long long)ws_size - (long long)OFF_HN;
    int tpc = (int)(avail / (long long)tile_bytes);
    if (tpc < 1) tpc = 1;
    if (tpc > MAX_TILES) tpc = MAX_TILES;
    int nchunks = (MAX_TILES + tpc - 1) / tpc;

    for (int c = 0; c < nchunks; ++c) {
      hipLaunchKernelGGL(k_gemm1n, dim3(tpc * (HID / 128)), dim3(256), 0, stream,
                         xb, w1T, b1, pair_token, tile_expert, tile_row0, ntiles, h, c * tpc);
      hipLaunchKernelGGL(k_gemm2n, dim3(tpc * (DIM / 128) * 2), dim3(256), 0, stream,
                         h, w2T, b2, pair_token, pair_gate, tile_expert, tile_row0, ntiles, out, c * tpc);
    }
  } else {
    unsigned short* h = (unsigned short*)(ws + OFF_W1T);
    long long avail = (long long)ws_size - (long long)OFF_W1T;
    int tpc = (avail > 0) ? (int)(avail / (long long)tile_bytes) : 0;
    if (tpc < 1) tpc = 1;
    if (tpc > MAX_TILES) tpc = MAX_TILES;
    int nchunks = (MAX_TILES + tpc - 1) / tpc;

    for (int c = 0; c < nchunks; ++c) {
      hipLaunchKernelGGL(k_gemm1, dim3(HID / 128, tpc), dim3(256), 0, stream,
                         xb, w1, b1, pair_token, tile_expert, tile_row0, ntiles, h, c * tpc);
      hipLaunchKernelGGL(k_gemm2, dim3(DIM / 128, tpc), dim3(256), 0, stream,
                         h, w2, b2, pair_token, pair_gate, tile_expert, tile_row0, ntiles, out, c * tpc);
    }
  }
}

// Round 10
// 817.608 us; speedup vs baseline: 1.1781x; 1.0148x over previous
//
#include <hip/hip_runtime.h>
#include <math.h>

// MoE top-2 of 8 experts, D=1024, H=4096, 8192 tokens.
// Round 10: r6 config (best measured), minus the manual lgkmcnt(0)+
// sched_barrier(0) scheduler pin (m141 failure mode: order-pinning defeats
// the compiler's fine-grained counted lgkmcnt). Compiler-only fence after
// each raw s_barrier keeps ds_reads from hoisting (s_barrier is IntrNoMem).
#define TOKENS 8192
#define DIM    1024
#define NEXP   8
#define HID    4096
#define TILE_M 128
#define MAX_TILES 136
#define BKS    32

// old-path (fallback) LDS strides
#define BK     32
#define LDA    40
#define LDB    40

typedef __bf16 bf16x8 __attribute__((ext_vector_type(8)));
typedef float  f32x4  __attribute__((ext_vector_type(4)));
typedef unsigned int u32x4 __attribute__((ext_vector_type(4)));

__device__ __forceinline__ unsigned short f2bf(float f) {
  union { float f; unsigned u; } v; v.f = f;
  unsigned u = v.u + 0x7fffu + ((v.u >> 16) & 1u);   // RNE
  return (unsigned short)(u >> 16);
}
__device__ __forceinline__ float gelu_f(float v) {
  return 0.5f * v * (1.f + erff(v * 0.7071067811865476f));
}
__device__ __forceinline__ float gelu_fast(float v) {
  float t = v * v;
  float y = 0.7978845608f * v * fmaf(t, 0.044715f, 1.0f);
  y = fminf(y, 15.f);
  float z = __expf(2.f * y);
  return v * z * __builtin_amdgcn_rcpf(1.f + z);
}
__device__ __forceinline__ void gload16(const void* g, void* l) {
  __builtin_amdgcn_global_load_lds(
      (const __attribute__((address_space(1))) void*)g,
      (__attribute__((address_space(3))) void*)l, 16, 0, 0);
}
// bijective XCD-chunked swizzle (m204)
__device__ __forceinline__ int xcd_swz(int id, int nwg) {
  int q = nwg >> 3, r = nwg & 7;
  int xcd = id & 7, rank = id >> 3;
  return (xcd < r) ? xcd * (q + 1) + rank : r * (q + 1) + (xcd - r) * q + rank;
}

// ---------------- router (+ fused x->bf16 cast): one wave per token ----------------
__global__ __launch_bounds__(256) void k_router(
    const float* __restrict__ x, const float* __restrict__ wr,
    const float* __restrict__ br, int* __restrict__ sel,
    float* __restrict__ gates, int* __restrict__ counts,
    unsigned short* __restrict__ xb)
{
  int t = blockIdx.x * 4 + (threadIdx.x >> 6);
  int lane = threadIdx.x & 63;
  const float* xr = x + (size_t)t * DIM;
  unsigned short* xo = xb + (size_t)t * DIM;
  float acc[NEXP];
#pragma unroll
  for (int e = 0; e < NEXP; ++e) acc[e] = 0.f;
#pragma unroll
  for (int it = 0; it < 4; ++it) {
    int d = it * 256 + lane * 4;
    float4 xv = *(const float4*)(xr + d);
    ushort4 pk;
    pk.x = f2bf(xv.x); pk.y = f2bf(xv.y); pk.z = f2bf(xv.z); pk.w = f2bf(xv.w);
    *(ushort4*)(xo + d) = pk;
    float xs[4] = {xv.x, xv.y, xv.z, xv.w};
#pragma unroll
    for (int j = 0; j < 4; ++j) {
      float4 wa = *(const float4*)(wr + (size_t)(d + j) * NEXP);
      float4 wb = *(const float4*)(wr + (size_t)(d + j) * NEXP + 4);
      acc[0] += xs[j] * wa.x; acc[1] += xs[j] * wa.y;
      acc[2] += xs[j] * wa.z; acc[3] += xs[j] * wa.w;
      acc[4] += xs[j] * wb.x; acc[5] += xs[j] * wb.y;
      acc[6] += xs[j] * wb.z; acc[7] += xs[j] * wb.w;
    }
  }
#pragma unroll
  for (int off = 32; off >= 1; off >>= 1) {
#pragma unroll
    for (int e = 0; e < NEXP; ++e) acc[e] += __shfl_xor(acc[e], off);
  }
  if (lane == 0) {
    float l[NEXP];
#pragma unroll
    for (int e = 0; e < NEXP; ++e) l[e] = acc[e] + br[e];
    int e1 = 0; float v1 = l[0];
#pragma unroll
    for (int e = 1; e < NEXP; ++e) if (l[e] > v1) { v1 = l[e]; e1 = e; }
    int e2 = -1; float v2 = -1e30f;
#pragma unroll
    for (int e = 0; e < NEXP; ++e) {
      if (e == e1) continue;
      if (l[e] > v2) { v2 = l[e]; e2 = e; }
    }
    float g1 = 1.f / (1.f + expf(v2 - v1));
    sel[t * 2] = e1; sel[t * 2 + 1] = e2;
    gates[t * 2] = g1; gates[t * 2 + 1] = 1.f - g1;
    atomicAdd(&counts[e1], 1);
    atomicAdd(&counts[e2], 1);
  }
}

// ---------------- setup: offsets, tile table, padding (parallel), loss ----------------
__global__ __launch_bounds__(256) void k_setup(
    const int* __restrict__ counts, int* __restrict__ cursors,
    int* __restrict__ ntiles_p, int* __restrict__ tile_expert,
    int* __restrict__ tile_row0, int* __restrict__ pair_token,
    float* __restrict__ pair_gate, float* __restrict__ loss_out)
{
  __shared__ int s_pad0[NEXP], s_pad1[NEXP];
  int tid = threadIdx.x;
  if (tid == 0) {
    int poff = 0, nt = 0;
    float var = 0.f;
    for (int e = 0; e < NEXP; ++e) {
      int c = counts[e];
      cursors[e] = poff;
      int ntl = (c + TILE_M - 1) / TILE_M;
      for (int i = 0; i < ntl; ++i) { tile_expert[nt] = e; tile_row0[nt] = poff + i * TILE_M; ++nt; }
      s_pad0[e] = poff + c;
      s_pad1[e] = poff + ntl * TILE_M;
      float d = (float)c - 2048.f;
      var += d * d;
      poff += ntl * TILE_M;
    }
    *ntiles_p = nt;
    *loss_out = (var * (1.f / 7.f)) * (1.f / 2048.f) * 0.01f;
  }
  __syncthreads();
#pragma unroll
  for (int e = 0; e < NEXP; ++e) {
    for (int r = s_pad0[e] + tid; r < s_pad1[e]; r += 256) {
      pair_token[r] = -1; pair_gate[r] = 0.f;
    }
  }
}

// ---------------- bucket: scatter pairs ----------------
__global__ __launch_bounds__(256) void k_bucket(
    const int* __restrict__ sel, const float* __restrict__ gates,
    int* __restrict__ cursors, int* __restrict__ pair_token, float* __restrict__ pair_gate)
{
  int t = blockIdx.x * 256 + threadIdx.x;
#pragma unroll
  for (int k = 0; k < 2; ++k) {
    int e = sel[t * 2 + k];
    int pos = atomicAdd(&cursors[e], 1);
    pair_token[pos] = t;
    pair_gate[pos] = gates[t * 2 + k];
  }
}

// ---------------- transpose-cast: w [E][K][N] f32 -> wT [E][N][K] bf16 ----------------
__global__ __launch_bounds__(256) void k_castwT(
    const float* __restrict__ w, unsigned short* __restrict__ wT, int K, int N)
{
  __shared__ unsigned short t[64][72];
  int e = blockIdx.z, n0 = blockIdx.x * 64, k0 = blockIdx.y * 64;
  int tid = threadIdx.x;
  int kr = tid >> 2, nc = (tid & 3) * 16;
  const float* src = w + ((size_t)e * K + k0 + kr) * N + n0 + nc;
#pragma unroll
  for (int j = 0; j < 4; ++j) {
    f32x4 v = *(const f32x4*)(src + j * 4);
#pragma unroll
    for (int q = 0; q < 4; ++q) t[nc + j * 4 + q][kr] = f2bf(v[q]);
  }
  __syncthreads();
  int nr = tid >> 2, kc = (tid & 3) * 16;
  unsigned short* dst = wT + ((size_t)e * N + n0 + nr) * K + k0 + kc;
  *(u32x4*)dst = *(const u32x4*)&t[nr][kc];
  *(u32x4*)(dst + 8) = *(const u32x4*)&t[nr][kc + 8];
}

// ================= 3-buffer counted-vmcnt GEMMs (T2-swizzled LDS, unpinned sched) =================
// Swizzle: LDS[row][granule g] holds logical granule g ^ ((row>>1)&3).
//  - write side (linear gload dest): source granule = (lane&3) ^ ((sr>>1)&3)
//  - read side: granule = lk ^ ((lr>>1)&3)   (lane-constant)
// GEMM1: h = gelu(x_gathered @ w1T^T + b1).  1-D grid = tpc * (HID/128).
__global__ __launch_bounds__(256) void k_gemm1n(
    const unsigned short* __restrict__ xb, const unsigned short* __restrict__ w1T,
    const float* __restrict__ b1, const int* __restrict__ pair_token,
    const int* __restrict__ tile_expert, const int* __restrict__ tile_row0,
    const int* __restrict__ ntiles_p, unsigned short* __restrict__ h, int chunk_base)
{
  const int NBn = HID / 128;                       // 32
  const int nwg = gridDim.x;
  int newid = xcd_swz(blockIdx.x, nwg);
  int ltile = newid / NBn, nb = newid - ltile * NBn;
  int tile = chunk_base + ltile;
  if (tile >= *ntiles_p) return;
  const int e = tile_expert[tile];
  const int row0 = tile_row0[tile];
  const int n0 = nb * 128;
  const int tid = threadIdx.x;
  const int w = tid >> 6, lane = tid & 63;

  __shared__ unsigned short As[3][128 * BKS];
  __shared__ unsigned short Bs[3][128 * BKS];
  __shared__ int tok[128];

  if (tid < 128) { int t = pair_token[row0 + tid]; tok[tid] = (t < 0) ? 0 : t; }
  __syncthreads();

  const int sr = lane >> 2;
  const int kq = (((lane & 3) ^ ((sr >> 1) & 3))) * 8;   // swizzled source granule
  const int ar1 = w * 32 + sr, ar2 = ar1 + 16;
  const unsigned short* ag1 = xb + (size_t)tok[ar1] * DIM + kq;
  const unsigned short* ag2 = xb + (size_t)tok[ar2] * DIM + kq;
  const unsigned short* bg1 = w1T + ((size_t)e * HID + n0 + ar1) * DIM + kq;
  const unsigned short* bg2 = w1T + ((size_t)e * HID + n0 + ar2) * DIM + kq;

  const int wm = (w & 1) * 64, wn = (w >> 1) * 64;
  const int lr = lane & 15, lk = lane >> 4;
  const int gx = lk ^ ((lr >> 1) & 3);                   // swizzled read granule

  f32x4 acc[4][4];
#pragma unroll
  for (int mi = 0; mi < 4; ++mi)
#pragma unroll
    for (int ni = 0; ni < 4; ++ni) acc[mi][ni] = {0.f, 0.f, 0.f, 0.f};

#define STAGE1(buf, koff)                                      \
  gload16(ag1 + (koff), &As[buf][(w * 32) * BKS]);             \
  gload16(ag2 + (koff), &As[buf][(w * 32 + 16) * BKS]);        \
  gload16(bg1 + (koff), &Bs[buf][(w * 32) * BKS]);             \
  gload16(bg2 + (koff), &Bs[buf][(w * 32 + 16) * BKS]);

  STAGE1(0, 0)
  STAGE1(1, BKS)
  asm volatile("s_waitcnt vmcnt(4)" ::: "memory");
  __builtin_amdgcn_s_barrier();
  asm volatile("" ::: "memory");

  const int NT = DIM / BKS;                        // 32
  int cur = 0, dst = 2;
  for (int t = 0; t < NT; ++t) {
    if (t + 2 < NT) { STAGE1(dst, (t + 2) * BKS) }
    bf16x8 af[4], bfr[4];
#pragma unroll
    for (int mi = 0; mi < 4; ++mi)
      af[mi] = *(const bf16x8*)&As[cur][(wm + mi * 16 + lr) * BKS + gx * 8];
#pragma unroll
    for (int ni = 0; ni < 4; ++ni)
      bfr[ni] = *(const bf16x8*)&Bs[cur][(wn + ni * 16 + lr) * BKS + gx * 8];
    // no manual lgkmcnt/sched_barrier: compiler emits counted lgkmcnt per-MFMA
    __builtin_amdgcn_s_setprio(1);
#pragma unroll
    for (int mi = 0; mi < 4; ++mi)
#pragma unroll
      for (int ni = 0; ni < 4; ++ni)
        acc[mi][ni] = __builtin_amdgcn_mfma_f32_16x16x32_bf16(bfr[ni], af[mi], acc[mi][ni], 0, 0, 0);
    __builtin_amdgcn_s_setprio(0);
    if (t + 2 < NT) { asm volatile("s_waitcnt vmcnt(4)" ::: "memory"); }
    else            { asm volatile("s_waitcnt vmcnt(0)" ::: "memory"); }
    __builtin_amdgcn_s_barrier();
    asm volatile("" ::: "memory");
    cur = (cur == 2) ? 0 : cur + 1;
    dst = (dst == 2) ? 0 : dst + 1;
  }
#undef STAGE1

  const size_t tl = (size_t)(tile - chunk_base);
  f32x4 bv[4];
#pragma unroll
  for (int ni = 0; ni < 4; ++ni)
    bv[ni] = *(const f32x4*)(b1 + (size_t)e * HID + n0 + wn + ni * 16 + lk * 4);
#pragma unroll
  for (int mi = 0; mi < 4; ++mi) {
    int m = wm + mi * 16 + lr;
    unsigned short* hrow = h + (tl * TILE_M + m) * HID + n0;
#pragma unroll
    for (int ni = 0; ni < 4; ++ni) {
      int nb4 = wn + ni * 16 + lk * 4;
      ushort4 pk;
      pk.x = f2bf(gelu_fast(acc[mi][ni][0] + bv[ni][0]));
      pk.y = f2bf(gelu_fast(acc[mi][ni][1] + bv[ni][1]));
      pk.z = f2bf(gelu_fast(acc[mi][ni][2] + bv[ni][2]));
      pk.w = f2bf(gelu_fast(acc[mi][ni][3] + bv[ni][3]));
      *(ushort4*)(hrow + nb4) = pk;
    }
  }
}

// GEMM2: out[token] += gate * (h @ w2T^T + b2).  1-D grid = tpc * (DIM/128).
__global__ __launch_bounds__(256) void k_gemm2n(
    const unsigned short* __restrict__ h, const unsigned short* __restrict__ w2T,
    const float* __restrict__ b2, const int* __restrict__ pair_token,
    const float* __restrict__ pair_gate,
    const int* __restrict__ tile_expert, const int* __restrict__ tile_row0,
    const int* __restrict__ ntiles_p, float* __restrict__ out, int chunk_base)
{
  const int NBn = DIM / 128;                       // 8
  const int nwg = gridDim.x;
  int newid = xcd_swz(blockIdx.x, nwg);
  int ltile = newid / NBn, nb = newid - ltile * NBn;
  int tile = chunk_base + ltile;
  if (tile >= *ntiles_p) return;
  const int e = tile_expert[tile];
  const int row0 = tile_row0[tile];
  const int n0 = nb * 128;
  const int tid = threadIdx.x;
  const int w = tid >> 6, lane = tid & 63;

  __shared__ unsigned short As[3][128 * BKS];
  __shared__ unsigned short Bs[3][128 * BKS];
  __shared__ int tok[128];
  __shared__ float gat[128];

  if (tid < 128) { tok[tid] = pair_token[row0 + tid]; gat[tid] = pair_gate[row0 + tid]; }
  __syncthreads();

  const int sr = lane >> 2;
  const int kq = (((lane & 3) ^ ((sr >> 1) & 3))) * 8;   // swizzled source granule
  const int ar1 = w * 32 + sr, ar2 = ar1 + 16;
  const size_t tl = (size_t)(tile - chunk_base);
  const unsigned short* ag1 = h + (tl * TILE_M + ar1) * HID + kq;
  const unsigned short* ag2 = h + (tl * TILE_M + ar2) * HID + kq;
  const unsigned short* bg1 = w2T + ((size_t)e * DIM + n0 + ar1) * HID + kq;
  const unsigned short* bg2 = w2T + ((size_t)e * DIM + n0 + ar2) * HID + kq;

  const int wm = (w & 1) * 64, wn = (w >> 1) * 64;
  const int lr = lane & 15, lk = lane >> 4;
  const int gx = lk ^ ((lr >> 1) & 3);                   // swizzled read granule

  f32x4 acc[4][4];
#pragma unroll
  for (int mi = 0; mi < 4; ++mi)
#pragma unroll
    for (int ni = 0; ni < 4; ++ni) acc[mi][ni] = {0.f, 0.f, 0.f, 0.f};

#define STAGE2(buf, koff)                                      \
  gload16(ag1 + (koff), &As[buf][(w * 32) * BKS]);             \
  gload16(ag2 + (koff), &As[buf][(w * 32 + 16) * BKS]);        \
  gload16(bg1 + (koff), &Bs[buf][(w * 32) * BKS]);             \
  gload16(bg2 + (koff), &Bs[buf][(w * 32 + 16) * BKS]);

  STAGE2(0, 0)
  STAGE2(1, BKS)
  asm volatile("s_waitcnt vmcnt(4)" ::: "memory");
  __builtin_amdgcn_s_barrier();
  asm volatile("" ::: "memory");

  const int NT = HID / BKS;                        // 128
  int cur = 0, dst = 2;
  for (int t = 0; t < NT; ++t) {
    if (t + 2 < NT) { STAGE2(dst, (t + 2) * BKS) }
    bf16x8 af[4], bfr[4];
#pragma unroll
    for (int mi = 0; mi < 4; ++mi)
      af[mi] = *(const bf16x8*)&As[cur][(wm + mi * 16 + lr) * BKS + gx * 8];
#pragma unroll
    for (int ni = 0; ni < 4; ++ni)
      bfr[ni] = *(const bf16x8*)&Bs[cur][(wn + ni * 16 + lr) * BKS + gx * 8];
    // no manual lgkmcnt/sched_barrier: compiler emits counted lgkmcnt per-MFMA
    __builtin_amdgcn_s_setprio(1);
#pragma unroll
    for (int mi = 0; mi < 4; ++mi)
#pragma unroll
      for (int ni = 0; ni < 4; ++ni)
        acc[mi][ni] = __builtin_amdgcn_mfma_f32_16x16x32_bf16(af[mi], bfr[ni], acc[mi][ni], 0, 0, 0);
    __builtin_amdgcn_s_setprio(0);
    if (t + 2 < NT) { asm volatile("s_waitcnt vmcnt(4)" ::: "memory"); }
    else            { asm volatile("s_waitcnt vmcnt(0)" ::: "memory"); }
    __builtin_amdgcn_s_barrier();
    asm volatile("" ::: "memory");
    cur = (cur == 2) ? 0 : cur + 1;
    dst = (dst == 2) ? 0 : dst + 1;
  }
#undef STAGE2

  float bia[4];
#pragma unroll
  for (int ni = 0; ni < 4; ++ni) bia[ni] = b2[(size_t)e * DIM + n0 + wn + ni * 16 + lr];
#pragma unroll
  for (int mi = 0; mi < 4; ++mi)
#pragma unroll
    for (int r = 0; r < 4; ++r) {
      int m = wm + mi * 16 + lk * 4 + r;
      int t = tok[m];
      if (t >= 0) {
        float g = gat[m];
#pragma unroll
        for (int ni = 0; ni < 4; ++ni) {
          int n = wn + ni * 16 + lr;
          atomicAdd(out + (size_t)t * DIM + n0 + n, (acc[mi][ni][r] + bia[ni]) * g);
        }
      }
    }
}

// ================= OLD fallback GEMMs (round-1, known-good) =================
__global__ __launch_bounds__(256) void k_gemm1(
    const unsigned short* __restrict__ xb, const float* __restrict__ w1,
    const float* __restrict__ b1, const int* __restrict__ pair_token,
    const int* __restrict__ tile_expert, const int* __restrict__ tile_row0,
    const int* __restrict__ ntiles_p, unsigned short* __restrict__ h, int chunk_base)
{
  int tile = chunk_base + blockIdx.y;
  if (tile >= *ntiles_p) return;
  const int e = tile_expert[tile];
  const int row0 = tile_row0[tile];
  const int n0 = blockIdx.x * 128;
  const int tid = threadIdx.x;

  __shared__ unsigned short As[TILE_M * LDA];
  __shared__ unsigned short Bs[128 * LDB];
  __shared__ int tok[TILE_M];

  if (tid < TILE_M) tok[tid] = pair_token[row0 + tid];
  __syncthreads();

  const int ar = tid >> 1, akh = (tid & 1) * 16;
  const int bk = tid >> 3, bnh = (tid & 7) * 16;
  const int bswz = tid & 3;
  const int wv = tid >> 6, lane = tid & 63;
  const int wm = (wv & 1) * 64, wn = (wv >> 1) * 64;
  const int lr = lane & 15, lk = lane >> 4;
  const int atok = tok[ar];

  f32x4 acc[4][4];
#pragma unroll
  for (int mi = 0; mi < 4; ++mi)
#pragma unroll
    for (int ni = 0; ni < 4; ++ni) acc[mi][ni] = {0.f, 0.f, 0.f, 0.f};

  const unsigned short* asrc = (atok >= 0) ? (xb + (size_t)atok * DIM + akh) : (const unsigned short*)0;
  const float* bsrc0 = w1 + ((size_t)e * DIM + bk) * HID + n0 + bnh;
  const int wcol = 8 * ((bk >> 3) ^ bswz) + (bk & 7);

  for (int k0 = 0; k0 < DIM; k0 += BK) {
    u32x4 av0 = {0, 0, 0, 0}, av1 = {0, 0, 0, 0};
    if (asrc) {
      av0 = *(const u32x4*)(asrc + k0);
      av1 = *(const u32x4*)(asrc + k0 + 8);
    }
    float bv[16];
    const float* bs = bsrc0 + (size_t)k0 * HID;
#pragma unroll
    for (int j = 0; j < 4; ++j) {
      f32x4 f = *(const f32x4*)(bs + j * 4);
      bv[j * 4 + 0] = f[0]; bv[j * 4 + 1] = f[1];
      bv[j * 4 + 2] = f[2]; bv[j * 4 + 3] = f[3];
    }
    __syncthreads();
    *(u32x4*)&As[ar * LDA + akh] = av0;
    *(u32x4*)&As[ar * LDA + akh + 8] = av1;
#pragma unroll
    for (int j = 0; j < 16; ++j)
      Bs[(bnh + j) * LDB + wcol] = f2bf(bv[j]);
    __syncthreads();

    bf16x8 af[4], bfr[4];
#pragma unroll
    for (int mi = 0; mi < 4; ++mi)
      af[mi] = *(const bf16x8*)&As[(wm + mi * 16 + lr) * LDA + lk * 8];
#pragma unroll
    for (int ni = 0; ni < 4; ++ni) {
      int pch = lk ^ (((wn >> 4) + ni) & 3);
      bfr[ni] = *(const bf16x8*)&Bs[(wn + ni * 16 + lr) * LDB + pch * 8];
    }
#pragma unroll
    for (int mi = 0; mi < 4; ++mi)
#pragma unroll
      for (int ni = 0; ni < 4; ++ni)
        acc[mi][ni] = __builtin_amdgcn_mfma_f32_16x16x32_bf16(af[mi], bfr[ni], acc[mi][ni], 0, 0, 0);
  }

  const size_t tl = (size_t)(tile - chunk_base);
#pragma unroll
  for (int mi = 0; mi < 4; ++mi)
#pragma unroll
    for (int ni = 0; ni < 4; ++ni)
#pragma unroll
      for (int r = 0; r < 4; ++r) {
        int m = wm + mi * 16 + (lane >> 4) * 4 + r;
        int n = wn + ni * 16 + (lane & 15);
        float v = acc[mi][ni][r] + b1[(size_t)e * HID + n0 + n];
        h[(tl * TILE_M + m) * HID + n0 + n] = f2bf(gelu_f(v));
      }
}

__global__ __launch_bounds__(256) void k_gemm2(
    const unsigned short* __restrict__ h, const float* __restrict__ w2,
    const float* __restrict__ b2, const int* __restrict__ pair_token,
    const float* __restrict__ pair_gate,
    const int* __restrict__ tile_expert, const int* __restrict__ tile_row0,
    const int* __restrict__ ntiles_p, float* __restrict__ out, int chunk_base)
{
  int tile = chunk_base + blockIdx.y;
  if (tile >= *ntiles_p) return;
  const int e = tile_expert[tile];
  const int row0 = tile_row0[tile];
  const int n0 = blockIdx.x * 128;
  const int tid = threadIdx.x;

  __shared__ unsigned short As[TILE_M * LDA];
  __shared__ unsigned short Bs[128 * LDB];
  __shared__ int tok[TILE_M];
  __shared__ float gat[TILE_M];

  if (tid < TILE_M) { tok[tid] = pair_token[row0 + tid]; gat[tid] = pair_gate[row0 + tid]; }
  __syncthreads();

  const int ar = tid >> 1, akh = (tid & 1) * 16;
  const int bk = tid >> 3, bnh = (tid & 7) * 16;
  const int bswz = tid & 3;
  const int wv = tid >> 6, lane = tid & 63;
  const int wm = (wv & 1) * 64, wn = (wv >> 1) * 64;
  const int lr = lane & 15, lk = lane >> 4;

  f32x4 acc[4][4];
#pragma unroll
  for (int mi = 0; mi < 4; ++mi)
#pragma unroll
    for (int ni = 0; ni < 4; ++ni) acc[mi][ni] = {0.f, 0.f, 0.f, 0.f};

  const size_t tl = (size_t)(tile - chunk_base);
  const unsigned short* asrc = h + (tl * TILE_M + ar) * HID + akh;
  const float* bsrc0 = w2 + ((size_t)e * HID + bk) * DIM + n0 + bnh;
  const int wcol = 8 * ((bk >> 3) ^ bswz) + (bk & 7);

  for (int k0 = 0; k0 < HID; k0 += BK) {
    u32x4 av0 = *(const u32x4*)(asrc + k0);
    u32x4 av1 = *(const u32x4*)(asrc + k0 + 8);
    float bv[16];
    const float* bs = bsrc0 + (size_t)k0 * DIM;
#pragma unroll
    for (int j = 0; j < 4; ++j) {
      f32x4 f = *(const f32x4*)(bs + j * 4);
      bv[j * 4 + 0] = f[0]; bv[j * 4 + 1] = f[1];
      bv[j * 4 + 2] = f[2]; bv[j * 4 + 3] = f[3];
    }
    __syncthreads();
    *(u32x4*)&As[ar * LDA + akh] = av0;
    *(u32x4*)&As[ar * LDA + akh + 8] = av1;
#pragma unroll
    for (int j = 0; j < 16; ++j)
      Bs[(bnh + j) * LDB + wcol] = f2bf(bv[j]);
    __syncthreads();

    bf16x8 af[4], bfr[4];
#pragma unroll
    for (int mi = 0; mi < 4; ++mi)
      af[mi] = *(const bf16x8*)&As[(wm + mi * 16 + lr) * LDA + lk * 8];
#pragma unroll
    for (int ni = 0; ni < 4; ++ni) {
      int pch = lk ^ (((wn >> 4) + ni) & 3);
      bfr[ni] = *(const bf16x8*)&Bs[(wn + ni * 16 + lr) * LDB + pch * 8];
    }
#pragma unroll
    for (int mi = 0; mi < 4; ++mi)
#pragma unroll
      for (int ni = 0; ni < 4; ++ni)
        acc[mi][ni] = __builtin_amdgcn_mfma_f32_16x16x32_bf16(af[mi], bfr[ni], acc[mi][ni], 0, 0, 0);
  }

#pragma unroll
  for (int mi = 0; mi < 4; ++mi)
#pragma unroll
    for (int ni = 0; ni < 4; ++ni)
#pragma unroll
      for (int r = 0; r < 4; ++r) {
        int m = wm + mi * 16 + (lane >> 4) * 4 + r;
        int n = wn + ni * 16 + (lane & 15);
        int t = tok[m];
        if (t >= 0) {
          float v = acc[mi][ni][r] + b2[(size_t)e * DIM + n0 + n];
          atomicAdd(out + (size_t)t * DIM + n0 + n, v * gat[m]);
        }
      }
}

extern "C" void kernel_launch(void* const* d_in, const int* in_sizes, int n_in,
                              void* d_out, int out_size, void* d_ws, size_t ws_size,
                              hipStream_t stream) {
  const float* x  = (const float*)d_in[0];
  const float* wr = (const float*)d_in[1];
  const float* br = (const float*)d_in[2];
  const float* w1 = (const float*)d_in[3];
  const float* b1 = (const float*)d_in[4];
  const float* w2 = (const float*)d_in[5];
  const float* b2 = (const float*)d_in[6];
  float* out = (float*)d_out;

  char* ws = (char*)d_ws;
  int*   counts      = (int*)(ws + 0);
  int*   cursors     = (int*)(ws + 64);
  int*   ntiles      = (int*)(ws + 128);
  int*   tile_expert = (int*)(ws + 256);
  int*   tile_row0   = (int*)(ws + 1024);
  int*   sel         = (int*)(ws + 4096);
  float* gates       = (float*)(ws + 4096 + 65536);
  int*   pair_token  = (int*)(ws + 4096 + 131072);
  float* pair_gate   = (float*)(ws + 4096 + 131072 + 69632);

  const size_t OFF_XB  = 274432;
  const size_t XB_SZ   = (size_t)TOKENS * DIM * 2;           // 16 MB
  const size_t OFF_W1T = OFF_XB + XB_SZ;
  const size_t WT_SZ   = (size_t)NEXP * DIM * HID * 2;       // 67 MB each
  const size_t OFF_W2T = OFF_W1T + WT_SZ;
  const size_t OFF_HN  = OFF_W2T + WT_SZ;
  const size_t tile_bytes = (size_t)TILE_M * HID * 2;        // 1 MB

  unsigned short* xb  = (unsigned short*)(ws + OFF_XB);

  hipMemsetAsync(d_out, 0, (size_t)out_size * sizeof(float), stream);
  hipMemsetAsync(counts, 0, 64, stream);

  hipLaunchKernelGGL(k_router, dim3(TOKENS / 4), dim3(256), 0, stream,
                     x, wr, br, sel, gates, counts, xb);
  hipLaunchKernelGGL(k_setup, dim3(1), dim3(256), 0, stream,
                     counts, cursors, ntiles, tile_expert, tile_row0,
                     pair_token, pair_gate, out + (size_t)out_size - 1);
  hipLaunchKernelGGL(k_bucket, dim3(TOKENS / 256), dim3(256), 0, stream,
                     sel, gates, cursors, pair_token, pair_gate);

  bool newpath = ws_size >= OFF_HN + tile_bytes;

  if (newpath) {
    unsigned short* w1T = (unsigned short*)(ws + OFF_W1T);
    unsigned short* w2T = (unsigned short*)(ws + OFF_W2T);
    unsigned short* h   = (unsigned short*)(ws + OFF_HN);

    hipLaunchKernelGGL(k_castwT, dim3(HID / 64, DIM / 64, NEXP), dim3(256), 0, stream,
                       w1, w1T, DIM, HID);
    hipLaunchKernelGGL(k_castwT, dim3(DIM / 64, HID / 64, NEXP), dim3(256), 0, stream,
                       w2, w2T, HID, DIM);

    long long avail = (long long)ws_size - (long long)OFF_HN;
    int tpc = (int)(avail / (long long)tile_bytes);
    if (tpc < 1) tpc = 1;
    if (tpc > MAX_TILES) tpc = MAX_TILES;
    int nchunks = (MAX_TILES + tpc - 1) / tpc;

    for (int c = 0; c < nchunks; ++c) {
      hipLaunchKernelGGL(k_gemm1n, dim3(tpc * (HID / 128)), dim3(256), 0, stream,
                         xb, w1T, b1, pair_token, tile_expert, tile_row0, ntiles, h, c * tpc);
      hipLaunchKernelGGL(k_gemm2n, dim3(tpc * (DIM / 128)), dim3(256), 0, stream,
                         h, w2T, b2, pair_token, pair_gate, tile_expert, tile_row0, ntiles, out, c * tpc);
    }
  } else {
    unsigned short* h = (unsigned short*)(ws + OFF_W1T);
    long long avail = (long long)ws_size - (long long)OFF_W1T;
    int tpc = (avail > 0) ? (int)(avail / (long long)tile_bytes) : 0;
    if (tpc < 1) tpc = 1;
    if (tpc > MAX_TILES) tpc = MAX_TILES;
    int nchunks = (MAX_TILES + tpc - 1) / tpc;

    for (int c = 0; c < nchunks; ++c) {
      hipLaunchKernelGGL(k_gemm1, dim3(HID / 128, tpc), dim3(256), 0, stream,
                         xb, w1, b1, pair_token, tile_expert, tile_row0, ntiles, h, c * tpc);
      hipLaunchKernelGGL(k_gemm2, dim3(DIM / 128, tpc), dim3(256), 0, stream,
                         h, w2, b2, pair_token, pair_gate, tile_expert, tile_row0, ntiles, out, c * tpc);
    }
  }
}

// Round 11
// 816.564 us; speedup vs baseline: 1.1796x; 1.0013x over previous
//
#include <hip/hip_runtime.h>
#include <math.h>

// MoE top-2 of 8 experts, D=1024, H=4096, 8192 tokens.
// Round 11: r10 GEMMs unchanged (best measured). k_castwT rewritten:
// 4k x 4n micro-tile per thread, 4 x ds_write_b64 packed writes instead of
// 16 x ds_write_u16 (4x fewer 8-way-conflicted LDS ops) -> transpose-cast
// moves toward BW-bound.
#define TOKENS 8192
#define DIM    1024
#define NEXP   8
#define HID    4096
#define TILE_M 128
#define MAX_TILES 136
#define BKS    32

// old-path (fallback) LDS strides
#define BK     32
#define LDA    40
#define LDB    40

typedef __bf16 bf16x8 __attribute__((ext_vector_type(8)));
typedef float  f32x4  __attribute__((ext_vector_type(4)));
typedef unsigned int u32x4 __attribute__((ext_vector_type(4)));

__device__ __forceinline__ unsigned short f2bf(float f) {
  union { float f; unsigned u; } v; v.f = f;
  unsigned u = v.u + 0x7fffu + ((v.u >> 16) & 1u);   // RNE
  return (unsigned short)(u >> 16);
}
__device__ __forceinline__ float gelu_f(float v) {
  return 0.5f * v * (1.f + erff(v * 0.7071067811865476f));
}
__device__ __forceinline__ float gelu_fast(float v) {
  float t = v * v;
  float y = 0.7978845608f * v * fmaf(t, 0.044715f, 1.0f);
  y = fminf(y, 15.f);
  float z = __expf(2.f * y);
  return v * z * __builtin_amdgcn_rcpf(1.f + z);
}
__device__ __forceinline__ void gload16(const void* g, void* l) {
  __builtin_amdgcn_global_load_lds(
      (const __attribute__((address_space(1))) void*)g,
      (__attribute__((address_space(3))) void*)l, 16, 0, 0);
}
// bijective XCD-chunked swizzle (m204)
__device__ __forceinline__ int xcd_swz(int id, int nwg) {
  int q = nwg >> 3, r = nwg & 7;
  int xcd = id & 7, rank = id >> 3;
  return (xcd < r) ? xcd * (q + 1) + rank : r * (q + 1) + (xcd - r) * q + rank;
}

// ---------------- router (+ fused x->bf16 cast): one wave per token ----------------
__global__ __launch_bounds__(256) void k_router(
    const float* __restrict__ x, const float* __restrict__ wr,
    const float* __restrict__ br, int* __restrict__ sel,
    float* __restrict__ gates, int* __restrict__ counts,
    unsigned short* __restrict__ xb)
{
  int t = blockIdx.x * 4 + (threadIdx.x >> 6);
  int lane = threadIdx.x & 63;
  const float* xr = x + (size_t)t * DIM;
  unsigned short* xo = xb + (size_t)t * DIM;
  float acc[NEXP];
#pragma unroll
  for (int e = 0; e < NEXP; ++e) acc[e] = 0.f;
#pragma unroll
  for (int it = 0; it < 4; ++it) {
    int d = it * 256 + lane * 4;
    float4 xv = *(const float4*)(xr + d);
    ushort4 pk;
    pk.x = f2bf(xv.x); pk.y = f2bf(xv.y); pk.z = f2bf(xv.z); pk.w = f2bf(xv.w);
    *(ushort4*)(xo + d) = pk;
    float xs[4] = {xv.x, xv.y, xv.z, xv.w};
#pragma unroll
    for (int j = 0; j < 4; ++j) {
      float4 wa = *(const float4*)(wr + (size_t)(d + j) * NEXP);
      float4 wb = *(const float4*)(wr + (size_t)(d + j) * NEXP + 4);
      acc[0] += xs[j] * wa.x; acc[1] += xs[j] * wa.y;
      acc[2] += xs[j] * wa.z; acc[3] += xs[j] * wa.w;
      acc[4] += xs[j] * wb.x; acc[5] += xs[j] * wb.y;
      acc[6] += xs[j] * wb.z; acc[7] += xs[j] * wb.w;
    }
  }
#pragma unroll
  for (int off = 32; off >= 1; off >>= 1) {
#pragma unroll
    for (int e = 0; e < NEXP; ++e) acc[e] += __shfl_xor(acc[e], off);
  }
  if (lane == 0) {
    float l[NEXP];
#pragma unroll
    for (int e = 0; e < NEXP; ++e) l[e] = acc[e] + br[e];
    int e1 = 0; float v1 = l[0];
#pragma unroll
    for (int e = 1; e < NEXP; ++e) if (l[e] > v1) { v1 = l[e]; e1 = e; }
    int e2 = -1; float v2 = -1e30f;
#pragma unroll
    for (int e = 0; e < NEXP; ++e) {
      if (e == e1) continue;
      if (l[e] > v2) { v2 = l[e]; e2 = e; }
    }
    float g1 = 1.f / (1.f + expf(v2 - v1));
    sel[t * 2] = e1; sel[t * 2 + 1] = e2;
    gates[t * 2] = g1; gates[t * 2 + 1] = 1.f - g1;
    atomicAdd(&counts[e1], 1);
    atomicAdd(&counts[e2], 1);
  }
}

// ---------------- setup: offsets, tile table, padding (parallel), loss ----------------
__global__ __launch_bounds__(256) void k_setup(
    const int* __restrict__ counts, int* __restrict__ cursors,
    int* __restrict__ ntiles_p, int* __restrict__ tile_expert,
    int* __restrict__ tile_row0, int* __restrict__ pair_token,
    float* __restrict__ pair_gate, float* __restrict__ loss_out)
{
  __shared__ int s_pad0[NEXP], s_pad1[NEXP];
  int tid = threadIdx.x;
  if (tid == 0) {
    int poff = 0, nt = 0;
    float var = 0.f;
    for (int e = 0; e < NEXP; ++e) {
      int c = counts[e];
      cursors[e] = poff;
      int ntl = (c + TILE_M - 1) / TILE_M;
      for (int i = 0; i < ntl; ++i) { tile_expert[nt] = e; tile_row0[nt] = poff + i * TILE_M; ++nt; }
      s_pad0[e] = poff + c;
      s_pad1[e] = poff + ntl * TILE_M;
      float d = (float)c - 2048.f;
      var += d * d;
      poff += ntl * TILE_M;
    }
    *ntiles_p = nt;
    *loss_out = (var * (1.f / 7.f)) * (1.f / 2048.f) * 0.01f;
  }
  __syncthreads();
#pragma unroll
  for (int e = 0; e < NEXP; ++e) {
    for (int r = s_pad0[e] + tid; r < s_pad1[e]; r += 256) {
      pair_token[r] = -1; pair_gate[r] = 0.f;
    }
  }
}

// ---------------- bucket: scatter pairs ----------------
__global__ __launch_bounds__(256) void k_bucket(
    const int* __restrict__ sel, const float* __restrict__ gates,
    int* __restrict__ cursors, int* __restrict__ pair_token, float* __restrict__ pair_gate)
{
  int t = blockIdx.x * 256 + threadIdx.x;
#pragma unroll
  for (int k = 0; k < 2; ++k) {
    int e = sel[t * 2 + k];
    int pos = atomicAdd(&cursors[e], 1);
    pair_token[pos] = t;
    pair_gate[pos] = gates[t * 2 + k];
  }
}

// ---------------- transpose-cast: w [E][K][N] f32 -> wT [E][N][K] bf16 ----------------
// 4k x 4n micro-tile per thread; 4 x ds_write_b64 (packed k-quads) instead of
// 16 scalar ds_write_u16. 64x64 tile per block, stride 72 (16B-aligned rows).
__global__ __launch_bounds__(256) void k_castwT(
    const float* __restrict__ w, unsigned short* __restrict__ wT, int K, int N)
{
  __shared__ unsigned short t[64 * 72];
  int e = blockIdx.z, n0 = blockIdx.x * 64, k0 = blockIdx.y * 64;
  int tid = threadIdx.x;
  {
    int kr = (tid >> 4) * 4;          // 0..60 step 4
    int nc = (tid & 15) * 4;          // 0..60 step 4
    const float* src = w + ((size_t)e * K + k0 + kr) * N + n0 + nc;
    f32x4 r0 = *(const f32x4*)(src);
    f32x4 r1 = *(const f32x4*)(src + N);
    f32x4 r2 = *(const f32x4*)(src + 2 * (size_t)N);
    f32x4 r3 = *(const f32x4*)(src + 3 * (size_t)N);
#pragma unroll
    for (int i = 0; i < 4; ++i) {
      ushort4 p;
      p.x = f2bf(r0[i]); p.y = f2bf(r1[i]); p.z = f2bf(r2[i]); p.w = f2bf(r3[i]);
      *(ushort4*)&t[(nc + i) * 72 + kr] = p;   // t[n][k..k+3]
    }
  }
  __syncthreads();
  int nr = tid >> 2, kc = (tid & 3) * 16;
  unsigned short* dst = wT + ((size_t)e * N + n0 + nr) * K + k0 + kc;
  *(u32x4*)dst = *(const u32x4*)&t[nr * 72 + kc];
  *(u32x4*)(dst + 8) = *(const u32x4*)&t[nr * 72 + kc + 8];
}

// ================= 3-buffer counted-vmcnt GEMMs (T2-swizzled LDS, unpinned sched) =================
// Swizzle: LDS[row][granule g] holds logical granule g ^ ((row>>1)&3).
//  - write side (linear gload dest): source granule = (lane&3) ^ ((sr>>1)&3)
//  - read side: granule = lk ^ ((lr>>1)&3)   (lane-constant)
// GEMM1: h = gelu(x_gathered @ w1T^T + b1).  1-D grid = tpc * (HID/128).
__global__ __launch_bounds__(256) void k_gemm1n(
    const unsigned short* __restrict__ xb, const unsigned short* __restrict__ w1T,
    const float* __restrict__ b1, const int* __restrict__ pair_token,
    const int* __restrict__ tile_expert, const int* __restrict__ tile_row0,
    const int* __restrict__ ntiles_p, unsigned short* __restrict__ h, int chunk_base)
{
  const int NBn = HID / 128;                       // 32
  const int nwg = gridDim.x;
  int newid = xcd_swz(blockIdx.x, nwg);
  int ltile = newid / NBn, nb = newid - ltile * NBn;
  int tile = chunk_base + ltile;
  if (tile >= *ntiles_p) return;
  const int e = tile_expert[tile];
  const int row0 = tile_row0[tile];
  const int n0 = nb * 128;
  const int tid = threadIdx.x;
  const int w = tid >> 6, lane = tid & 63;

  __shared__ unsigned short As[3][128 * BKS];
  __shared__ unsigned short Bs[3][128 * BKS];
  __shared__ int tok[128];

  if (tid < 128) { int t = pair_token[row0 + tid]; tok[tid] = (t < 0) ? 0 : t; }
  __syncthreads();

  const int sr = lane >> 2;
  const int kq = (((lane & 3) ^ ((sr >> 1) & 3))) * 8;   // swizzled source granule
  const int ar1 = w * 32 + sr, ar2 = ar1 + 16;
  const unsigned short* ag1 = xb + (size_t)tok[ar1] * DIM + kq;
  const unsigned short* ag2 = xb + (size_t)tok[ar2] * DIM + kq;
  const unsigned short* bg1 = w1T + ((size_t)e * HID + n0 + ar1) * DIM + kq;
  const unsigned short* bg2 = w1T + ((size_t)e * HID + n0 + ar2) * DIM + kq;

  const int wm = (w & 1) * 64, wn = (w >> 1) * 64;
  const int lr = lane & 15, lk = lane >> 4;
  const int gx = lk ^ ((lr >> 1) & 3);                   // swizzled read granule

  f32x4 acc[4][4];
#pragma unroll
  for (int mi = 0; mi < 4; ++mi)
#pragma unroll
    for (int ni = 0; ni < 4; ++ni) acc[mi][ni] = {0.f, 0.f, 0.f, 0.f};

#define STAGE1(buf, koff)                                      \
  gload16(ag1 + (koff), &As[buf][(w * 32) * BKS]);             \
  gload16(ag2 + (koff), &As[buf][(w * 32 + 16) * BKS]);        \
  gload16(bg1 + (koff), &Bs[buf][(w * 32) * BKS]);             \
  gload16(bg2 + (koff), &Bs[buf][(w * 32 + 16) * BKS]);

  STAGE1(0, 0)
  STAGE1(1, BKS)
  asm volatile("s_waitcnt vmcnt(4)" ::: "memory");
  __builtin_amdgcn_s_barrier();
  asm volatile("" ::: "memory");

  const int NT = DIM / BKS;                        // 32
  int cur = 0, dst = 2;
  for (int t = 0; t < NT; ++t) {
    if (t + 2 < NT) { STAGE1(dst, (t + 2) * BKS) }
    bf16x8 af[4], bfr[4];
#pragma unroll
    for (int mi = 0; mi < 4; ++mi)
      af[mi] = *(const bf16x8*)&As[cur][(wm + mi * 16 + lr) * BKS + gx * 8];
#pragma unroll
    for (int ni = 0; ni < 4; ++ni)
      bfr[ni] = *(const bf16x8*)&Bs[cur][(wn + ni * 16 + lr) * BKS + gx * 8];
    // no manual lgkmcnt/sched_barrier: compiler emits counted lgkmcnt per-MFMA
    __builtin_amdgcn_s_setprio(1);
#pragma unroll
    for (int mi = 0; mi < 4; ++mi)
#pragma unroll
      for (int ni = 0; ni < 4; ++ni)
        acc[mi][ni] = __builtin_amdgcn_mfma_f32_16x16x32_bf16(bfr[ni], af[mi], acc[mi][ni], 0, 0, 0);
    __builtin_amdgcn_s_setprio(0);
    if (t + 2 < NT) { asm volatile("s_waitcnt vmcnt(4)" ::: "memory"); }
    else            { asm volatile("s_waitcnt vmcnt(0)" ::: "memory"); }
    __builtin_amdgcn_s_barrier();
    asm volatile("" ::: "memory");
    cur = (cur == 2) ? 0 : cur + 1;
    dst = (dst == 2) ? 0 : dst + 1;
  }
#undef STAGE1

  const size_t tl = (size_t)(tile - chunk_base);
  f32x4 bv[4];
#pragma unroll
  for (int ni = 0; ni < 4; ++ni)
    bv[ni] = *(const f32x4*)(b1 + (size_t)e * HID + n0 + wn + ni * 16 + lk * 4);
#pragma unroll
  for (int mi = 0; mi < 4; ++mi) {
    int m = wm + mi * 16 + lr;
    unsigned short* hrow = h + (tl * TILE_M + m) * HID + n0;
#pragma unroll
    for (int ni = 0; ni < 4; ++ni) {
      int nb4 = wn + ni * 16 + lk * 4;
      ushort4 pk;
      pk.x = f2bf(gelu_fast(acc[mi][ni][0] + bv[ni][0]));
      pk.y = f2bf(gelu_fast(acc[mi][ni][1] + bv[ni][1]));
      pk.z = f2bf(gelu_fast(acc[mi][ni][2] + bv[ni][2]));
      pk.w = f2bf(gelu_fast(acc[mi][ni][3] + bv[ni][3]));
      *(ushort4*)(hrow + nb4) = pk;
    }
  }
}

// GEMM2: out[token] += gate * (h @ w2T^T + b2).  1-D grid = tpc * (DIM/128).
__global__ __launch_bounds__(256) void k_gemm2n(
    const unsigned short* __restrict__ h, const unsigned short* __restrict__ w2T,
    const float* __restrict__ b2, const int* __restrict__ pair_token,
    const float* __restrict__ pair_gate,
    const int* __restrict__ tile_expert, const int* __restrict__ tile_row0,
    const int* __restrict__ ntiles_p, float* __restrict__ out, int chunk_base)
{
  const int NBn = DIM / 128;                       // 8
  const int nwg = gridDim.x;
  int newid = xcd_swz(blockIdx.x, nwg);
  int ltile = newid / NBn, nb = newid - ltile * NBn;
  int tile = chunk_base + ltile;
  if (tile >= *ntiles_p) return;
  const int e = tile_expert[tile];
  const int row0 = tile_row0[tile];
  const int n0 = nb * 128;
  const int tid = threadIdx.x;
  const int w = tid >> 6, lane = tid & 63;

  __shared__ unsigned short As[3][128 * BKS];
  __shared__ unsigned short Bs[3][128 * BKS];
  __shared__ int tok[128];
  __shared__ float gat[128];

  if (tid < 128) { tok[tid] = pair_token[row0 + tid]; gat[tid] = pair_gate[row0 + tid]; }
  __syncthreads();

  const int sr = lane >> 2;
  const int kq = (((lane & 3) ^ ((sr >> 1) & 3))) * 8;   // swizzled source granule
  const int ar1 = w * 32 + sr, ar2 = ar1 + 16;
  const size_t tl = (size_t)(tile - chunk_base);
  const unsigned short* ag1 = h + (tl * TILE_M + ar1) * HID + kq;
  const unsigned short* ag2 = h + (tl * TILE_M + ar2) * HID + kq;
  const unsigned short* bg1 = w2T + ((size_t)e * DIM + n0 + ar1) * HID + kq;
  const unsigned short* bg2 = w2T + ((size_t)e * DIM + n0 + ar2) * HID + kq;

  const int wm = (w & 1) * 64, wn = (w >> 1) * 64;
  const int lr = lane & 15, lk = lane >> 4;
  const int gx = lk ^ ((lr >> 1) & 3);                   // swizzled read granule

  f32x4 acc[4][4];
#pragma unroll
  for (int mi = 0; mi < 4; ++mi)
#pragma unroll
    for (int ni = 0; ni < 4; ++ni) acc[mi][ni] = {0.f, 0.f, 0.f, 0.f};

#define STAGE2(buf, koff)                                      \
  gload16(ag1 + (koff), &As[buf][(w * 32) * BKS]);             \
  gload16(ag2 + (koff), &As[buf][(w * 32 + 16) * BKS]);        \
  gload16(bg1 + (koff), &Bs[buf][(w * 32) * BKS]);             \
  gload16(bg2 + (koff), &Bs[buf][(w * 32 + 16) * BKS]);

  STAGE2(0, 0)
  STAGE2(1, BKS)
  asm volatile("s_waitcnt vmcnt(4)" ::: "memory");
  __builtin_amdgcn_s_barrier();
  asm volatile("" ::: "memory");

  const int NT = HID / BKS;                        // 128
  int cur = 0, dst = 2;
  for (int t = 0; t < NT; ++t) {
    if (t + 2 < NT) { STAGE2(dst, (t + 2) * BKS) }
    bf16x8 af[4], bfr[4];
#pragma unroll
    for (int mi = 0; mi < 4; ++mi)
      af[mi] = *(const bf16x8*)&As[cur][(wm + mi * 16 + lr) * BKS + gx * 8];
#pragma unroll
    for (int ni = 0; ni < 4; ++ni)
      bfr[ni] = *(const bf16x8*)&Bs[cur][(wn + ni * 16 + lr) * BKS + gx * 8];
    // no manual lgkmcnt/sched_barrier: compiler emits counted lgkmcnt per-MFMA
    __builtin_amdgcn_s_setprio(1);
#pragma unroll
    for (int mi = 0; mi < 4; ++mi)
#pragma unroll
      for (int ni = 0; ni < 4; ++ni)
        acc[mi][ni] = __builtin_amdgcn_mfma_f32_16x16x32_bf16(af[mi], bfr[ni], acc[mi][ni], 0, 0, 0);
    __builtin_amdgcn_s_setprio(0);
    if (t + 2 < NT) { asm volatile("s_waitcnt vmcnt(4)" ::: "memory"); }
    else            { asm volatile("s_waitcnt vmcnt(0)" ::: "memory"); }
    __builtin_amdgcn_s_barrier();
    asm volatile("" ::: "memory");
    cur = (cur == 2) ? 0 : cur + 1;
    dst = (dst == 2) ? 0 : dst + 1;
  }
#undef STAGE2

  float bia[4];
#pragma unroll
  for (int ni = 0; ni < 4; ++ni) bia[ni] = b2[(size_t)e * DIM + n0 + wn + ni * 16 + lr];
#pragma unroll
  for (int mi = 0; mi < 4; ++mi)
#pragma unroll
    for (int r = 0; r < 4; ++r) {
      int m = wm + mi * 16 + lk * 4 + r;
      int t = tok[m];
      if (t >= 0) {
        float g = gat[m];
#pragma unroll
        for (int ni = 0; ni < 4; ++ni) {
          int n = wn + ni * 16 + lr;
          atomicAdd(out + (size_t)t * DIM + n0 + n, (acc[mi][ni][r] + bia[ni]) * g);
        }
      }
    }
}

// ================= OLD fallback GEMMs (round-1, known-good) =================
__global__ __launch_bounds__(256) void k_gemm1(
    const unsigned short* __restrict__ xb, const float* __restrict__ w1,
    const float* __restrict__ b1, const int* __restrict__ pair_token,
    const int* __restrict__ tile_expert, const int* __restrict__ tile_row0,
    const int* __restrict__ ntiles_p, unsigned short* __restrict__ h, int chunk_base)
{
  int tile = chunk_base + blockIdx.y;
  if (tile >= *ntiles_p) return;
  const int e = tile_expert[tile];
  const int row0 = tile_row0[tile];
  const int n0 = blockIdx.x * 128;
  const int tid = threadIdx.x;

  __shared__ unsigned short As[TILE_M * LDA];
  __shared__ unsigned short Bs[128 * LDB];
  __shared__ int tok[TILE_M];

  if (tid < TILE_M) tok[tid] = pair_token[row0 + tid];
  __syncthreads();

  const int ar = tid >> 1, akh = (tid & 1) * 16;
  const int bk = tid >> 3, bnh = (tid & 7) * 16;
  const int bswz = tid & 3;
  const int wv = tid >> 6, lane = tid & 63;
  const int wm = (wv & 1) * 64, wn = (wv >> 1) * 64;
  const int lr = lane & 15, lk = lane >> 4;
  const int atok = tok[ar];

  f32x4 acc[4][4];
#pragma unroll
  for (int mi = 0; mi < 4; ++mi)
#pragma unroll
    for (int ni = 0; ni < 4; ++ni) acc[mi][ni] = {0.f, 0.f, 0.f, 0.f};

  const unsigned short* asrc = (atok >= 0) ? (xb + (size_t)atok * DIM + akh) : (const unsigned short*)0;
  const float* bsrc0 = w1 + ((size_t)e * DIM + bk) * HID + n0 + bnh;
  const int wcol = 8 * ((bk >> 3) ^ bswz) + (bk & 7);

  for (int k0 = 0; k0 < DIM; k0 += BK) {
    u32x4 av0 = {0, 0, 0, 0}, av1 = {0, 0, 0, 0};
    if (asrc) {
      av0 = *(const u32x4*)(asrc + k0);
      av1 = *(const u32x4*)(asrc + k0 + 8);
    }
    float bv[16];
    const float* bs = bsrc0 + (size_t)k0 * HID;
#pragma unroll
    for (int j = 0; j < 4; ++j) {
      f32x4 f = *(const f32x4*)(bs + j * 4);
      bv[j * 4 + 0] = f[0]; bv[j * 4 + 1] = f[1];
      bv[j * 4 + 2] = f[2]; bv[j * 4 + 3] = f[3];
    }
    __syncthreads();
    *(u32x4*)&As[ar * LDA + akh] = av0;
    *(u32x4*)&As[ar * LDA + akh + 8] = av1;
#pragma unroll
    for (int j = 0; j < 16; ++j)
      Bs[(bnh + j) * LDB + wcol] = f2bf(bv[j]);
    __syncthreads();

    bf16x8 af[4], bfr[4];
#pragma unroll
    for (int mi = 0; mi < 4; ++mi)
      af[mi] = *(const bf16x8*)&As[(wm + mi * 16 + lr) * LDA + lk * 8];
#pragma unroll
    for (int ni = 0; ni < 4; ++ni) {
      int pch = lk ^ (((wn >> 4) + ni) & 3);
      bfr[ni] = *(const bf16x8*)&Bs[(wn + ni * 16 + lr) * LDB + pch * 8];
    }
#pragma unroll
    for (int mi = 0; mi < 4; ++mi)
#pragma unroll
      for (int ni = 0; ni < 4; ++ni)
        acc[mi][ni] = __builtin_amdgcn_mfma_f32_16x16x32_bf16(af[mi], bfr[ni], acc[mi][ni], 0, 0, 0);
  }

  const size_t tl = (size_t)(tile - chunk_base);
#pragma unroll
  for (int mi = 0; mi < 4; ++mi)
#pragma unroll
    for (int ni = 0; ni < 4; ++ni)
#pragma unroll
      for (int r = 0; r < 4; ++r) {
        int m = wm + mi * 16 + (lane >> 4) * 4 + r;
        int n = wn + ni * 16 + (lane & 15);
        float v = acc[mi][ni][r] + b1[(size_t)e * HID + n0 + n];
        h[(tl * TILE_M + m) * HID + n0 + n] = f2bf(gelu_f(v));
      }
}

__global__ __launch_bounds__(256) void k_gemm2(
    const unsigned short* __restrict__ h, const float* __restrict__ w2,
    const float* __restrict__ b2, const int* __restrict__ pair_token,
    const float* __restrict__ pair_gate,
    const int* __restrict__ tile_expert, const int* __restrict__ tile_row0,
    const int* __restrict__ ntiles_p, float* __restrict__ out, int chunk_base)
{
  int tile = chunk_base + blockIdx.y;
  if (tile >= *ntiles_p) return;
  const int e = tile_expert[tile];
  const int row0 = tile_row0[tile];
  const int n0 = blockIdx.x * 128;
  const int tid = threadIdx.x;

  __shared__ unsigned short As[TILE_M * LDA];
  __shared__ unsigned short Bs[128 * LDB];
  __shared__ int tok[TILE_M];
  __shared__ float gat[TILE_M];

  if (tid < TILE_M) { tok[tid] = pair_token[row0 + tid]; gat[tid] = pair_gate[row0 + tid]; }
  __syncthreads();

  const int ar = tid >> 1, akh = (tid & 1) * 16;
  const int bk = tid >> 3, bnh = (tid & 7) * 16;
  const int bswz = tid & 3;
  const int wv = tid >> 6, lane = tid & 63;
  const int wm = (wv & 1) * 64, wn = (wv >> 1) * 64;
  const int lr = lane & 15, lk = lane >> 4;

  f32x4 acc[4][4];
#pragma unroll
  for (int mi = 0; mi < 4; ++mi)
#pragma unroll
    for (int ni = 0; ni < 4; ++ni) acc[mi][ni] = {0.f, 0.f, 0.f, 0.f};

  const size_t tl = (size_t)(tile - chunk_base);
  const unsigned short* asrc = h + (tl * TILE_M + ar) * HID + akh;
  const float* bsrc0 = w2 + ((size_t)e * HID + bk) * DIM + n0 + bnh;
  const int wcol = 8 * ((bk >> 3) ^ bswz) + (bk & 7);

  for (int k0 = 0; k0 < HID; k0 += BK) {
    u32x4 av0 = *(const u32x4*)(asrc + k0);
    u32x4 av1 = *(const u32x4*)(asrc + k0 + 8);
    float bv[16];
    const float* bs = bsrc0 + (size_t)k0 * DIM;
#pragma unroll
    for (int j = 0; j < 4; ++j) {
      f32x4 f = *(const f32x4*)(bs + j * 4);
      bv[j * 4 + 0] = f[0]; bv[j * 4 + 1] = f[1];
      bv[j * 4 + 2] = f[2]; bv[j * 4 + 3] = f[3];
    }
    __syncthreads();
    *(u32x4*)&As[ar * LDA + akh] = av0;
    *(u32x4*)&As[ar * LDA + akh + 8] = av1;
#pragma unroll
    for (int j = 0; j < 16; ++j)
      Bs[(bnh + j) * LDB + wcol] = f2bf(bv[j]);
    __syncthreads();

    bf16x8 af[4], bfr[4];
#pragma unroll
    for (int mi = 0; mi < 4; ++mi)
      af[mi] = *(const bf16x8*)&As[(wm + mi * 16 + lr) * LDA + lk * 8];
#pragma unroll
    for (int ni = 0; ni < 4; ++ni) {
      int pch = lk ^ (((wn >> 4) + ni) & 3);
      bfr[ni] = *(const bf16x8*)&Bs[(wn + ni * 16 + lr) * LDB + pch * 8];
    }
#pragma unroll
    for (int mi = 0; mi < 4; ++mi)
#pragma unroll
      for (int ni = 0; ni < 4; ++ni)
        acc[mi][ni] = __builtin_amdgcn_mfma_f32_16x16x32_bf16(af[mi], bfr[ni], acc[mi][ni], 0, 0, 0);
  }

#pragma unroll
  for (int mi = 0; mi < 4; ++mi)
#pragma unroll
    for (int ni = 0; ni < 4; ++ni)
#pragma unroll
      for (int r = 0; r < 4; ++r) {
        int m = wm + mi * 16 + (lane >> 4) * 4 + r;
        int n = wn + ni * 16 + (lane & 15);
        int t = tok[m];
        if (t >= 0) {
          float v = acc[mi][ni][r] + b2[(size_t)e * DIM + n0 + n];
          atomicAdd(out + (size_t)t * DIM + n0 + n, v * gat[m]);
        }
      }
}

extern "C" void kernel_launch(void* const* d_in, const int* in_sizes, int n_in,
                              void* d_out, int out_size, void* d_ws, size_t ws_size,
                              hipStream_t stream) {
  const float* x  = (const float*)d_in[0];
  const float* wr = (const float*)d_in[1];
  const float* br = (const float*)d_in[2];
  const float* w1 = (const float*)d_in[3];
  const float* b1 = (const float*)d_in[4];
  const float* w2 = (const float*)d_in[5];
  const float* b2 = (const float*)d_in[6];
  float* out = (float*)d_out;

  char* ws = (char*)d_ws;
  int*   counts      = (int*)(ws + 0);
  int*   cursors     = (int*)(ws + 64);
  int*   ntiles      = (int*)(ws + 128);
  int*   tile_expert = (int*)(ws + 256);
  int*   tile_row0   = (int*)(ws + 1024);
  int*   sel         = (int*)(ws + 4096);
  float* gates       = (float*)(ws + 4096 + 65536);
  int*   pair_token  = (int*)(ws + 4096 + 131072);
  float* pair_gate   = (float*)(ws + 4096 + 131072 + 69632);

  const size_t OFF_XB  = 274432;
  const size_t XB_SZ   = (size_t)TOKENS * DIM * 2;           // 16 MB
  const size_t OFF_W1T = OFF_XB + XB_SZ;
  const size_t WT_SZ   = (size_t)NEXP * DIM * HID * 2;       // 67 MB each
  const size_t OFF_W2T = OFF_W1T + WT_SZ;
  const size_t OFF_HN  = OFF_W2T + WT_SZ;
  const size_t tile_bytes = (size_t)TILE_M * HID * 2;        // 1 MB

  unsigned short* xb  = (unsigned short*)(ws + OFF_XB);

  hipMemsetAsync(d_out, 0, (size_t)out_size * sizeof(float), stream);
  hipMemsetAsync(counts, 0, 64, stream);

  hipLaunchKernelGGL(k_router, dim3(TOKENS / 4), dim3(256), 0, stream,
                     x, wr, br, sel, gates, counts, xb);
  hipLaunchKernelGGL(k_setup, dim3(1), dim3(256), 0, stream,
                     counts, cursors, ntiles, tile_expert, tile_row0,
                     pair_token, pair_gate, out + (size_t)out_size - 1);
  hipLaunchKernelGGL(k_bucket, dim3(TOKENS / 256), dim3(256), 0, stream,
                     sel, gates, cursors, pair_token, pair_gate);

  bool newpath = ws_size >= OFF_HN + tile_bytes;

  if (newpath) {
    unsigned short* w1T = (unsigned short*)(ws + OFF_W1T);
    unsigned short* w2T = (unsigned short*)(ws + OFF_W2T);
    unsigned short* h   = (unsigned short*)(ws + OFF_HN);

    hipLaunchKernelGGL(k_castwT, dim3(HID / 64, DIM / 64, NEXP), dim3(256), 0, stream,
                       w1, w1T, DIM, HID);
    hipLaunchKernelGGL(k_castwT, dim3(DIM / 64, HID / 64, NEXP), dim3(256), 0, stream,
                       w2, w2T, HID, DIM);

    long long avail = (long long)ws_size - (long long)OFF_HN;
    int tpc = (int)(avail / (long long)tile_bytes);
    if (tpc < 1) tpc = 1;
    if (tpc > MAX_TILES) tpc = MAX_TILES;
    int nchunks = (MAX_TILES + tpc - 1) / tpc;

    for (int c = 0; c < nchunks; ++c) {
      hipLaunchKernelGGL(k_gemm1n, dim3(tpc * (HID / 128)), dim3(256), 0, stream,
                         xb, w1T, b1, pair_token, tile_expert, tile_row0, ntiles, h, c * tpc);
      hipLaunchKernelGGL(k_gemm2n, dim3(tpc * (DIM / 128)), dim3(256), 0, stream,
                         h, w2T, b2, pair_token, pair_gate, tile_expert, tile_row0, ntiles, out, c * tpc);
    }
  } else {
    unsigned short* h = (unsigned short*)(ws + OFF_W1T);
    long long avail = (long long)ws_size - (long long)OFF_W1T;
    int tpc = (avail > 0) ? (int)(avail / (long long)tile_bytes) : 0;
    if (tpc < 1) tpc = 1;
    if (tpc > MAX_TILES) tpc = MAX_TILES;
    int nchunks = (MAX_TILES + tpc - 1) / tpc;

    for (int c = 0; c < nchunks; ++c) {
      hipLaunchKernelGGL(k_gemm1, dim3(HID / 128, tpc), dim3(256), 0, stream,
                         xb, w1, b1, pair_token, tile_expert, tile_row0, ntiles, h, c * tpc);
      hipLaunchKernelGGL(k_gemm2, dim3(DIM / 128, tpc), dim3(256), 0, stream,
                         h, w2, b2, pair_token, pair_gate, tile_expert, tile_row0, ntiles, out, c * tpc);
    }
  }
}

// Round 12
// 798.152 us; speedup vs baseline: 1.2068x; 1.0231x over previous
//
#include <hip/hip_runtime.h>
#include <math.h>

// MoE top-2 of 8 experts, D=1024, H=4096, 8192 tokens.
// Round 12: r11 GEMMs unchanged (best measured). Overhead polish:
// - merged single k_castw launch for w1T+w2T (flat grid, decode)
// - counts zeroing folded into castw block 0 (one fewer memset launch)
// - castw LDS stride 72->68 (row bank-step 2: 8-way -> ~4-way conflicts)
#define TOKENS 8192
#define DIM    1024
#define NEXP   8
#define HID    4096
#define TILE_M 128
#define MAX_TILES 136
#define BKS    32

// old-path (fallback) LDS strides
#define BK     32
#define LDA    40
#define LDB    40

typedef __bf16 bf16x8 __attribute__((ext_vector_type(8)));
typedef float  f32x4  __attribute__((ext_vector_type(4)));
typedef unsigned int u32x4 __attribute__((ext_vector_type(4)));

__device__ __forceinline__ unsigned short f2bf(float f) {
  union { float f; unsigned u; } v; v.f = f;
  unsigned u = v.u + 0x7fffu + ((v.u >> 16) & 1u);   // RNE
  return (unsigned short)(u >> 16);
}
__device__ __forceinline__ float gelu_f(float v) {
  return 0.5f * v * (1.f + erff(v * 0.7071067811865476f));
}
__device__ __forceinline__ float gelu_fast(float v) {
  float t = v * v;
  float y = 0.7978845608f * v * fmaf(t, 0.044715f, 1.0f);
  y = fminf(y, 15.f);
  float z = __expf(2.f * y);
  return v * z * __builtin_amdgcn_rcpf(1.f + z);
}
__device__ __forceinline__ void gload16(const void* g, void* l) {
  __builtin_amdgcn_global_load_lds(
      (const __attribute__((address_space(1))) void*)g,
      (__attribute__((address_space(3))) void*)l, 16, 0, 0);
}
// bijective XCD-chunked swizzle (m204)
__device__ __forceinline__ int xcd_swz(int id, int nwg) {
  int q = nwg >> 3, r = nwg & 7;
  int xcd = id & 7, rank = id >> 3;
  return (xcd < r) ? xcd * (q + 1) + rank : r * (q + 1) + (xcd - r) * q + rank;
}

// ---------------- router (+ fused x->bf16 cast): one wave per token ----------------
__global__ __launch_bounds__(256) void k_router(
    const float* __restrict__ x, const float* __restrict__ wr,
    const float* __restrict__ br, int* __restrict__ sel,
    float* __restrict__ gates, int* __restrict__ counts,
    unsigned short* __restrict__ xb)
{
  int t = blockIdx.x * 4 + (threadIdx.x >> 6);
  int lane = threadIdx.x & 63;
  const float* xr = x + (size_t)t * DIM;
  unsigned short* xo = xb + (size_t)t * DIM;
  float acc[NEXP];
#pragma unroll
  for (int e = 0; e < NEXP; ++e) acc[e] = 0.f;
#pragma unroll
  for (int it = 0; it < 4; ++it) {
    int d = it * 256 + lane * 4;
    float4 xv = *(const float4*)(xr + d);
    ushort4 pk;
    pk.x = f2bf(xv.x); pk.y = f2bf(xv.y); pk.z = f2bf(xv.z); pk.w = f2bf(xv.w);
    *(ushort4*)(xo + d) = pk;
    float xs[4] = {xv.x, xv.y, xv.z, xv.w};
#pragma unroll
    for (int j = 0; j < 4; ++j) {
      float4 wa = *(const float4*)(wr + (size_t)(d + j) * NEXP);
      float4 wb = *(const float4*)(wr + (size_t)(d + j) * NEXP + 4);
      acc[0] += xs[j] * wa.x; acc[1] += xs[j] * wa.y;
      acc[2] += xs[j] * wa.z; acc[3] += xs[j] * wa.w;
      acc[4] += xs[j] * wb.x; acc[5] += xs[j] * wb.y;
      acc[6] += xs[j] * wb.z; acc[7] += xs[j] * wb.w;
    }
  }
#pragma unroll
  for (int off = 32; off >= 1; off >>= 1) {
#pragma unroll
    for (int e = 0; e < NEXP; ++e) acc[e] += __shfl_xor(acc[e], off);
  }
  if (lane == 0) {
    float l[NEXP];
#pragma unroll
    for (int e = 0; e < NEXP; ++e) l[e] = acc[e] + br[e];
    int e1 = 0; float v1 = l[0];
#pragma unroll
    for (int e = 1; e < NEXP; ++e) if (l[e] > v1) { v1 = l[e]; e1 = e; }
    int e2 = -1; float v2 = -1e30f;
#pragma unroll
    for (int e = 0; e < NEXP; ++e) {
      if (e == e1) continue;
      if (l[e] > v2) { v2 = l[e]; e2 = e; }
    }
    float g1 = 1.f / (1.f + expf(v2 - v1));
    sel[t * 2] = e1; sel[t * 2 + 1] = e2;
    gates[t * 2] = g1; gates[t * 2 + 1] = 1.f - g1;
    atomicAdd(&counts[e1], 1);
    atomicAdd(&counts[e2], 1);
  }
}

// ---------------- setup: offsets, tile table, padding (parallel), loss ----------------
__global__ __launch_bounds__(256) void k_setup(
    const int* __restrict__ counts, int* __restrict__ cursors,
    int* __restrict__ ntiles_p, int* __restrict__ tile_expert,
    int* __restrict__ tile_row0, int* __restrict__ pair_token,
    float* __restrict__ pair_gate, float* __restrict__ loss_out)
{
  __shared__ int s_pad0[NEXP], s_pad1[NEXP];
  int tid = threadIdx.x;
  if (tid == 0) {
    int poff = 0, nt = 0;
    float var = 0.f;
    for (int e = 0; e < NEXP; ++e) {
      int c = counts[e];
      cursors[e] = poff;
      int ntl = (c + TILE_M - 1) / TILE_M;
      for (int i = 0; i < ntl; ++i) { tile_expert[nt] = e; tile_row0[nt] = poff + i * TILE_M; ++nt; }
      s_pad0[e] = poff + c;
      s_pad1[e] = poff + ntl * TILE_M;
      float d = (float)c - 2048.f;
      var += d * d;
      poff += ntl * TILE_M;
    }
    *ntiles_p = nt;
    *loss_out = (var * (1.f / 7.f)) * (1.f / 2048.f) * 0.01f;
  }
  __syncthreads();
#pragma unroll
  for (int e = 0; e < NEXP; ++e) {
    for (int r = s_pad0[e] + tid; r < s_pad1[e]; r += 256) {
      pair_token[r] = -1; pair_gate[r] = 0.f;
    }
  }
}

// ---------------- bucket: scatter pairs ----------------
__global__ __launch_bounds__(256) void k_bucket(
    const int* __restrict__ sel, const float* __restrict__ gates,
    int* __restrict__ cursors, int* __restrict__ pair_token, float* __restrict__ pair_gate)
{
  int t = blockIdx.x * 256 + threadIdx.x;
#pragma unroll
  for (int k = 0; k < 2; ++k) {
    int e = sel[t * 2 + k];
    int pos = atomicAdd(&cursors[e], 1);
    pair_token[pos] = t;
    pair_gate[pos] = gates[t * 2 + k];
  }
}

// ---------------- merged transpose-cast: w1 [E][D][H] -> w1T [E][H][D] and
// w2 [E][H][D] -> w2T [E][D][H], both f32 -> bf16. Flat grid 16384 blocks.
// Block 0 also zeroes counts (replaces a memset launch; castw runs first).
__global__ __launch_bounds__(256) void k_castw(
    const float* __restrict__ w1, unsigned short* __restrict__ w1T,
    const float* __restrict__ w2, unsigned short* __restrict__ w2T,
    int* __restrict__ counts)
{
  __shared__ unsigned short t[64 * 68];
  int bid = blockIdx.x;
  int tid = threadIdx.x;
  if (bid == 0 && tid < 16) counts[tid] = 0;

  const float* w; unsigned short* wT; int K, N, nb, kb, e;
  if (bid < 8192) {
    w = w1; wT = w1T; K = DIM; N = HID;             // blocks (N/64=64) x (K/64=16) x 8
    nb = bid & 63; kb = (bid >> 6) & 15; e = bid >> 10;
  } else {
    int b = bid - 8192;
    w = w2; wT = w2T; K = HID; N = DIM;             // blocks (N/64=16) x (K/64=64) x 8
    nb = b & 15; kb = (b >> 4) & 63; e = b >> 10;
  }
  int n0 = nb * 64, k0 = kb * 64;
  {
    int kr = (tid >> 4) * 4;          // 0..60 step 4
    int nc = (tid & 15) * 4;          // 0..60 step 4
    const float* src = w + ((size_t)e * K + k0 + kr) * N + n0 + nc;
    f32x4 r0 = *(const f32x4*)(src);
    f32x4 r1 = *(const f32x4*)(src + N);
    f32x4 r2 = *(const f32x4*)(src + 2 * (size_t)N);
    f32x4 r3 = *(const f32x4*)(src + 3 * (size_t)N);
#pragma unroll
    for (int i = 0; i < 4; ++i) {
      ushort4 p;
      p.x = f2bf(r0[i]); p.y = f2bf(r1[i]); p.z = f2bf(r2[i]); p.w = f2bf(r3[i]);
      *(ushort4*)&t[(nc + i) * 68 + kr] = p;   // t[n][k..k+3], stride 68
    }
  }
  __syncthreads();
  int nr = tid >> 2, kc = (tid & 3) * 16;
  unsigned short* dst = wT + ((size_t)e * N + n0 + nr) * K + k0 + kc;
#pragma unroll
  for (int j = 0; j < 4; ++j)
    *(unsigned long long*)(dst + 4 * j) =
        *(const unsigned long long*)&t[nr * 68 + kc + 4 * j];
}

// ================= 3-buffer counted-vmcnt GEMMs (T2-swizzled LDS, unpinned sched) =================
// Swizzle: LDS[row][granule g] holds logical granule g ^ ((row>>1)&3).
//  - write side (linear gload dest): source granule = (lane&3) ^ ((sr>>1)&3)
//  - read side: granule = lk ^ ((lr>>1)&3)   (lane-constant)
// GEMM1: h = gelu(x_gathered @ w1T^T + b1).  1-D grid = tpc * (HID/128).
__global__ __launch_bounds__(256) void k_gemm1n(
    const unsigned short* __restrict__ xb, const unsigned short* __restrict__ w1T,
    const float* __restrict__ b1, const int* __restrict__ pair_token,
    const int* __restrict__ tile_expert, const int* __restrict__ tile_row0,
    const int* __restrict__ ntiles_p, unsigned short* __restrict__ h, int chunk_base)
{
  const int NBn = HID / 128;                       // 32
  const int nwg = gridDim.x;
  int newid = xcd_swz(blockIdx.x, nwg);
  int ltile = newid / NBn, nb = newid - ltile * NBn;
  int tile = chunk_base + ltile;
  if (tile >= *ntiles_p) return;
  const int e = tile_expert[tile];
  const int row0 = tile_row0[tile];
  const int n0 = nb * 128;
  const int tid = threadIdx.x;
  const int w = tid >> 6, lane = tid & 63;

  __shared__ unsigned short As[3][128 * BKS];
  __shared__ unsigned short Bs[3][128 * BKS];
  __shared__ int tok[128];

  if (tid < 128) { int t = pair_token[row0 + tid]; tok[tid] = (t < 0) ? 0 : t; }
  __syncthreads();

  const int sr = lane >> 2;
  const int kq = (((lane & 3) ^ ((sr >> 1) & 3))) * 8;   // swizzled source granule
  const int ar1 = w * 32 + sr, ar2 = ar1 + 16;
  const unsigned short* ag1 = xb + (size_t)tok[ar1] * DIM + kq;
  const unsigned short* ag2 = xb + (size_t)tok[ar2] * DIM + kq;
  const unsigned short* bg1 = w1T + ((size_t)e * HID + n0 + ar1) * DIM + kq;
  const unsigned short* bg2 = w1T + ((size_t)e * HID + n0 + ar2) * DIM + kq;

  const int wm = (w & 1) * 64, wn = (w >> 1) * 64;
  const int lr = lane & 15, lk = lane >> 4;
  const int gx = lk ^ ((lr >> 1) & 3);                   // swizzled read granule

  f32x4 acc[4][4];
#pragma unroll
  for (int mi = 0; mi < 4; ++mi)
#pragma unroll
    for (int ni = 0; ni < 4; ++ni) acc[mi][ni] = {0.f, 0.f, 0.f, 0.f};

#define STAGE1(buf, koff)                                      \
  gload16(ag1 + (koff), &As[buf][(w * 32) * BKS]);             \
  gload16(ag2 + (koff), &As[buf][(w * 32 + 16) * BKS]);        \
  gload16(bg1 + (koff), &Bs[buf][(w * 32) * BKS]);             \
  gload16(bg2 + (koff), &Bs[buf][(w * 32 + 16) * BKS]);

  STAGE1(0, 0)
  STAGE1(1, BKS)
  asm volatile("s_waitcnt vmcnt(4)" ::: "memory");
  __builtin_amdgcn_s_barrier();
  asm volatile("" ::: "memory");

  const int NT = DIM / BKS;                        // 32
  int cur = 0, dst = 2;
  for (int t = 0; t < NT; ++t) {
    if (t + 2 < NT) { STAGE1(dst, (t + 2) * BKS) }
    bf16x8 af[4], bfr[4];
#pragma unroll
    for (int mi = 0; mi < 4; ++mi)
      af[mi] = *(const bf16x8*)&As[cur][(wm + mi * 16 + lr) * BKS + gx * 8];
#pragma unroll
    for (int ni = 0; ni < 4; ++ni)
      bfr[ni] = *(const bf16x8*)&Bs[cur][(wn + ni * 16 + lr) * BKS + gx * 8];
    // no manual lgkmcnt/sched_barrier: compiler emits counted lgkmcnt per-MFMA
    __builtin_amdgcn_s_setprio(1);
#pragma unroll
    for (int mi = 0; mi < 4; ++mi)
#pragma unroll
      for (int ni = 0; ni < 4; ++ni)
        acc[mi][ni] = __builtin_amdgcn_mfma_f32_16x16x32_bf16(bfr[ni], af[mi], acc[mi][ni], 0, 0, 0);
    __builtin_amdgcn_s_setprio(0);
    if (t + 2 < NT) { asm volatile("s_waitcnt vmcnt(4)" ::: "memory"); }
    else            { asm volatile("s_waitcnt vmcnt(0)" ::: "memory"); }
    __builtin_amdgcn_s_barrier();
    asm volatile("" ::: "memory");
    cur = (cur == 2) ? 0 : cur + 1;
    dst = (dst == 2) ? 0 : dst + 1;
  }
#undef STAGE1

  const size_t tl = (size_t)(tile - chunk_base);
  f32x4 bv[4];
#pragma unroll
  for (int ni = 0; ni < 4; ++ni)
    bv[ni] = *(const f32x4*)(b1 + (size_t)e * HID + n0 + wn + ni * 16 + lk * 4);
#pragma unroll
  for (int mi = 0; mi < 4; ++mi) {
    int m = wm + mi * 16 + lr;
    unsigned short* hrow = h + (tl * TILE_M + m) * HID + n0;
#pragma unroll
    for (int ni = 0; ni < 4; ++ni) {
      int nb4 = wn + ni * 16 + lk * 4;
      ushort4 pk;
      pk.x = f2bf(gelu_fast(acc[mi][ni][0] + bv[ni][0]));
      pk.y = f2bf(gelu_fast(acc[mi][ni][1] + bv[ni][1]));
      pk.z = f2bf(gelu_fast(acc[mi][ni][2] + bv[ni][2]));
      pk.w = f2bf(gelu_fast(acc[mi][ni][3] + bv[ni][3]));
      *(ushort4*)(hrow + nb4) = pk;
    }
  }
}

// GEMM2: out[token] += gate * (h @ w2T^T + b2).  1-D grid = tpc * (DIM/128).
__global__ __launch_bounds__(256) void k_gemm2n(
    const unsigned short* __restrict__ h, const unsigned short* __restrict__ w2T,
    const float* __restrict__ b2, const int* __restrict__ pair_token,
    const float* __restrict__ pair_gate,
    const int* __restrict__ tile_expert, const int* __restrict__ tile_row0,
    const int* __restrict__ ntiles_p, float* __restrict__ out, int chunk_base)
{
  const int NBn = DIM / 128;                       // 8
  const int nwg = gridDim.x;
  int newid = xcd_swz(blockIdx.x, nwg);
  int ltile = newid / NBn, nb = newid - ltile * NBn;
  int tile = chunk_base + ltile;
  if (tile >= *ntiles_p) return;
  const int e = tile_expert[tile];
  const int row0 = tile_row0[tile];
  const int n0 = nb * 128;
  const int tid = threadIdx.x;
  const int w = tid >> 6, lane = tid & 63;

  __shared__ unsigned short As[3][128 * BKS];
  __shared__ unsigned short Bs[3][128 * BKS];
  __shared__ int tok[128];
  __shared__ float gat[128];

  if (tid < 128) { tok[tid] = pair_token[row0 + tid]; gat[tid] = pair_gate[row0 + tid]; }
  __syncthreads();

  const int sr = lane >> 2;
  const int kq = (((lane & 3) ^ ((sr >> 1) & 3))) * 8;   // swizzled source granule
  const int ar1 = w * 32 + sr, ar2 = ar1 + 16;
  const size_t tl = (size_t)(tile - chunk_base);
  const unsigned short* ag1 = h + (tl * TILE_M + ar1) * HID + kq;
  const unsigned short* ag2 = h + (tl * TILE_M + ar2) * HID + kq;
  const unsigned short* bg1 = w2T + ((size_t)e * DIM + n0 + ar1) * HID + kq;
  const unsigned short* bg2 = w2T + ((size_t)e * DIM + n0 + ar2) * HID + kq;

  const int wm = (w & 1) * 64, wn = (w >> 1) * 64;
  const int lr = lane & 15, lk = lane >> 4;
  const int gx = lk ^ ((lr >> 1) & 3);                   // swizzled read granule

  f32x4 acc[4][4];
#pragma unroll
  for (int mi = 0; mi < 4; ++mi)
#pragma unroll
    for (int ni = 0; ni < 4; ++ni) acc[mi][ni] = {0.f, 0.f, 0.f, 0.f};

#define STAGE2(buf, koff)                                      \
  gload16(ag1 + (koff), &As[buf][(w * 32) * BKS]);             \
  gload16(ag2 + (koff), &As[buf][(w * 32 + 16) * BKS]);        \
  gload16(bg1 + (koff), &Bs[buf][(w * 32) * BKS]);             \
  gload16(bg2 + (koff), &Bs[buf][(w * 32 + 16) * BKS]);

  STAGE2(0, 0)
  STAGE2(1, BKS)
  asm volatile("s_waitcnt vmcnt(4)" ::: "memory");
  __builtin_amdgcn_s_barrier();
  asm volatile("" ::: "memory");

  const int NT = HID / BKS;                        // 128
  int cur = 0, dst = 2;
  for (int t = 0; t < NT; ++t) {
    if (t + 2 < NT) { STAGE2(dst, (t + 2) * BKS) }
    bf16x8 af[4], bfr[4];
#pragma unroll
    for (int mi = 0; mi < 4; ++mi)
      af[mi] = *(const bf16x8*)&As[cur][(wm + mi * 16 + lr) * BKS + gx * 8];
#pragma unroll
    for (int ni = 0; ni < 4; ++ni)
      bfr[ni] = *(const bf16x8*)&Bs[cur][(wn + ni * 16 + lr) * BKS + gx * 8];
    // no manual lgkmcnt/sched_barrier: compiler emits counted lgkmcnt per-MFMA
    __builtin_amdgcn_s_setprio(1);
#pragma unroll
    for (int mi = 0; mi < 4; ++mi)
#pragma unroll
      for (int ni = 0; ni < 4; ++ni)
        acc[mi][ni] = __builtin_amdgcn_mfma_f32_16x16x32_bf16(af[mi], bfr[ni], acc[mi][ni], 0, 0, 0);
    __builtin_amdgcn_s_setprio(0);
    if (t + 2 < NT) { asm volatile("s_waitcnt vmcnt(4)" ::: "memory"); }
    else            { asm volatile("s_waitcnt vmcnt(0)" ::: "memory"); }
    __builtin_amdgcn_s_barrier();
    asm volatile("" ::: "memory");
    cur = (cur == 2) ? 0 : cur + 1;
    dst = (dst == 2) ? 0 : dst + 1;
  }
#undef STAGE2

  float bia[4];
#pragma unroll
  for (int ni = 0; ni < 4; ++ni) bia[ni] = b2[(size_t)e * DIM + n0 + wn + ni * 16 + lr];
#pragma unroll
  for (int mi = 0; mi < 4; ++mi)
#pragma unroll
    for (int r = 0; r < 4; ++r) {
      int m = wm + mi * 16 + lk * 4 + r;
      int t = tok[m];
      if (t >= 0) {
        float g = gat[m];
#pragma unroll
        for (int ni = 0; ni < 4; ++ni) {
          int n = wn + ni * 16 + lr;
          atomicAdd(out + (size_t)t * DIM + n0 + n, (acc[mi][ni][r] + bia[ni]) * g);
        }
      }
    }
}

// ================= OLD fallback GEMMs (round-1, known-good) =================
__global__ __launch_bounds__(256) void k_gemm1(
    const unsigned short* __restrict__ xb, const float* __restrict__ w1,
    const float* __restrict__ b1, const int* __restrict__ pair_token,
    const int* __restrict__ tile_expert, const int* __restrict__ tile_row0,
    const int* __restrict__ ntiles_p, unsigned short* __restrict__ h, int chunk_base)
{
  int tile = chunk_base + blockIdx.y;
  if (tile >= *ntiles_p) return;
  const int e = tile_expert[tile];
  const int row0 = tile_row0[tile];
  const int n0 = blockIdx.x * 128;
  const int tid = threadIdx.x;

  __shared__ unsigned short As[TILE_M * LDA];
  __shared__ unsigned short Bs[128 * LDB];
  __shared__ int tok[TILE_M];

  if (tid < TILE_M) tok[tid] = pair_token[row0 + tid];
  __syncthreads();

  const int ar = tid >> 1, akh = (tid & 1) * 16;
  const int bk = tid >> 3, bnh = (tid & 7) * 16;
  const int bswz = tid & 3;
  const int wv = tid >> 6, lane = tid & 63;
  const int wm = (wv & 1) * 64, wn = (wv >> 1) * 64;
  const int lr = lane & 15, lk = lane >> 4;
  const int atok = tok[ar];

  f32x4 acc[4][4];
#pragma unroll
  for (int mi = 0; mi < 4; ++mi)
#pragma unroll
    for (int ni = 0; ni < 4; ++ni) acc[mi][ni] = {0.f, 0.f, 0.f, 0.f};

  const unsigned short* asrc = (atok >= 0) ? (xb + (size_t)atok * DIM + akh) : (const unsigned short*)0;
  const float* bsrc0 = w1 + ((size_t)e * DIM + bk) * HID + n0 + bnh;
  const int wcol = 8 * ((bk >> 3) ^ bswz) + (bk & 7);

  for (int k0 = 0; k0 < DIM; k0 += BK) {
    u32x4 av0 = {0, 0, 0, 0}, av1 = {0, 0, 0, 0};
    if (asrc) {
      av0 = *(const u32x4*)(asrc + k0);
      av1 = *(const u32x4*)(asrc + k0 + 8);
    }
    float bv[16];
    const float* bs = bsrc0 + (size_t)k0 * HID;
#pragma unroll
    for (int j = 0; j < 4; ++j) {
      f32x4 f = *(const f32x4*)(bs + j * 4);
      bv[j * 4 + 0] = f[0]; bv[j * 4 + 1] = f[1];
      bv[j * 4 + 2] = f[2]; bv[j * 4 + 3] = f[3];
    }
    __syncthreads();
    *(u32x4*)&As[ar * LDA + akh] = av0;
    *(u32x4*)&As[ar * LDA + akh + 8] = av1;
#pragma unroll
    for (int j = 0; j < 16; ++j)
      Bs[(bnh + j) * LDB + wcol] = f2bf(bv[j]);
    __syncthreads();

    bf16x8 af[4], bfr[4];
#pragma unroll
    for (int mi = 0; mi < 4; ++mi)
      af[mi] = *(const bf16x8*)&As[(wm + mi * 16 + lr) * LDA + lk * 8];
#pragma unroll
    for (int ni = 0; ni < 4; ++ni) {
      int pch = lk ^ (((wn >> 4) + ni) & 3);
      bfr[ni] = *(const bf16x8*)&Bs[(wn + ni * 16 + lr) * LDB + pch * 8];
    }
#pragma unroll
    for (int mi = 0; mi < 4; ++mi)
#pragma unroll
      for (int ni = 0; ni < 4; ++ni)
        acc[mi][ni] = __builtin_amdgcn_mfma_f32_16x16x32_bf16(af[mi], bfr[ni], acc[mi][ni], 0, 0, 0);
  }

  const size_t tl = (size_t)(tile - chunk_base);
#pragma unroll
  for (int mi = 0; mi < 4; ++mi)
#pragma unroll
    for (int ni = 0; ni < 4; ++ni)
#pragma unroll
      for (int r = 0; r < 4; ++r) {
        int m = wm + mi * 16 + (lane >> 4) * 4 + r;
        int n = wn + ni * 16 + (lane & 15);
        float v = acc[mi][ni][r] + b1[(size_t)e * HID + n0 + n];
        h[(tl * TILE_M + m) * HID + n0 + n] = f2bf(gelu_f(v));
      }
}

__global__ __launch_bounds__(256) void k_gemm2(
    const unsigned short* __restrict__ h, const float* __restrict__ w2,
    const float* __restrict__ b2, const int* __restrict__ pair_token,
    const float* __restrict__ pair_gate,
    const int* __restrict__ tile_expert, const int* __restrict__ tile_row0,
    const int* __restrict__ ntiles_p, float* __restrict__ out, int chunk_base)
{
  int tile = chunk_base + blockIdx.y;
  if (tile >= *ntiles_p) return;
  const int e = tile_expert[tile];
  const int row0 = tile_row0[tile];
  const int n0 = blockIdx.x * 128;
  const int tid = threadIdx.x;

  __shared__ unsigned short As[TILE_M * LDA];
  __shared__ unsigned short Bs[128 * LDB];
  __shared__ int tok[TILE_M];
  __shared__ float gat[TILE_M];

  if (tid < TILE_M) { tok[tid] = pair_token[row0 + tid]; gat[tid] = pair_gate[row0 + tid]; }
  __syncthreads();

  const int ar = tid >> 1, akh = (tid & 1) * 16;
  const int bk = tid >> 3, bnh = (tid & 7) * 16;
  const int bswz = tid & 3;
  const int wv = tid >> 6, lane = tid & 63;
  const int wm = (wv & 1) * 64, wn = (wv >> 1) * 64;
  const int lr = lane & 15, lk = lane >> 4;

  f32x4 acc[4][4];
#pragma unroll
  for (int mi = 0; mi < 4; ++mi)
#pragma unroll
    for (int ni = 0; ni < 4; ++ni) acc[mi][ni] = {0.f, 0.f, 0.f, 0.f};

  const size_t tl = (size_t)(tile - chunk_base);
  const unsigned short* asrc = h + (tl * TILE_M + ar) * HID + akh;
  const float* bsrc0 = w2 + ((size_t)e * HID + bk) * DIM + n0 + bnh;
  const int wcol = 8 * ((bk >> 3) ^ bswz) + (bk & 7);

  for (int k0 = 0; k0 < HID; k0 += BK) {
    u32x4 av0 = *(const u32x4*)(asrc + k0);
    u32x4 av1 = *(const u32x4*)(asrc + k0 + 8);
    float bv[16];
    const float* bs = bsrc0 + (size_t)k0 * DIM;
#pragma unroll
    for (int j = 0; j < 4; ++j) {
      f32x4 f = *(const f32x4*)(bs + j * 4);
      bv[j * 4 + 0] = f[0]; bv[j * 4 + 1] = f[1];
      bv[j * 4 + 2] = f[2]; bv[j * 4 + 3] = f[3];
    }
    __syncthreads();
    *(u32x4*)&As[ar * LDA + akh] = av0;
    *(u32x4*)&As[ar * LDA + akh + 8] = av1;
#pragma unroll
    for (int j = 0; j < 16; ++j)
      Bs[(bnh + j) * LDB + wcol] = f2bf(bv[j]);
    __syncthreads();

    bf16x8 af[4], bfr[4];
#pragma unroll
    for (int mi = 0; mi < 4; ++mi)
      af[mi] = *(const bf16x8*)&As[(wm + mi * 16 + lr) * LDA + lk * 8];
#pragma unroll
    for (int ni = 0; ni < 4; ++ni) {
      int pch = lk ^ (((wn >> 4) + ni) & 3);
      bfr[ni] = *(const bf16x8*)&Bs[(wn + ni * 16 + lr) * LDB + pch * 8];
    }
#pragma unroll
    for (int mi = 0; mi < 4; ++mi)
#pragma unroll
      for (int ni = 0; ni < 4; ++ni)
        acc[mi][ni] = __builtin_amdgcn_mfma_f32_16x16x32_bf16(af[mi], bfr[ni], acc[mi][ni], 0, 0, 0);
  }

#pragma unroll
  for (int mi = 0; mi < 4; ++mi)
#pragma unroll
    for (int ni = 0; ni < 4; ++ni)
#pragma unroll
      for (int r = 0; r < 4; ++r) {
        int m = wm + mi * 16 + (lane >> 4) * 4 + r;
        int n = wn + ni * 16 + (lane & 15);
        int t = tok[m];
        if (t >= 0) {
          float v = acc[mi][ni][r] + b2[(size_t)e * DIM + n0 + n];
          atomicAdd(out + (size_t)t * DIM + n0 + n, v * gat[m]);
        }
      }
}

extern "C" void kernel_launch(void* const* d_in, const int* in_sizes, int n_in,
                              void* d_out, int out_size, void* d_ws, size_t ws_size,
                              hipStream_t stream) {
  const float* x  = (const float*)d_in[0];
  const float* wr = (const float*)d_in[1];
  const float* br = (const float*)d_in[2];
  const float* w1 = (const float*)d_in[3];
  const float* b1 = (const float*)d_in[4];
  const float* w2 = (const float*)d_in[5];
  const float* b2 = (const float*)d_in[6];
  float* out = (float*)d_out;

  char* ws = (char*)d_ws;
  int*   counts      = (int*)(ws + 0);
  int*   cursors     = (int*)(ws + 64);
  int*   ntiles      = (int*)(ws + 128);
  int*   tile_expert = (int*)(ws + 256);
  int*   tile_row0   = (int*)(ws + 1024);
  int*   sel         = (int*)(ws + 4096);
  float* gates       = (float*)(ws + 4096 + 65536);
  int*   pair_token  = (int*)(ws + 4096 + 131072);
  float* pair_gate   = (float*)(ws + 4096 + 131072 + 69632);

  const size_t OFF_XB  = 274432;
  const size_t XB_SZ   = (size_t)TOKENS * DIM * 2;           // 16 MB
  const size_t OFF_W1T = OFF_XB + XB_SZ;
  const size_t WT_SZ   = (size_t)NEXP * DIM * HID * 2;       // 67 MB each
  const size_t OFF_W2T = OFF_W1T + WT_SZ;
  const size_t OFF_HN  = OFF_W2T + WT_SZ;
  const size_t tile_bytes = (size_t)TILE_M * HID * 2;        // 1 MB

  unsigned short* xb  = (unsigned short*)(ws + OFF_XB);

  hipMemsetAsync(d_out, 0, (size_t)out_size * sizeof(float), stream);

  bool newpath = ws_size >= OFF_HN + tile_bytes;

  if (newpath) {
    unsigned short* w1T = (unsigned short*)(ws + OFF_W1T);
    unsigned short* w2T = (unsigned short*)(ws + OFF_W2T);
    unsigned short* h   = (unsigned short*)(ws + OFF_HN);

    // castw first: also zeroes counts (block 0) before k_router's atomics.
    hipLaunchKernelGGL(k_castw, dim3(16384), dim3(256), 0, stream,
                       w1, w1T, w2, w2T, counts);
    hipLaunchKernelGGL(k_router, dim3(TOKENS / 4), dim3(256), 0, stream,
                       x, wr, br, sel, gates, counts, xb);
    hipLaunchKernelGGL(k_setup, dim3(1), dim3(256), 0, stream,
                       counts, cursors, ntiles, tile_expert, tile_row0,
                       pair_token, pair_gate, out + (size_t)out_size - 1);
    hipLaunchKernelGGL(k_bucket, dim3(TOKENS / 256), dim3(256), 0, stream,
                       sel, gates, cursors, pair_token, pair_gate);

    long long avail = (long long)ws_size - (long long)OFF_HN;
    int tpc = (int)(avail / (long long)tile_bytes);
    if (tpc < 1) tpc = 1;
    if (tpc > MAX_TILES) tpc = MAX_TILES;
    int nchunks = (MAX_TILES + tpc - 1) / tpc;

    for (int c = 0; c < nchunks; ++c) {
      hipLaunchKernelGGL(k_gemm1n, dim3(tpc * (HID / 128)), dim3(256), 0, stream,
                         xb, w1T, b1, pair_token, tile_expert, tile_row0, ntiles, h, c * tpc);
      hipLaunchKernelGGL(k_gemm2n, dim3(tpc * (DIM / 128)), dim3(256), 0, stream,
                         h, w2T, b2, pair_token, pair_gate, tile_expert, tile_row0, ntiles, out, c * tpc);
    }
  } else {
    hipMemsetAsync(counts, 0, 64, stream);
    hipLaunchKernelGGL(k_router, dim3(TOKENS / 4), dim3(256), 0, stream,
                       x, wr, br, sel, gates, counts, xb);
    hipLaunchKernelGGL(k_setup, dim3(1), dim3(256), 0, stream,
                       counts, cursors, ntiles, tile_expert, tile_row0,
                       pair_token, pair_gate, out + (size_t)out_size - 1);
    hipLaunchKernelGGL(k_bucket, dim3(TOKENS / 256), dim3(256), 0, stream,
                       sel, gates, cursors, pair_token, pair_gate);

    unsigned short* h = (unsigned short*)(ws + OFF_W1T);
    long long avail = (long long)ws_size - (long long)OFF_W1T;
    int tpc = (avail > 0) ? (int)(avail / (long long)tile_bytes) : 0;
    if (tpc < 1) tpc = 1;
    if (tpc > MAX_TILES) tpc = MAX_TILES;
    int nchunks = (MAX_TILES + tpc - 1) / tpc;

    for (int c = 0; c < nchunks; ++c) {
      hipLaunchKernelGGL(k_gemm1, dim3(HID / 128, tpc), dim3(256), 0, stream,
                         xb, w1, b1, pair_token, tile_expert, tile_row0, ntiles, h, c * tpc);
      hipLaunchKernelGGL(k_gemm2, dim3(DIM / 128, tpc), dim3(256), 0, stream,
                         h, w2, b2, pair_token, pair_gate, tile_expert, tile_row0, ntiles, out, c * tpc);
    }
  }
}